// Round 1
// 4102.660 us; speedup vs baseline: 1.4071x; 1.4071x over previous
//
#include <hip/hip_runtime.h>
#include <math.h>

typedef unsigned short u16;
typedef float v4f  __attribute__((ext_vector_type(4)));
typedef __bf16 v8bf __attribute__((ext_vector_type(8)));

enum { nB=4, nL=1024, nW=1024, nH=16, nN=64, nE=2048, nP=128, nNH=32, nDEPTH=4 };
enum { C_CH=16, T_CH=64 };   // chunked scan: 16 chunks of 64 steps

__device__ __forceinline__ float bf2f(u16 u){ unsigned v=((unsigned)u)<<16; return __builtin_bit_cast(float,v); }
__device__ __forceinline__ u16 f2bf(float f){ unsigned x=__builtin_bit_cast(unsigned,f); return (u16)((x + 0x7fffu + ((x>>16)&1u))>>16); }
__device__ __forceinline__ float softplus_f(float v){ return (v>15.f)? v : log1pf(expf(v)); }
__device__ __forceinline__ void unp8(uint4 u, float* f){
  f[0]=bf2f((u16)(u.x&0xffff)); f[1]=bf2f((u16)(u.x>>16));
  f[2]=bf2f((u16)(u.y&0xffff)); f[3]=bf2f((u16)(u.y>>16));
  f[4]=bf2f((u16)(u.z&0xffff)); f[5]=bf2f((u16)(u.z>>16));
  f[6]=bf2f((u16)(u.w&0xffff)); f[7]=bf2f((u16)(u.w>>16));
}
__device__ __forceinline__ v4f unp4(ushort4 u){
  v4f r = {bf2f(u.x), bf2f(u.y), bf2f(u.z), bf2f(u.w)}; return r;
}

// ---------------- copy h (fp32) -> x (fp32 residual) ----------------
__global__ void k_cvt(const float* __restrict__ hsrc, float* __restrict__ x){
  int i = (blockIdx.x*256 + threadIdx.x)*4;
  *(v4f*)(x + i) = *(const v4f*)(hsrc + i);
}

// ---------------- transpose fp32 (R,C) -> bf16 (C,R) ----------------
__global__ __launch_bounds__(256) void k_transpose(const float* __restrict__ src, u16* __restrict__ dst,
    int R, int C)
{
  __shared__ u16 tl[32][36];
  int r0 = blockIdx.y*32, c0 = blockIdx.x*32;
  int tid = threadIdx.x;
  int r = tid>>3, c4 = (tid&7)*4;
  if (r0 + r < R){
#pragma unroll
    for (int jj=0;jj<4;jj++){
      int c = c0 + c4 + jj;
      tl[r][c4+jj] = (c < C) ? f2bf(src[(size_t)(r0+r)*C + c]) : (u16)0;
    }
  }
  __syncthreads();
  int c = tid>>3, r4 = (tid&7)*4;
  if (c0 + c < C){
#pragma unroll
    for (int jj=0;jj<4;jj++){
      int rr = r0 + r4 + jj;
      if (rr < R) dst[(size_t)(c0+c)*R + rr] = tl[r4+jj][c];
    }
  }
}

// ---------------- rmsnorm: x(fp32) * w(fp32) -> bf16 and/or fp32 ----------------
__global__ __launch_bounds__(256) void k_rmsnorm(const float* __restrict__ x, const float* __restrict__ w,
    u16* __restrict__ obf, float* __restrict__ of32)
{
  int row = blockIdx.x, tid = threadIdx.x;
  const float* xr = x + (size_t)row*1024;
  v4f v = *(const v4f*)(xr + tid*4);
  float ss = v[0]*v[0]+v[1]*v[1]+v[2]*v[2]+v[3]*v[3];
#pragma unroll
  for (int o=1;o<64;o<<=1) ss += __shfl_xor(ss,o);
  __shared__ float red[4];
  if ((tid&63)==0) red[tid>>6] = ss;
  __syncthreads();
  float tot = red[0]+red[1]+red[2]+red[3];
  float rms = rsqrtf(tot*(1.f/1024.f) + 1e-6f);
  v4f wv = *(const v4f*)(w + tid*4);
  float o0=v[0]*rms*wv[0], o1=v[1]*rms*wv[1], o2=v[2]*rms*wv[2], o3=v[3]*rms*wv[3];
  if (obf){
    ushort4 ob = { f2bf(o0), f2bf(o1), f2bf(o2), f2bf(o3) };
    *(ushort4*)(obf + (size_t)row*1024 + tid*4) = ob;
  }
  if (of32){
    v4f ov = {o0,o1,o2,o3};
    *(v4f*)(of32 + (size_t)row*1024 + tid*4) = ov;
  }
}

// ---------------- MFMA GEMM: C = A(MxK,bf16) @ BT(NxK,bf16)^T + bias(fp32); OT float(+=) or u16
template<typename OT, bool ADD>
__global__ __launch_bounds__(256) void k_gemm(const u16* __restrict__ A, const u16* __restrict__ BT,
    const float* __restrict__ bias, OT* __restrict__ C, int N, int K)
{
  __shared__ u16 As[128*40];
  __shared__ u16 Bs[128*40];
  const int tid = threadIdx.x;
  const int wave = tid>>6, lane = tid&63, quad = lane>>4, l15 = lane&15;
  const int bm = blockIdx.y*128, bn = blockIdx.x*128;
  const int wm = (wave>>1)*64, wn = (wave&1)*64;
  v4f acc[4][4];
#pragma unroll
  for (int i=0;i<4;i++)
#pragma unroll
    for (int j=0;j<4;j++){ v4f z = {0.f,0.f,0.f,0.f}; acc[i][j]=z; }

  for (int k0=0; k0<K; k0+=32){
    uint4 av[2], bv[2];
#pragma unroll
    for (int i=0;i<2;i++){
      int c = 2*tid+i, row = c>>2, pos = c&3;
      av[i] = *(const uint4*)(A  + (size_t)(bm+row)*K + k0 + pos*8);
      bv[i] = *(const uint4*)(BT + (size_t)(bn+row)*K + k0 + pos*8);
    }
    __syncthreads();
#pragma unroll
    for (int i=0;i<2;i++){
      int c = 2*tid+i, row = c>>2, pos = c&3;
      *(uint4*)(As + row*40 + pos*8) = av[i];
      *(uint4*)(Bs + row*40 + pos*8) = bv[i];
    }
    __syncthreads();
    v8bf af[4], bfr[4];
#pragma unroll
    for (int mi=0;mi<4;mi++) af[mi]  = *(const v8bf*)(As + (wm+mi*16+l15)*40 + quad*8);
#pragma unroll
    for (int ni=0;ni<4;ni++) bfr[ni] = *(const v8bf*)(Bs + (wn+ni*16+l15)*40 + quad*8);
#pragma unroll
    for (int mi=0;mi<4;mi++)
#pragma unroll
      for (int ni=0;ni<4;ni++)
        acc[mi][ni] = __builtin_amdgcn_mfma_f32_16x16x32_bf16(af[mi], bfr[ni], acc[mi][ni], 0,0,0);
  }
#pragma unroll
  for (int ni=0;ni<4;ni++){
    int col = bn + wn + ni*16 + l15;
    float bz = bias[col];
#pragma unroll
    for (int mi=0;mi<4;mi++){
      int row = bm + wm + mi*16 + quad*4;
      v4f v = acc[mi][ni];
#pragma unroll
      for (int r=0;r<4;r++){
        size_t off = (size_t)(row+r)*N + col;
        float o = v[r] + bz;
        if constexpr (ADD) o += ((const float*)C)[off];
        if constexpr (sizeof(OT)==2) ((u16*)C)[off] = f2bf(o);
        else ((float*)C)[off] = o;
      }
    }
  }
}

// ---------------- dt matmul: dtraw(rows x 16) = r(bf16) @ dt_wT(16x1024,bf16)^T --------------
__global__ __launch_bounds__(64) void k_dt(const u16* __restrict__ r, const u16* __restrict__ dtwT,
    float* __restrict__ dtraw)
{
  int row = blockIdx.x, lane = threadIdx.x;
  const u16* rp = r + (size_t)row*1024 + lane*16;
  float rv[16];
  unp8(*(const uint4*)rp, rv);
  unp8(*(const uint4*)(rp+8), rv+8);
  float keep = 0.f;
  for (int hh=0; hh<16; hh++){
    const u16* wp = dtwT + hh*1024 + lane*16;
    float wv[16];
    unp8(*(const uint4*)wp, wv);
    unp8(*(const uint4*)(wp+8), wv+8);
    float sv = 0.f;
#pragma unroll
    for (int j=0;j<16;j++) sv = fmaf(rv[j], wv[j], sv);
#pragma unroll
    for (int o=1;o<64;o<<=1) sv += __shfl_xor(sv, o);
    if (lane==hh) keep = sv;
  }
  if (lane<16) dtraw[(size_t)row*16 + lane] = keep;
}

// ---------------- prep2 per (b,l,h): scal2 = (dec, 0.5*dt); dtarr = dt ----------------
__global__ void k_prep2(const float* __restrict__ dtraw, const float* __restrict__ dt_b,
    const float* __restrict__ A_log, float* __restrict__ scal2, float* __restrict__ dtarr)
{
  int i = blockIdx.x*256 + threadIdx.x;      // (b,l,h) h-fastest
  int h = i & 15;
  float dt0 = fminf(softplus_f(dtraw[i] + dt_b[h]), 30.f);
  float A = -expf(A_log[h]);
  scal2[(size_t)i*2]   = expf(A*dt0);
  scal2[(size_t)i*2+1] = 0.5f*dt0;
  dtarr[i] = dt0;
}

// ---------------- cs2: per-step cos/sin only ----------------
__global__ void k_cs2(const float* __restrict__ dtarr, const float* __restrict__ omega,
    float* __restrict__ cst, float* __restrict__ sst)
{
  int i = blockIdx.x*256 + threadIdx.x;   // (b,l,h,q)
  int q = i & 31, blh = i>>5;
  float sn, cn; __sincosf(dtarr[blh]*omega[q], &sn, &cn);
  cst[i]=cn; sst[i]=sn;
}

// ---------------- chunk cumulative transition: prod[(bh*16+c)*64 + 2q+{0,1}] = exp(A*S)*(cos,sin)(w_q*S)
// S = sum of dt over the chunk. Valid because prod_t dec_t*e^{i dt_t w_q} = e^{A*S} e^{i w_q S}.
__global__ void k_chunkprod(const float* __restrict__ dtarr, const float* __restrict__ A_log,
    const float* __restrict__ omega, float* __restrict__ prod)
{
  int i = blockIdx.x*256 + threadIdx.x;   // 1024 items: (bh, c)
  int bh = i >> 4, c = i & 15;
  int b = bh >> 4, h = bh & 15;
  size_t base = ((size_t)b*nL + c*T_CH)*16 + h;
  float S = 0.f;
  for (int t=0;t<T_CH;t++) S += dtarr[base + (size_t)t*16];
  float A = -expf(A_log[h]);
  float decF = expf(A*S);
  float* pp = prod + (size_t)i*64;
#pragma unroll
  for (int q=0;q<32;q++){
    float sn, cn; __sincosf(omega[q]*S, &sn, &cn);
    pp[q*2]   = decF*cn;
    pp[q*2+1] = decF*sn;
  }
}

// ---------------- scan phase 1: per (bh, chunk), local scan from zero state; store end state ----
// hend layout: ((bh*16+c)*256 + tid)*32 + 4*j4 + {0..3} = {h1[2j4], h2[2j4], h1[2j4+1], h2[2j4+1]}
__global__ __launch_bounds__(256) void k_scan_p1(const u16* __restrict__ xz, const u16* __restrict__ bcb,
    const float* __restrict__ scal2, const float* __restrict__ cst, const float* __restrict__ sst,
    float* __restrict__ hend)
{
  int bc_ = blockIdx.x;               // bh*16 + c
  int bh = bc_ >> 4, c = bc_ & 15;
  int b = bh >> 4, h = bh & 15;
  int t = threadIdx.x, p = t>>1, half = t&1, q0 = half*16;
  int t0 = c*T_CH;
  float h1[16], h2[16], B1p[16], B2p[16];
#pragma unroll
  for (int j=0;j<16;j++){ h1[j]=0.f; h2[j]=0.f; }
  float xprev = 0.f;
  size_t rowbase = (size_t)b*nL + t0;
  const u16* xp = xz + rowbase*4096 + h*128 + p;
  const u16* Bp = bcb + rowbase*2048 + h*64 + q0;
  const float* sc = scal2 + (rowbase*16 + h)*2;
  const float* cp = cst + (rowbase*16 + h)*32 + q0;
  const float* sp = sst + (rowbase*16 + h)*32 + q0;
  if (c){
    xprev = bf2f(xp[-4096]);
    unp8(*(const uint4*)(Bp-2048),    B1p);  unp8(*(const uint4*)(Bp-2048+8),  B1p+8);
    unp8(*(const uint4*)(Bp-2048+32), B2p);  unp8(*(const uint4*)(Bp-2048+40), B2p+8);
  } else {
#pragma unroll
    for (int j=0;j<16;j++){ B1p[j]=0.f; B2p[j]=0.f; }
  }
  for (int l=0; l<T_CH; l++){
    float dec = sc[0], hdt = sc[1];
    float xv = bf2f(*xp);
    float dxp = dec * xprev;
    float Bn1[16], Bn2[16], cv[16], sv[16];
    unp8(*(const uint4*)(Bp),    Bn1);  unp8(*(const uint4*)(Bp+8),    Bn1+8);
    unp8(*(const uint4*)(Bp+32), Bn2);  unp8(*(const uint4*)(Bp+40),   Bn2+8);
#pragma unroll
    for (int j4=0;j4<4;j4++){
      v4f c4 = *(const v4f*)(cp + 4*j4);
      v4f s4 = *(const v4f*)(sp + 4*j4);
#pragma unroll
      for (int j=0;j<4;j++){ cv[4*j4+j]=c4[j]; sv[4*j4+j]=s4[j]; }
    }
#pragma unroll
    for (int j=0;j<16;j++){
      float cc = cv[j], ss = sv[j];
      float rh1 = h1[j]*cc - h2[j]*ss;
      float rh2 = h1[j]*ss + h2[j]*cc;
      float rb1 = B1p[j]*cc - B2p[j]*ss;
      float rb2 = B1p[j]*ss + B2p[j]*cc;
      h1[j] = fmaf(dec, rh1, hdt*fmaf(dxp, rb1, xv*Bn1[j]));
      h2[j] = fmaf(dec, rh2, hdt*fmaf(dxp, rb2, xv*Bn2[j]));
      B1p[j]=Bn1[j]; B2p[j]=Bn2[j];
    }
    xprev = xv;
    xp += 4096; Bp += 2048; sc += 32; cp += 512; sp += 512;
  }
  float* hp = hend + ((size_t)bc_*256 + t)*32;
#pragma unroll
  for (int j4=0;j4<8;j4++){
    v4f o = { h1[2*j4], h2[2*j4], h1[2*j4+1], h2[2*j4+1] };
    *(v4f*)(hp + 4*j4) = o;
  }
}

// ---------------- scan phase 2: propagate carries across chunks (serial depth 16) -------------
// In-place: hend[bh][c] is read (local end state), then overwritten with the carry-IN for chunk c.
__global__ __launch_bounds__(256) void k_scan_p2(float* __restrict__ hend, const float* __restrict__ prod)
{
  int bh = blockIdx.x, t = threadIdx.x, half = t&1;
  float c1[16], c2[16];
#pragma unroll
  for (int j=0;j<16;j++){ c1[j]=0.f; c2[j]=0.f; }
  for (int c=0;c<C_CH;c++){
    float* hp = hend + (((size_t)(bh*16+c))*256 + t)*32;
    const float* pp = prod + (size_t)(bh*16+c)*64 + half*32;
    float t1[16], t2[16];
#pragma unroll
    for (int j4=0;j4<8;j4++){
      v4f r = *(const v4f*)(hp + 4*j4);
      t1[2*j4]=r[0]; t2[2*j4]=r[1]; t1[2*j4+1]=r[2]; t2[2*j4+1]=r[3];
    }
#pragma unroll
    for (int j4=0;j4<8;j4++){
      v4f o = { c1[2*j4], c2[2*j4], c1[2*j4+1], c2[2*j4+1] };
      *(v4f*)(hp + 4*j4) = o;
    }
#pragma unroll
    for (int j=0;j<16;j++){
      float pr = pp[2*j], pi = pp[2*j+1];
      float n1 = fmaf(pr, c1[j], fmaf(-pi, c2[j], t1[j]));
      float n2 = fmaf(pr, c2[j], fmaf( pi, c1[j], t2[j]));
      c1[j]=n1; c2[j]=n2;
    }
  }
}

// ---------------- scan phase 3: re-run chunk with correct carry-in; produce y -----------------
__global__ __launch_bounds__(256) void k_scan_p3(const u16* __restrict__ xz, const u16* __restrict__ bcb,
    const float* __restrict__ scal2, const float* __restrict__ cst, const float* __restrict__ sst,
    const float* __restrict__ Dsk, const float* __restrict__ hcar, float* __restrict__ y)
{
  int bc_ = blockIdx.x;               // bh*16 + c
  int bh = bc_ >> 4, c = bc_ & 15;
  int b = bh >> 4, h = bh & 15;
  int t = threadIdx.x, p = t>>1, half = t&1, q0 = half*16;
  int t0 = c*T_CH;
  float h1[16], h2[16], B1p[16], B2p[16];
  const float* hp0 = hcar + ((size_t)bc_*256 + t)*32;
#pragma unroll
  for (int j4=0;j4<8;j4++){
    v4f r = *(const v4f*)(hp0 + 4*j4);
    h1[2*j4]=r[0]; h2[2*j4]=r[1]; h1[2*j4+1]=r[2]; h2[2*j4+1]=r[3];
  }
  float xprev = 0.f;
  float Dskip = Dsk[h];
  size_t rowbase = (size_t)b*nL + t0;
  const u16* xp = xz + rowbase*4096 + h*128 + p;
  const u16* Bp = bcb + rowbase*2048 + h*64 + q0;
  const u16* Cp = Bp + 1024;
  const float* sc = scal2 + (rowbase*16 + h)*2;
  const float* cp = cst + (rowbase*16 + h)*32 + q0;
  const float* sp = sst + (rowbase*16 + h)*32 + q0;
  float* yp = y + rowbase*2048 + h*128 + p;
  if (c){
    xprev = bf2f(xp[-4096]);
    unp8(*(const uint4*)(Bp-2048),    B1p);  unp8(*(const uint4*)(Bp-2048+8),  B1p+8);
    unp8(*(const uint4*)(Bp-2048+32), B2p);  unp8(*(const uint4*)(Bp-2048+40), B2p+8);
  } else {
#pragma unroll
    for (int j=0;j<16;j++){ B1p[j]=0.f; B2p[j]=0.f; }
  }
  for (int l=0; l<T_CH; l++){
    float dec = sc[0], hdt = sc[1];
    float xv = bf2f(*xp);
    float dxp = dec * xprev;
    float Bn1[16], Bn2[16], Cn1[16], Cn2[16], cv[16], sv[16];
    unp8(*(const uint4*)(Bp),    Bn1);  unp8(*(const uint4*)(Bp+8),    Bn1+8);
    unp8(*(const uint4*)(Bp+32), Bn2);  unp8(*(const uint4*)(Bp+40),   Bn2+8);
    unp8(*(const uint4*)(Cp),    Cn1);  unp8(*(const uint4*)(Cp+8),    Cn1+8);
    unp8(*(const uint4*)(Cp+32), Cn2);  unp8(*(const uint4*)(Cp+40),   Cn2+8);
#pragma unroll
    for (int j4=0;j4<4;j4++){
      v4f c4 = *(const v4f*)(cp + 4*j4);
      v4f s4 = *(const v4f*)(sp + 4*j4);
#pragma unroll
      for (int j=0;j<4;j++){ cv[4*j4+j]=c4[j]; sv[4*j4+j]=s4[j]; }
    }
    float yacc = 0.f;
#pragma unroll
    for (int j=0;j<16;j++){
      float cc = cv[j], ss = sv[j];
      float rh1 = h1[j]*cc - h2[j]*ss;
      float rh2 = h1[j]*ss + h2[j]*cc;
      float rb1 = B1p[j]*cc - B2p[j]*ss;
      float rb2 = B1p[j]*ss + B2p[j]*cc;
      float nh1 = fmaf(dec, rh1, hdt*fmaf(dxp, rb1, xv*Bn1[j]));
      float nh2 = fmaf(dec, rh2, hdt*fmaf(dxp, rb2, xv*Bn2[j]));
      h1[j]=nh1; h2[j]=nh2;
      B1p[j]=Bn1[j]; B2p[j]=Bn2[j];
      yacc = fmaf(nh1, Cn1[j], fmaf(nh2, Cn2[j], yacc));
    }
    xprev = xv;
    yacc += __shfl_xor(yacc, 1);
    if (half==0) *yp = fmaf(xv, Dskip, yacc);
    xp += 4096; Bp += 2048; Cp += 2048; sc += 32; cp += 512; sp += 512; yp += 2048;
  }
}

// ---------------- direct scan (fallback if workspace too small): exact reference recurrence ---
__global__ __launch_bounds__(256) void k_scan_direct(const u16* __restrict__ xz, const u16* __restrict__ bcb,
    const float* __restrict__ scal2, const float* __restrict__ cst, const float* __restrict__ sst,
    const float* __restrict__ Dsk, float* __restrict__ y)
{
  int bh = blockIdx.x; int b = bh>>4, h = bh&15;
  int t = threadIdx.x, p = t>>1, half = t&1, q0 = half*16;
  float h1[16], h2[16], B1p[16], B2p[16];
#pragma unroll
  for (int j=0;j<16;j++){ h1[j]=0.f; h2[j]=0.f; B1p[j]=0.f; B2p[j]=0.f; }
  float xprev = 0.f;
  float Dskip = Dsk[h];
  size_t rowbase = (size_t)b*nL;
  const u16* xp = xz + rowbase*4096 + h*128 + p;
  const u16* Bp = bcb + rowbase*2048 + h*64 + q0;
  const u16* Cp = Bp + 1024;
  const float* sc = scal2 + (rowbase*16 + h)*2;
  const float* cp = cst + (rowbase*16 + h)*32 + q0;
  const float* sp = sst + (rowbase*16 + h)*32 + q0;
  float* yp = y + rowbase*2048 + h*128 + p;
  for (int l=0; l<nL; l++){
    float dec = sc[0], hdt = sc[1];
    float xv = bf2f(*xp);
    float dxp = dec * xprev;
    float Bn1[16], Bn2[16], Cn1[16], Cn2[16], cv[16], sv[16];
    unp8(*(const uint4*)(Bp),    Bn1);  unp8(*(const uint4*)(Bp+8),    Bn1+8);
    unp8(*(const uint4*)(Bp+32), Bn2);  unp8(*(const uint4*)(Bp+40),   Bn2+8);
    unp8(*(const uint4*)(Cp),    Cn1);  unp8(*(const uint4*)(Cp+8),    Cn1+8);
    unp8(*(const uint4*)(Cp+32), Cn2);  unp8(*(const uint4*)(Cp+40),   Cn2+8);
#pragma unroll
    for (int j4=0;j4<4;j4++){
      v4f c4 = *(const v4f*)(cp + 4*j4);
      v4f s4 = *(const v4f*)(sp + 4*j4);
#pragma unroll
      for (int j=0;j<4;j++){ cv[4*j4+j]=c4[j]; sv[4*j4+j]=s4[j]; }
    }
    float yacc = 0.f;
#pragma unroll
    for (int j=0;j<16;j++){
      float c = cv[j], s = sv[j];
      float rh1 = h1[j]*c - h2[j]*s;
      float rh2 = h1[j]*s + h2[j]*c;
      float rb1 = B1p[j]*c - B2p[j]*s;
      float rb2 = B1p[j]*s + B2p[j]*c;
      float nh1 = fmaf(dec, rh1, hdt*fmaf(dxp, rb1, xv*Bn1[j]));
      float nh2 = fmaf(dec, rh2, hdt*fmaf(dxp, rb2, xv*Bn2[j]));
      h1[j]=nh1; h2[j]=nh2;
      B1p[j]=Bn1[j]; B2p[j]=Bn2[j];
      yacc = fmaf(nh1, Cn1[j], fmaf(nh2, Cn2[j], yacc));
    }
    xprev = xv;
    yacc += __shfl_xor(yacc, 1);
    if (half==0) *yp = fmaf(xv, Dskip, yacc);
    xp += 4096; Bp += 2048; Cp += 2048; sc += 32; cp += 512; sp += 512; yp += 2048;
  }
}

// ---------------- gate: g = y * silu(z)  -> bf16 (internal) ----------------
__global__ void k_gate(const float* __restrict__ y, const u16* __restrict__ xz, u16* __restrict__ gbuf){
  int e0 = (blockIdx.x*256 + threadIdx.x)*4;
  int rw = e0 >> 11, col = e0 & 2047;
  v4f yv = *(const v4f*)(y + e0);
  v4f zv = unp4(*(const ushort4*)(xz + (size_t)rw*4096 + 2048 + col));
  ushort4 ob;
  float z0=zv[0], z1=zv[1], z2=zv[2], z3=zv[3];
  ob.x = f2bf(yv[0]*z0/(1.f+expf(-z0)));
  ob.y = f2bf(yv[1]*z1/(1.f+expf(-z1)));
  ob.z = f2bf(yv[2]*z2/(1.f+expf(-z2)));
  ob.w = f2bf(yv[3]*z3/(1.f+expf(-z3)));
  *(ushort4*)(gbuf + e0) = ob;
}

// ---------------- attention logits: attn[b,l] = q . xn[b,l] / 32 ----------------
__global__ __launch_bounds__(256) void k_attn(const float* __restrict__ xn, const float* __restrict__ q,
    float* __restrict__ attn)
{
  int wid = blockIdx.x*4 + (threadIdx.x>>6);
  int lane = threadIdx.x & 63;
  const float* xr = xn + (size_t)wid*1024 + lane*16;
  const float* qr = q + lane*16;
  float sAcc=0.f;
#pragma unroll
  for (int j4=0;j4<4;j4++){
    v4f xv = *(const v4f*)(xr + 4*j4);
    v4f qv = *(const v4f*)(qr + 4*j4);
#pragma unroll
    for (int j=0;j<4;j++) sAcc = fmaf(xv[j], qv[j], sAcc);
  }
#pragma unroll
  for (int o=1;o<64;o<<=1) sAcc += __shfl_xor(sAcc,o);
  if (lane==0) attn[wid] = sAcc*(1.f/32.f);
}

// ---------------- softmax over L + pooled[b,w] ----------------
__global__ __launch_bounds__(1024) void k_pool(const float* __restrict__ attn, const float* __restrict__ xn,
    float* __restrict__ pooled)
{
  int b = blockIdx.x, t = threadIdx.x;
  __shared__ float ash[1024];
  __shared__ float red[16];
  __shared__ float red2[16];
  float av = attn[b*1024 + t];
  float m = av;
#pragma unroll
  for (int o=1;o<64;o<<=1) m = fmaxf(m, __shfl_xor(m,o));
  if ((t&63)==0) red[t>>6] = m;
  __syncthreads();
  float bm = red[0];
  for (int jj=1;jj<16;jj++) bm = fmaxf(bm, red[jj]);
  float e = expf(av - bm);
  ash[t] = e;
  float sm = e;
#pragma unroll
  for (int o=1;o<64;o<<=1) sm += __shfl_xor(sm,o);
  if ((t&63)==0) red2[t>>6] = sm;
  __syncthreads();
  float tot = 0.f;
  for (int jj=0;jj<16;jj++) tot += red2[jj];
  float inv = 1.f/tot;
  float acc = 0.f;
  for (int l=0;l<1024;l++) acc = fmaf(ash[l], xn[((size_t)b*1024 + l)*1024 + t], acc);
  pooled[(size_t)b*1024 + t] = acc*inv;
}

// ---------------- heads: 96 outputs (16 features then 80 biases), fp32 in, FP32 OUT -------
__global__ __launch_bounds__(256) void k_heads(const float* __restrict__ pooled,
    const float* __restrict__ fw, const float* __restrict__ fb,
    const float* __restrict__ bw, const float* __restrict__ bb, float* __restrict__ outp)
{
  int o = blockIdx.x, t = threadIdx.x;
  int b, j, NJ; const float *Wp, *Bp;
  if (o < 16){ b = o>>2; j = o&3; NJ = 4; Wp = fw; Bp = fb; }
  else { int oo = o-16; b = oo/20; j = oo - b*20; NJ = 20; Wp = bw; Bp = bb; }
  v4f pv = *(const v4f*)(pooled + (size_t)b*1024 + t*4);
  int w0 = t*4;
  float sAcc = pv[0]*Wp[(size_t)(w0+0)*NJ + j] + pv[1]*Wp[(size_t)(w0+1)*NJ + j]
             + pv[2]*Wp[(size_t)(w0+2)*NJ + j] + pv[3]*Wp[(size_t)(w0+3)*NJ + j];
#pragma unroll
  for (int of=1; of<64; of<<=1) sAcc += __shfl_xor(sAcc, of);
  __shared__ float red[4];
  if ((t&63)==0) red[t>>6] = sAcc;
  __syncthreads();
  if (t==0) outp[o] = red[0]+red[1]+red[2]+red[3] + Bp[j];   // fp32 output — d_out is float*
}

extern "C" void kernel_launch(void* const* d_in, const int* in_sizes, int n_in,
                              void* d_out, int out_size, void* d_ws, size_t ws_size,
                              hipStream_t stream)
{
  (void)n_in; (void)out_size;
  int base = (in_sizes[2] >= 1000000) ? 1 : 2;   // index of ln_w (mask present -> 2)
  const float* h_in   = (const float*)d_in[0];
  const float* ln_w   = (const float*)d_in[base+0];
  const float* in_w   = (const float*)d_in[base+1];
  const float* in_b   = (const float*)d_in[base+2];
  const float* dt_w   = (const float*)d_in[base+3];
  const float* dt_b   = (const float*)d_in[base+4];
  const float* bc_w   = (const float*)d_in[base+5];
  const float* bc_b   = (const float*)d_in[base+6];
  const float* A_log  = (const float*)d_in[base+7];
  const float* omega  = (const float*)d_in[base+8];
  const float* D_skip = (const float*)d_in[base+9];
  const float* out_w  = (const float*)d_in[base+10];
  const float* out_b  = (const float*)d_in[base+11];
  const float* fln_w  = (const float*)d_in[base+12];
  const float* queries= (const float*)d_in[base+13];
  const float* feat_w = (const float*)d_in[base+14];
  const float* feat_b = (const float*)d_in[base+15];
  const float* bias_w = (const float*)d_in[base+16];
  const float* bias_b = (const float*)d_in[base+17];

  char* w0 = (char*)d_ws;
  size_t off = 0;
  auto take = [&](size_t bytes)->char*{ char* pp = w0 + off; off += (bytes + 255) & ~(size_t)255; return pp; };
  u16* wT_in  = (u16*)take((size_t)4096*1024*2);
  u16* wT_bc  = (u16*)take((size_t)2048*1024*2);
  u16* wT_out = (u16*)take((size_t)1024*2048*2);
  u16* wT_dt  = (u16*)take((size_t)16*1024*2);
  float* x    = (float*)take((size_t)4194304*4);
  u16* rbf    = (u16*)take((size_t)4194304*2);
  u16* xz     = (u16*)take((size_t)16777216*2);
  u16* bcb    = (u16*)take((size_t)8388608*2);
  float* ybuf = (float*)take((size_t)8388608*4);
  u16* gbuf   = (u16*)take((size_t)8388608*2);
  float* cst  = (float*)take((size_t)2097152*4);
  float* sst  = (float*)take((size_t)2097152*4);
  float* dtraw= (float*)take((size_t)65536*4);
  float* dtarr= (float*)take((size_t)65536*4);
  float* scal2= (float*)take((size_t)65536*8);
  float* attnb= (float*)take((size_t)4096*4);
  float* pool = (float*)take((size_t)4096*4);
  size_t off_base = off;
  float* hendb= (float*)take((size_t)8388608*4);   // 64 bh x 16 chunks x 256 tid x 32 floats
  float* prodb= (float*)take((size_t)65536*4);     // 1024 x 32 complex
  if (off_base > ws_size) return;   // insufficient scratch: fail cleanly, not a fault
  bool fastscan = (off <= ws_size);
  float* xn   = ybuf;          // alias (ybuf dead after last gate)

  k_cvt<<<4096,256,0,stream>>>(h_in, x);
  for (int d=0; d<4; d++){
    k_transpose<<<dim3(128,32),256,0,stream>>>(in_w + (size_t)d*1024*4096, wT_in, 1024, 4096);
    k_transpose<<<dim3(64,32),256,0,stream>>>(bc_w + (size_t)d*1024*2048, wT_bc, 1024, 2048);
    k_transpose<<<dim3(32,64),256,0,stream>>>(out_w + (size_t)d*2048*1024, wT_out, 2048, 1024);
    k_transpose<<<dim3(1,32),256,0,stream>>>(dt_w + (size_t)d*1024*16, wT_dt, 1024, 16);
    k_rmsnorm<<<4096,256,0,stream>>>(x, ln_w + d*1024, rbf, (float*)nullptr);
    k_gemm<u16,false><<<dim3(32,32),256,0,stream>>>(rbf, wT_in, in_b + d*4096, xz, 4096, 1024);
    k_gemm<u16,false><<<dim3(16,32),256,0,stream>>>(rbf, wT_bc, bc_b + d*2048, bcb, 2048, 1024);
    k_dt<<<4096,64,0,stream>>>(rbf, wT_dt, dtraw);
    k_prep2<<<256,256,0,stream>>>(dtraw, dt_b + d*16, A_log + d*16, scal2, dtarr);
    k_cs2<<<8192,256,0,stream>>>(dtarr, omega + d*32, cst, sst);
    if (fastscan){
      k_chunkprod<<<4,256,0,stream>>>(dtarr, A_log + d*16, omega + d*32, prodb);
      k_scan_p1<<<1024,256,0,stream>>>(xz, bcb, scal2, cst, sst, hendb);
      k_scan_p2<<<64,256,0,stream>>>(hendb, prodb);
      k_scan_p3<<<1024,256,0,stream>>>(xz, bcb, scal2, cst, sst, D_skip + d*16, hendb, ybuf);
    } else {
      k_scan_direct<<<64,256,0,stream>>>(xz, bcb, scal2, cst, sst, D_skip + d*16, ybuf);
    }
    k_gate<<<8192,256,0,stream>>>(ybuf, xz, gbuf);
    k_gemm<float,true><<<dim3(8,32),256,0,stream>>>(gbuf, wT_out, out_b + d*1024, x, 1024, 2048);
  }
  k_rmsnorm<<<4096,256,0,stream>>>(x, fln_w, (u16*)nullptr, xn);
  k_attn<<<1024,256,0,stream>>>(xn, queries, attnb);
  k_pool<<<4,1024,0,stream>>>(attnb, xn, pool);
  k_heads<<<96,256,0,stream>>>(pool, feat_w, feat_b, bias_w, bias_b, (float*)d_out);
}

// Round 2
// 3029.856 us; speedup vs baseline: 1.9054x; 1.3541x over previous
//
#include <hip/hip_runtime.h>
#include <math.h>

typedef unsigned short u16;
typedef float v4f  __attribute__((ext_vector_type(4)));
typedef __bf16 v8bf __attribute__((ext_vector_type(8)));

enum { nB=4, nL=1024, nW=1024, nH=16, nN=64, nE=2048, nP=128, nNH=32, nDEPTH=4 };
enum { C_CH=32, T_CH=32 };   // chunked scan: 32 chunks of 32 steps

__device__ __forceinline__ float bf2f(u16 u){ unsigned v=((unsigned)u)<<16; return __builtin_bit_cast(float,v); }
__device__ __forceinline__ u16 f2bf(float f){ unsigned x=__builtin_bit_cast(unsigned,f); return (u16)((x + 0x7fffu + ((x>>16)&1u))>>16); }
__device__ __forceinline__ float softplus_f(float v){ return (v>15.f)? v : log1pf(expf(v)); }
__device__ __forceinline__ void unp8(uint4 u, float* f){
  f[0]=bf2f((u16)(u.x&0xffff)); f[1]=bf2f((u16)(u.x>>16));
  f[2]=bf2f((u16)(u.y&0xffff)); f[3]=bf2f((u16)(u.y>>16));
  f[4]=bf2f((u16)(u.z&0xffff)); f[5]=bf2f((u16)(u.z>>16));
  f[6]=bf2f((u16)(u.w&0xffff)); f[7]=bf2f((u16)(u.w>>16));
}

// ---------------- copy h (fp32) -> x (fp32 residual) ----------------
__global__ void k_cvt(const float* __restrict__ hsrc, float* __restrict__ x){
  int i = (blockIdx.x*256 + threadIdx.x)*4;
  *(v4f*)(x + i) = *(const v4f*)(hsrc + i);
}

// ---------------- transpose fp32 (R,C) -> bf16 (C,R) ----------------
__global__ __launch_bounds__(256) void k_transpose(const float* __restrict__ src, u16* __restrict__ dst,
    int R, int C)
{
  __shared__ u16 tl[32][36];
  int r0 = blockIdx.y*32, c0 = blockIdx.x*32;
  int tid = threadIdx.x;
  int r = tid>>3, c4 = (tid&7)*4;
  if (r0 + r < R){
#pragma unroll
    for (int jj=0;jj<4;jj++){
      int c = c0 + c4 + jj;
      tl[r][c4+jj] = (c < C) ? f2bf(src[(size_t)(r0+r)*C + c]) : (u16)0;
    }
  }
  __syncthreads();
  int c = tid>>3, r4 = (tid&7)*4;
  if (c0 + c < C){
#pragma unroll
    for (int jj=0;jj<4;jj++){
      int rr = r0 + r4 + jj;
      if (rr < R) dst[(size_t)(c0+c)*R + rr] = tl[r4+jj][c];
    }
  }
}

// ---------------- rmsnorm: x(fp32) * w(fp32) -> bf16 and/or fp32 ----------------
__global__ __launch_bounds__(256) void k_rmsnorm(const float* __restrict__ x, const float* __restrict__ w,
    u16* __restrict__ obf, float* __restrict__ of32)
{
  int row = blockIdx.x, tid = threadIdx.x;
  const float* xr = x + (size_t)row*1024;
  v4f v = *(const v4f*)(xr + tid*4);
  float ss = v[0]*v[0]+v[1]*v[1]+v[2]*v[2]+v[3]*v[3];
#pragma unroll
  for (int o=1;o<64;o<<=1) ss += __shfl_xor(ss,o);
  __shared__ float red[4];
  if ((tid&63)==0) red[tid>>6] = ss;
  __syncthreads();
  float tot = red[0]+red[1]+red[2]+red[3];
  float rms = rsqrtf(tot*(1.f/1024.f) + 1e-6f);
  v4f wv = *(const v4f*)(w + tid*4);
  float o0=v[0]*rms*wv[0], o1=v[1]*rms*wv[1], o2=v[2]*rms*wv[2], o3=v[3]*rms*wv[3];
  if (obf){
    ushort4 ob = { f2bf(o0), f2bf(o1), f2bf(o2), f2bf(o3) };
    *(ushort4*)(obf + (size_t)row*1024 + tid*4) = ob;
  }
  if (of32){
    v4f ov = {o0,o1,o2,o3};
    *(v4f*)(of32 + (size_t)row*1024 + tid*4) = ov;
  }
}

// ---------------- MFMA GEMM: C = A(MxK,bf16) @ BT(NxK,bf16)^T + bias(fp32); OT float(+=) or u16
template<typename OT, bool ADD>
__global__ __launch_bounds__(256) void k_gemm(const u16* __restrict__ A, const u16* __restrict__ BT,
    const float* __restrict__ bias, OT* __restrict__ C, int N, int K)
{
  __shared__ u16 As[128*40];
  __shared__ u16 Bs[128*40];
  const int tid = threadIdx.x;
  const int wave = tid>>6, lane = tid&63, quad = lane>>4, l15 = lane&15;
  const int bm = blockIdx.y*128, bn = blockIdx.x*128;
  const int wm = (wave>>1)*64, wn = (wave&1)*64;
  v4f acc[4][4];
#pragma unroll
  for (int i=0;i<4;i++)
#pragma unroll
    for (int j=0;j<4;j++){ v4f z = {0.f,0.f,0.f,0.f}; acc[i][j]=z; }

  for (int k0=0; k0<K; k0+=32){
    uint4 av[2], bv[2];
#pragma unroll
    for (int i=0;i<2;i++){
      int c = 2*tid+i, row = c>>2, pos = c&3;
      av[i] = *(const uint4*)(A  + (size_t)(bm+row)*K + k0 + pos*8);
      bv[i] = *(const uint4*)(BT + (size_t)(bn+row)*K + k0 + pos*8);
    }
    __syncthreads();
#pragma unroll
    for (int i=0;i<2;i++){
      int c = 2*tid+i, row = c>>2, pos = c&3;
      *(uint4*)(As + row*40 + pos*8) = av[i];
      *(uint4*)(Bs + row*40 + pos*8) = bv[i];
    }
    __syncthreads();
    v8bf af[4], bfr[4];
#pragma unroll
    for (int mi=0;mi<4;mi++) af[mi]  = *(const v8bf*)(As + (wm+mi*16+l15)*40 + quad*8);
#pragma unroll
    for (int ni=0;ni<4;ni++) bfr[ni] = *(const v8bf*)(Bs + (wn+ni*16+l15)*40 + quad*8);
#pragma unroll
    for (int mi=0;mi<4;mi++)
#pragma unroll
      for (int ni=0;ni<4;ni++)
        acc[mi][ni] = __builtin_amdgcn_mfma_f32_16x16x32_bf16(af[mi], bfr[ni], acc[mi][ni], 0,0,0);
  }
#pragma unroll
  for (int ni=0;ni<4;ni++){
    int col = bn + wn + ni*16 + l15;
    float bz = bias[col];
#pragma unroll
    for (int mi=0;mi<4;mi++){
      int row = bm + wm + mi*16 + quad*4;
      v4f v = acc[mi][ni];
#pragma unroll
      for (int r=0;r<4;r++){
        size_t off = (size_t)(row+r)*N + col;
        float o = v[r] + bz;
        if constexpr (ADD) o += ((const float*)C)[off];
        if constexpr (sizeof(OT)==2) ((u16*)C)[off] = f2bf(o);
        else ((float*)C)[off] = o;
      }
    }
  }
}

// ---------------- dt matmul: dtraw(rows x 16) = r(bf16) @ dt_wT(16x1024,bf16)^T --------------
__global__ __launch_bounds__(64) void k_dt(const u16* __restrict__ r, const u16* __restrict__ dtwT,
    float* __restrict__ dtraw)
{
  int row = blockIdx.x, lane = threadIdx.x;
  const u16* rp = r + (size_t)row*1024 + lane*16;
  float rv[16];
  unp8(*(const uint4*)rp, rv);
  unp8(*(const uint4*)(rp+8), rv+8);
  float keep = 0.f;
  for (int hh=0; hh<16; hh++){
    const u16* wp = dtwT + hh*1024 + lane*16;
    float wv[16];
    unp8(*(const uint4*)wp, wv);
    unp8(*(const uint4*)(wp+8), wv+8);
    float sv = 0.f;
#pragma unroll
    for (int j=0;j<16;j++) sv = fmaf(rv[j], wv[j], sv);
#pragma unroll
    for (int o=1;o<64;o<<=1) sv += __shfl_xor(sv, o);
    if (lane==hh) keep = sv;
  }
  if (lane<16) dtraw[(size_t)row*16 + lane] = keep;
}

// ---------------- prep2 per (b,l,h): hdtb = 0.5*dt; dtarr = dt ----------------
__global__ void k_prep2(const float* __restrict__ dtraw, const float* __restrict__ dt_b,
    float* __restrict__ hdtb, float* __restrict__ dtarr)
{
  int i = blockIdx.x*256 + threadIdx.x;      // (b,l,h) h-fastest
  int h = i & 15;
  float dt0 = fminf(softplus_f(dtraw[i] + dt_b[h]), 30.f);
  hdtb[i] = 0.5f*dt0;
  dtarr[i] = dt0;
}

// ---------------- cs2: per-step dec-folded cos/sin: dcs = dec*cos, dss = dec*sin ----------------
__global__ void k_cs2(const float* __restrict__ dtarr, const float* __restrict__ omega,
    const float* __restrict__ A_log, float* __restrict__ dcst, float* __restrict__ dsst)
{
  int i = blockIdx.x*256 + threadIdx.x;   // (b,l,h,q)
  int q = i & 31, blh = i>>5, h = blh & 15;
  float dt = dtarr[blh];
  float dec = expf(-expf(A_log[h])*dt);
  float sn, cn; __sincosf(dt*omega[q], &sn, &cn);
  dcst[i]=dec*cn; dsst[i]=dec*sn;
}

// ---------------- chunk cumulative transition: prod[(bh*C+c)*64 + 2q+{0,1}] = exp(A*S)*(cos,sin)(w_q*S)
__global__ void k_chunkprod(const float* __restrict__ dtarr, const float* __restrict__ A_log,
    const float* __restrict__ omega, float* __restrict__ prod)
{
  int i = blockIdx.x*256 + threadIdx.x;   // 2048 items: (bh, c)
  int bh = i >> 5, c = i & 31;
  int b = bh >> 4, h = bh & 15;
  size_t base = ((size_t)b*nL + c*T_CH)*16 + h;
  float S = 0.f;
  for (int t=0;t<T_CH;t++) S += dtarr[base + (size_t)t*16];
  float A = -expf(A_log[h]);
  float decF = expf(A*S);
  float* pp = prod + (size_t)i*64;
#pragma unroll
  for (int q=0;q<32;q++){
    float sn, cn; __sincosf(omega[q]*S, &sn, &cn);
    pp[q*2]   = decF*cn;
    pp[q*2+1] = decF*sn;
  }
}

// ---------------- scan phase 1: per (bh, chunk), local scan from zero state; store end state ----
// hend layout: ((bh*C+c)*256 + tid)*32 + 4*j4 + {0..3} = {h1[2j4], h2[2j4], h1[2j4+1], h2[2j4+1]}
__global__ __launch_bounds__(256) void k_scan_p1(const u16* __restrict__ xz, const u16* __restrict__ bcb,
    const float* __restrict__ hdtb, const float* __restrict__ dcst, const float* __restrict__ dsst,
    float* __restrict__ hend)
{
  int bc_ = blockIdx.x;               // bh*32 + c
  int bh = bc_ >> 5, c = bc_ & 31;
  int b = bh >> 4, h = bh & 15;
  int t = threadIdx.x, p = t>>1, half = t&1, q0 = half*16;
  size_t rowbase = (size_t)b*nL + c*T_CH;
  __shared__ float sB[T_CH+1][64];
  __shared__ float sDC[T_CH][32];
  __shared__ float sDS[T_CH][32];
  for (int e=t; e<(T_CH+1)*64; e+=256){
    int l = e>>6, n = e&63;
    float v = 0.f;
    if (l) v = bf2f(bcb[(rowbase + l-1)*2048 + h*64 + n]);
    else if (c) v = bf2f(bcb[(rowbase - 1)*2048 + h*64 + n]);
    sB[l][n] = v;
  }
  for (int e=t; e<T_CH*32; e+=256){
    int l = e>>5, q = e&31;
    size_t idx = ((rowbase+l)*16 + h)*32 + q;
    sDC[l][q] = dcst[idx]; sDS[l][q] = dsst[idx];
  }
  __syncthreads();
  float h1[16], h2[16];
#pragma unroll
  for (int j=0;j<16;j++){ h1[j]=0.f; h2[j]=0.f; }
  float xprev = c ? bf2f(xz[(rowbase-1)*4096 + h*128 + p]) : 0.f;
  const u16* xp = xz + rowbase*4096 + h*128 + p;
  const float* scp = hdtb + rowbase*16 + h;
  for (int l=0; l<T_CH; l++){
    float hdt = *scp;
    float xv = bf2f(*xp);
    float a = hdt*xprev, bb = hdt*xv;
#pragma unroll
    for (int j4=0;j4<4;j4++){
      v4f Bp1 = *(const v4f*)&sB[l][q0+4*j4];
      v4f Bp2 = *(const v4f*)&sB[l][32+q0+4*j4];
      v4f Bn1 = *(const v4f*)&sB[l+1][q0+4*j4];
      v4f Bn2 = *(const v4f*)&sB[l+1][32+q0+4*j4];
      v4f dc  = *(const v4f*)&sDC[l][q0+4*j4];
      v4f dsn = *(const v4f*)&sDS[l][q0+4*j4];
#pragma unroll
      for (int j=0;j<4;j++){
        int jj = 4*j4+j;
        float m1 = fmaf(a, Bp1[j], h1[jj]);
        float m2 = fmaf(a, Bp2[j], h2[jj]);
        h1[jj] = fmaf(bb, Bn1[j], fmaf(-m2, dsn[j], m1*dc[j]));
        h2[jj] = fmaf(bb, Bn2[j], fmaf( m1, dsn[j], m2*dc[j]));
      }
    }
    xprev = xv;
    xp += 4096; scp += 16;
  }
  float* hp = hend + ((size_t)bc_*256 + t)*32;
#pragma unroll
  for (int j4=0;j4<8;j4++){
    v4f o = { h1[2*j4], h2[2*j4], h1[2*j4+1], h2[2*j4+1] };
    *(v4f*)(hp + 4*j4) = o;
  }
}

// ---------------- scan phase 2: propagate carries across chunks (serial depth 32) -------------
__global__ __launch_bounds__(256) void k_scan_p2(float* __restrict__ hend, const float* __restrict__ prod)
{
  int bh = blockIdx.x, t = threadIdx.x, half = t&1;
  float c1[16], c2[16];
#pragma unroll
  for (int j=0;j<16;j++){ c1[j]=0.f; c2[j]=0.f; }
  for (int c=0;c<C_CH;c++){
    float* hp = hend + (((size_t)(bh*C_CH+c))*256 + t)*32;
    const float* pp = prod + (size_t)(bh*C_CH+c)*64 + half*32;
    float t1[16], t2[16];
#pragma unroll
    for (int j4=0;j4<8;j4++){
      v4f r = *(const v4f*)(hp + 4*j4);
      t1[2*j4]=r[0]; t2[2*j4]=r[1]; t1[2*j4+1]=r[2]; t2[2*j4+1]=r[3];
    }
#pragma unroll
    for (int j4=0;j4<8;j4++){
      v4f o = { c1[2*j4], c2[2*j4], c1[2*j4+1], c2[2*j4+1] };
      *(v4f*)(hp + 4*j4) = o;
    }
#pragma unroll
    for (int j=0;j<16;j++){
      float pr = pp[2*j], pi = pp[2*j+1];
      float n1 = fmaf(pr, c1[j], fmaf(-pi, c2[j], t1[j]));
      float n2 = fmaf(pr, c2[j], fmaf( pi, c1[j], t2[j]));
      c1[j]=n1; c2[j]=n2;
    }
  }
}

// ---------------- scan phase 3: re-run chunk with carry-in; fused D-skip + gate -> gbuf bf16 --
__global__ __launch_bounds__(256) void k_scan_p3(const u16* __restrict__ xz, const u16* __restrict__ bcb,
    const float* __restrict__ hdtb, const float* __restrict__ dcst, const float* __restrict__ dsst,
    const float* __restrict__ Dsk, const float* __restrict__ hcar, u16* __restrict__ gbuf)
{
  int bc_ = blockIdx.x;               // bh*32 + c
  int bh = bc_ >> 5, c = bc_ & 31;
  int b = bh >> 4, h = bh & 15;
  int t = threadIdx.x, p = t>>1, half = t&1, q0 = half*16;
  size_t rowbase = (size_t)b*nL + c*T_CH;
  __shared__ float sB[T_CH+1][64];
  __shared__ float sC[T_CH][64];
  __shared__ float sDC[T_CH][32];
  __shared__ float sDS[T_CH][32];
  for (int e=t; e<(T_CH+1)*64; e+=256){
    int l = e>>6, n = e&63;
    float v = 0.f;
    if (l) v = bf2f(bcb[(rowbase + l-1)*2048 + h*64 + n]);
    else if (c) v = bf2f(bcb[(rowbase - 1)*2048 + h*64 + n]);
    sB[l][n] = v;
  }
  for (int e=t; e<T_CH*64; e+=256){
    int l = e>>6, n = e&63;
    sC[l][n] = bf2f(bcb[(rowbase + l)*2048 + 1024 + h*64 + n]);
  }
  for (int e=t; e<T_CH*32; e+=256){
    int l = e>>5, q = e&31;
    size_t idx = ((rowbase+l)*16 + h)*32 + q;
    sDC[l][q] = dcst[idx]; sDS[l][q] = dsst[idx];
  }
  __syncthreads();
  float h1[16], h2[16];
  const float* hp0 = hcar + ((size_t)bc_*256 + t)*32;
#pragma unroll
  for (int j4=0;j4<8;j4++){
    v4f r = *(const v4f*)(hp0 + 4*j4);
    h1[2*j4]=r[0]; h2[2*j4]=r[1]; h1[2*j4+1]=r[2]; h2[2*j4+1]=r[3];
  }
  float xprev = c ? bf2f(xz[(rowbase-1)*4096 + h*128 + p]) : 0.f;
  float Dskip = Dsk[h];
  const u16* xp = xz + rowbase*4096 + h*128 + p;
  const u16* zp = xz + rowbase*4096 + 2048 + h*128 + p;
  const float* scp = hdtb + rowbase*16 + h;
  u16* gp = gbuf + rowbase*2048 + h*128 + p;
  for (int l=0; l<T_CH; l++){
    float hdt = *scp;
    float xv = bf2f(*xp);
    float a = hdt*xprev, bb = hdt*xv;
    float yacc = 0.f;
#pragma unroll
    for (int j4=0;j4<4;j4++){
      v4f Bp1 = *(const v4f*)&sB[l][q0+4*j4];
      v4f Bp2 = *(const v4f*)&sB[l][32+q0+4*j4];
      v4f Bn1 = *(const v4f*)&sB[l+1][q0+4*j4];
      v4f Bn2 = *(const v4f*)&sB[l+1][32+q0+4*j4];
      v4f C1  = *(const v4f*)&sC[l][q0+4*j4];
      v4f C2  = *(const v4f*)&sC[l][32+q0+4*j4];
      v4f dc  = *(const v4f*)&sDC[l][q0+4*j4];
      v4f dsn = *(const v4f*)&sDS[l][q0+4*j4];
#pragma unroll
      for (int j=0;j<4;j++){
        int jj = 4*j4+j;
        float m1 = fmaf(a, Bp1[j], h1[jj]);
        float m2 = fmaf(a, Bp2[j], h2[jj]);
        float nh1 = fmaf(bb, Bn1[j], fmaf(-m2, dsn[j], m1*dc[j]));
        float nh2 = fmaf(bb, Bn2[j], fmaf( m1, dsn[j], m2*dc[j]));
        h1[jj]=nh1; h2[jj]=nh2;
        yacc = fmaf(nh1, C1[j], fmaf(nh2, C2[j], yacc));
      }
    }
    xprev = xv;
    yacc += __shfl_xor(yacc, 1);
    if (half==0){
      float yv = fmaf(xv, Dskip, yacc);
      float zv = bf2f(*zp);
      float g = yv*zv/(1.f+expf(-zv));
      *gp = f2bf(g);
    }
    xp += 4096; zp += 4096; scp += 16; gp += 2048;
  }
}

// ---------------- attention logits: attn[b,l] = q . xn[b,l] / 32 ----------------
__global__ __launch_bounds__(256) void k_attn(const float* __restrict__ xn, const float* __restrict__ q,
    float* __restrict__ attn)
{
  int wid = blockIdx.x*4 + (threadIdx.x>>6);
  int lane = threadIdx.x & 63;
  const float* xr = xn + (size_t)wid*1024 + lane*16;
  const float* qr = q + lane*16;
  float sAcc=0.f;
#pragma unroll
  for (int j4=0;j4<4;j4++){
    v4f xv = *(const v4f*)(xr + 4*j4);
    v4f qv = *(const v4f*)(qr + 4*j4);
#pragma unroll
    for (int j=0;j<4;j++) sAcc = fmaf(xv[j], qv[j], sAcc);
  }
#pragma unroll
  for (int o=1;o<64;o<<=1) sAcc += __shfl_xor(sAcc,o);
  if (lane==0) attn[wid] = sAcc*(1.f/32.f);
}

// ---------------- softmax over L (in place, normalized probs) ----------------
__global__ __launch_bounds__(1024) void k_smax(float* __restrict__ attn)
{
  int b = blockIdx.x, t = threadIdx.x;
  __shared__ float red[16];
  __shared__ float red2[16];
  float av = attn[b*1024 + t];
  float m = av;
#pragma unroll
  for (int o=1;o<64;o<<=1) m = fmaxf(m, __shfl_xor(m,o));
  if ((t&63)==0) red[t>>6] = m;
  __syncthreads();
  float bm = red[0];
  for (int jj=1;jj<16;jj++) bm = fmaxf(bm, red[jj]);
  float e = expf(av - bm);
  float sm = e;
#pragma unroll
  for (int o=1;o<64;o<<=1) sm += __shfl_xor(sm,o);
  if ((t&63)==0) red2[t>>6] = sm;
  __syncthreads();
  float tot = 0.f;
  for (int jj=0;jj<16;jj++) tot += red2[jj];
  attn[b*1024 + t] = e/tot;
}

// ---------------- pooled[b,w] = sum_l p[l] * xn[b,l,w], parallel over w slices ----------------
__global__ __launch_bounds__(256) void k_pool2(const float* __restrict__ attnp, const float* __restrict__ xn,
    float* __restrict__ pooled)
{
  int wsl = blockIdx.x, b = blockIdx.y, t = threadIdx.x;
  int w = wsl*64 + (t&63), ls = t>>6;
  float acc = 0.f;
  for (int l=ls; l<1024; l+=4)
    acc = fmaf(attnp[b*1024 + l], xn[((size_t)b*1024 + l)*1024 + w], acc);
  __shared__ float red[256];
  red[t] = acc;
  __syncthreads();
  if (t<64)
    pooled[(size_t)b*1024 + wsl*64 + t] = red[t]+red[t+64]+red[t+128]+red[t+192];
}

// ---------------- heads: 96 outputs (16 features then 80 biases), fp32 in, FP32 OUT -------
__global__ __launch_bounds__(256) void k_heads(const float* __restrict__ pooled,
    const float* __restrict__ fw, const float* __restrict__ fb,
    const float* __restrict__ bw, const float* __restrict__ bb, float* __restrict__ outp)
{
  int o = blockIdx.x, t = threadIdx.x;
  int b, j, NJ; const float *Wp, *Bp;
  if (o < 16){ b = o>>2; j = o&3; NJ = 4; Wp = fw; Bp = fb; }
  else { int oo = o-16; b = oo/20; j = oo - b*20; NJ = 20; Wp = bw; Bp = bb; }
  v4f pv = *(const v4f*)(pooled + (size_t)b*1024 + t*4);
  int w0 = t*4;
  float sAcc = pv[0]*Wp[(size_t)(w0+0)*NJ + j] + pv[1]*Wp[(size_t)(w0+1)*NJ + j]
             + pv[2]*Wp[(size_t)(w0+2)*NJ + j] + pv[3]*Wp[(size_t)(w0+3)*NJ + j];
#pragma unroll
  for (int of=1; of<64; of<<=1) sAcc += __shfl_xor(sAcc, of);
  __shared__ float red[4];
  if ((t&63)==0) red[t>>6] = sAcc;
  __syncthreads();
  if (t==0) outp[o] = red[0]+red[1]+red[2]+red[3] + Bp[j];   // fp32 output — d_out is float*
}

extern "C" void kernel_launch(void* const* d_in, const int* in_sizes, int n_in,
                              void* d_out, int out_size, void* d_ws, size_t ws_size,
                              hipStream_t stream)
{
  (void)n_in; (void)out_size;
  int base = (in_sizes[2] >= 1000000) ? 1 : 2;   // index of ln_w (mask present -> 2)
  const float* h_in   = (const float*)d_in[0];
  const float* ln_w   = (const float*)d_in[base+0];
  const float* in_w   = (const float*)d_in[base+1];
  const float* in_b   = (const float*)d_in[base+2];
  const float* dt_w   = (const float*)d_in[base+3];
  const float* dt_b   = (const float*)d_in[base+4];
  const float* bc_w   = (const float*)d_in[base+5];
  const float* bc_b   = (const float*)d_in[base+6];
  const float* A_log  = (const float*)d_in[base+7];
  const float* omega  = (const float*)d_in[base+8];
  const float* D_skip = (const float*)d_in[base+9];
  const float* out_w  = (const float*)d_in[base+10];
  const float* out_b  = (const float*)d_in[base+11];
  const float* fln_w  = (const float*)d_in[base+12];
  const float* queries= (const float*)d_in[base+13];
  const float* feat_w = (const float*)d_in[base+14];
  const float* feat_b = (const float*)d_in[base+15];
  const float* bias_w = (const float*)d_in[base+16];
  const float* bias_b = (const float*)d_in[base+17];

  char* w0 = (char*)d_ws;
  size_t off = 0;
  auto take = [&](size_t bytes)->char*{ char* pp = w0 + off; off += (bytes + 255) & ~(size_t)255; return pp; };
  u16* wT_in  = (u16*)take((size_t)4096*1024*2);
  u16* wT_bc  = (u16*)take((size_t)2048*1024*2);
  u16* wT_out = (u16*)take((size_t)1024*2048*2);
  u16* wT_dt  = (u16*)take((size_t)16*1024*2);
  float* x    = (float*)take((size_t)4194304*4);
  u16* rbf    = (u16*)take((size_t)4194304*2);
  u16* xz     = (u16*)take((size_t)16777216*2);
  u16* bcb    = (u16*)take((size_t)8388608*2);
  char* bigscratch = take((size_t)67108864);     // hendb (64MB) during scan; xn (16MB) after
  u16* gbuf   = (u16*)take((size_t)8388608*2);
  float* cst  = (float*)take((size_t)2097152*4);
  float* sst  = (float*)take((size_t)2097152*4);
  float* dtraw= (float*)take((size_t)65536*4);
  float* dtarr= (float*)take((size_t)65536*4);
  float* hdtb = (float*)take((size_t)65536*4);
  float* attnb= (float*)take((size_t)4096*4);
  float* pool = (float*)take((size_t)4096*4);
  float* prodb= (float*)take((size_t)2048*64*4);   // 2048 x 32 complex
  if (off > ws_size) return;   // insufficient scratch: fail cleanly, not a fault
  float* hendb = (float*)bigscratch;
  float* xn    = (float*)bigscratch;   // alias (hendb dead after last p3)

  k_cvt<<<4096,256,0,stream>>>(h_in, x);
  for (int d=0; d<4; d++){
    k_transpose<<<dim3(128,32),256,0,stream>>>(in_w + (size_t)d*1024*4096, wT_in, 1024, 4096);
    k_transpose<<<dim3(64,32),256,0,stream>>>(bc_w + (size_t)d*1024*2048, wT_bc, 1024, 2048);
    k_transpose<<<dim3(32,64),256,0,stream>>>(out_w + (size_t)d*2048*1024, wT_out, 2048, 1024);
    k_transpose<<<dim3(1,32),256,0,stream>>>(dt_w + (size_t)d*1024*16, wT_dt, 1024, 16);
    k_rmsnorm<<<4096,256,0,stream>>>(x, ln_w + d*1024, rbf, (float*)nullptr);
    k_gemm<u16,false><<<dim3(32,32),256,0,stream>>>(rbf, wT_in, in_b + d*4096, xz, 4096, 1024);
    k_gemm<u16,false><<<dim3(16,32),256,0,stream>>>(rbf, wT_bc, bc_b + d*2048, bcb, 2048, 1024);
    k_dt<<<4096,64,0,stream>>>(rbf, wT_dt, dtraw);
    k_prep2<<<256,256,0,stream>>>(dtraw, dt_b + d*16, hdtb, dtarr);
    k_cs2<<<8192,256,0,stream>>>(dtarr, omega + d*32, A_log + d*16, cst, sst);
    k_chunkprod<<<8,256,0,stream>>>(dtarr, A_log + d*16, omega + d*32, prodb);
    k_scan_p1<<<2048,256,0,stream>>>(xz, bcb, hdtb, cst, sst, hendb);
    k_scan_p2<<<64,256,0,stream>>>(hendb, prodb);
    k_scan_p3<<<2048,256,0,stream>>>(xz, bcb, hdtb, cst, sst, D_skip + d*16, hendb, gbuf);
    k_gemm<float,true><<<dim3(8,32),256,0,stream>>>(gbuf, wT_out, out_b + d*1024, x, 1024, 2048);
  }
  k_rmsnorm<<<4096,256,0,stream>>>(x, fln_w, (u16*)nullptr, xn);
  k_attn<<<1024,256,0,stream>>>(xn, queries, attnb);
  k_smax<<<4,1024,0,stream>>>(attnb);
  k_pool2<<<dim3(16,4),256,0,stream>>>(attnb, xn, pool);
  k_heads<<<96,256,0,stream>>>(pool, feat_w, feat_b, bias_w, bias_b, (float*)d_out);
}

// Round 3
// 2926.880 us; speedup vs baseline: 1.9724x; 1.0352x over previous
//
#include <hip/hip_runtime.h>
#include <math.h>

typedef unsigned short u16;
typedef float v4f  __attribute__((ext_vector_type(4)));
typedef __bf16 v8bf __attribute__((ext_vector_type(8)));

enum { nB=4, nL=1024, nW=1024, nH=16, nN=64, nE=2048, nP=128, nNH=32, nDEPTH=4 };
enum { C_CH=32, T_CH=32 };   // chunked scan: 32 chunks of 32 steps

__device__ __forceinline__ float bf2f(u16 u){ unsigned v=((unsigned)u)<<16; return __builtin_bit_cast(float,v); }
__device__ __forceinline__ u16 f2bf(float f){ unsigned x=__builtin_bit_cast(unsigned,f); return (u16)((x + 0x7fffu + ((x>>16)&1u))>>16); }
__device__ __forceinline__ unsigned pk2(float a, float b){ return (unsigned)f2bf(a) | ((unsigned)f2bf(b)<<16); }
__device__ __forceinline__ float softplus_f(float v){ return (v>15.f)? v : log1pf(expf(v)); }
__device__ __forceinline__ void unp8(uint4 u, float* f){
  f[0]=bf2f((u16)(u.x&0xffff)); f[1]=bf2f((u16)(u.x>>16));
  f[2]=bf2f((u16)(u.y&0xffff)); f[3]=bf2f((u16)(u.y>>16));
  f[4]=bf2f((u16)(u.z&0xffff)); f[5]=bf2f((u16)(u.z>>16));
  f[6]=bf2f((u16)(u.w&0xffff)); f[7]=bf2f((u16)(u.w>>16));
}

// ---------------- copy h (fp32) -> x (fp32 residual) ----------------
__global__ void k_cvt(const float* __restrict__ hsrc, float* __restrict__ x){
  int i = (blockIdx.x*256 + threadIdx.x)*4;
  *(v4f*)(x + i) = *(const v4f*)(hsrc + i);
}

// ---------------- transpose fp32 (R,C) -> bf16 (C,R) ----------------
__global__ __launch_bounds__(256) void k_transpose(const float* __restrict__ src, u16* __restrict__ dst,
    int R, int C)
{
  __shared__ u16 tl[32][36];
  int r0 = blockIdx.y*32, c0 = blockIdx.x*32;
  int tid = threadIdx.x;
  int r = tid>>3, c4 = (tid&7)*4;
  if (r0 + r < R){
#pragma unroll
    for (int jj=0;jj<4;jj++){
      int c = c0 + c4 + jj;
      tl[r][c4+jj] = (c < C) ? f2bf(src[(size_t)(r0+r)*C + c]) : (u16)0;
    }
  }
  __syncthreads();
  int c = tid>>3, r4 = (tid&7)*4;
  if (c0 + c < C){
#pragma unroll
    for (int jj=0;jj<4;jj++){
      int rr = r0 + r4 + jj;
      if (rr < R) dst[(size_t)(c0+c)*R + rr] = tl[r4+jj][c];
    }
  }
}

// ---------------- rmsnorm: x(fp32) * w(fp32) -> bf16 and/or fp32 ----------------
__global__ __launch_bounds__(256) void k_rmsnorm(const float* __restrict__ x, const float* __restrict__ w,
    u16* __restrict__ obf, float* __restrict__ of32)
{
  int row = blockIdx.x, tid = threadIdx.x;
  const float* xr = x + (size_t)row*1024;
  v4f v = *(const v4f*)(xr + tid*4);
  float ss = v[0]*v[0]+v[1]*v[1]+v[2]*v[2]+v[3]*v[3];
#pragma unroll
  for (int o=1;o<64;o<<=1) ss += __shfl_xor(ss,o);
  __shared__ float red[4];
  if ((tid&63)==0) red[tid>>6] = ss;
  __syncthreads();
  float tot = red[0]+red[1]+red[2]+red[3];
  float rms = rsqrtf(tot*(1.f/1024.f) + 1e-6f);
  v4f wv = *(const v4f*)(w + tid*4);
  float o0=v[0]*rms*wv[0], o1=v[1]*rms*wv[1], o2=v[2]*rms*wv[2], o3=v[3]*rms*wv[3];
  if (obf){
    ushort4 ob = { f2bf(o0), f2bf(o1), f2bf(o2), f2bf(o3) };
    *(ushort4*)(obf + (size_t)row*1024 + tid*4) = ob;
  }
  if (of32){
    v4f ov = {o0,o1,o2,o3};
    *(v4f*)(of32 + (size_t)row*1024 + tid*4) = ov;
  }
}

// ---------------- MFMA GEMM: C = A(MxK,bf16) @ BT(NxK,bf16)^T + bias(fp32)
// BK=64, reg-prefetch of next K-tile under MFMA, LDS-staged coalesced epilogue.
template<typename OT, bool ADD>
__global__ __launch_bounds__(256) void k_gemm(const u16* __restrict__ A, const u16* __restrict__ BT,
    const float* __restrict__ bias, OT* __restrict__ C, int N, int K)
{
  __shared__ __align__(16) u16 As[128*72];
  __shared__ __align__(16) u16 Bs[128*72];
  const int tid = threadIdx.x;
  const int wave = tid>>6, lane = tid&63, quad = lane>>4, l15 = lane&15;
  const int bm = blockIdx.y*128, bn = blockIdx.x*128;
  const int wm = (wave>>1)*64, wn = (wave&1)*64;
  v4f acc[4][4];
#pragma unroll
  for (int i=0;i<4;i++)
#pragma unroll
    for (int j=0;j<4;j++){ v4f z = {0.f,0.f,0.f,0.f}; acc[i][j]=z; }

  const int srow = tid>>1, shalf = tid&1;
  const u16* ag = A  + (size_t)(bm+srow)*K + shalf*32;
  const u16* bg = BT + (size_t)(bn+srow)*K + shalf*32;
  uint4 av[4], bv[4];
#pragma unroll
  for (int j=0;j<4;j++){ av[j] = *(const uint4*)(ag + j*8); bv[j] = *(const uint4*)(bg + j*8); }

  const int nk = K>>6;
  for (int k0=0; k0<nk; k0++){
    __syncthreads();                       // prior K-step's LDS reads done
#pragma unroll
    for (int j=0;j<4;j++){
      *(uint4*)(As + srow*72 + shalf*32 + j*8) = av[j];
      *(uint4*)(Bs + srow*72 + shalf*32 + j*8) = bv[j];
    }
    __syncthreads();                       // staging visible
    if (k0+1 < nk){
      ag += 64; bg += 64;
#pragma unroll
      for (int j=0;j<4;j++){ av[j] = *(const uint4*)(ag + j*8); bv[j] = *(const uint4*)(bg + j*8); }
    }
#pragma unroll
    for (int kk=0; kk<2; kk++){
      v8bf af[4], bfr[4];
#pragma unroll
      for (int mi=0;mi<4;mi++) af[mi]  = *(const v8bf*)(As + (wm+mi*16+l15)*72 + kk*32 + quad*8);
#pragma unroll
      for (int ni=0;ni<4;ni++) bfr[ni] = *(const v8bf*)(Bs + (wn+ni*16+l15)*72 + kk*32 + quad*8);
#pragma unroll
      for (int mi=0;mi<4;mi++)
#pragma unroll
        for (int ni=0;ni<4;ni++)
          acc[mi][ni] = __builtin_amdgcn_mfma_f32_16x16x32_bf16(af[mi], bfr[ni], acc[mi][ni], 0,0,0);
    }
  }

  // -------- LDS-staged epilogue: coalesced full-line stores --------
  float* eps = (float*)As;                 // 32 x 132 f32 = 16.9 KB (As is 18.4 KB)
  float bz[4];
#pragma unroll
  for (int ni=0;ni<4;ni++) bz[ni] = bias[bn + wn + ni*16 + l15];
  const int erb = (wave>>1)*16 + quad*4;
  __syncthreads();                         // all K-loop LDS reads complete
#pragma unroll
  for (int mi=0;mi<4;mi++){
#pragma unroll
    for (int ni=0;ni<4;ni++){
      v4f v = acc[mi][ni];
#pragma unroll
      for (int r=0;r<4;r++)
        eps[(erb + r)*132 + wn + ni*16 + l15] = v[r] + bz[ni];
    }
    __syncthreads();
    {
      int e = tid>>3, seg = tid&7;
      int grow = bm + (e>>4)*64 + mi*16 + (e&15);
      int gcol = bn + seg*16;
      const float* ep = eps + e*132 + seg*16;
      if constexpr (ADD){
        float* cp = (float*)C + (size_t)grow*N + gcol;
#pragma unroll
        for (int u=0;u<4;u++){
          v4f ov = *(const v4f*)(ep + 4*u);
          v4f cv = *(const v4f*)(cp + 4*u);
          ov += cv;
          *(v4f*)(cp + 4*u) = ov;
        }
      } else {
        u16* cp = (u16*)C + (size_t)grow*N + gcol;
        v4f e0 = *(const v4f*)(ep+0), e1 = *(const v4f*)(ep+4);
        v4f e2 = *(const v4f*)(ep+8), e3 = *(const v4f*)(ep+12);
        uint4 pA = { pk2(e0[0],e0[1]), pk2(e0[2],e0[3]), pk2(e1[0],e1[1]), pk2(e1[2],e1[3]) };
        uint4 pB = { pk2(e2[0],e2[1]), pk2(e2[2],e2[3]), pk2(e3[0],e3[1]), pk2(e3[2],e3[3]) };
        *(uint4*)(cp)   = pA;
        *(uint4*)(cp+8) = pB;
      }
    }
    __syncthreads();
  }
}

// ---------------- dt matmul: dtraw(rows x 16) = r(bf16) @ dt_wT(16x1024,bf16)^T --------------
__global__ __launch_bounds__(64) void k_dt(const u16* __restrict__ r, const u16* __restrict__ dtwT,
    float* __restrict__ dtraw)
{
  int row = blockIdx.x, lane = threadIdx.x;
  const u16* rp = r + (size_t)row*1024 + lane*16;
  float rv[16];
  unp8(*(const uint4*)rp, rv);
  unp8(*(const uint4*)(rp+8), rv+8);
  float keep = 0.f;
  for (int hh=0; hh<16; hh++){
    const u16* wp = dtwT + hh*1024 + lane*16;
    float wv[16];
    unp8(*(const uint4*)wp, wv);
    unp8(*(const uint4*)(wp+8), wv+8);
    float sv = 0.f;
#pragma unroll
    for (int j=0;j<16;j++) sv = fmaf(rv[j], wv[j], sv);
#pragma unroll
    for (int o=1;o<64;o<<=1) sv += __shfl_xor(sv, o);
    if (lane==hh) keep = sv;
  }
  if (lane<16) dtraw[(size_t)row*16 + lane] = keep;
}

// ---------------- prep2 per (b,l,h): hdtb = 0.5*dt; dtarr = dt ----------------
__global__ void k_prep2(const float* __restrict__ dtraw, const float* __restrict__ dt_b,
    float* __restrict__ hdtb, float* __restrict__ dtarr)
{
  int i = blockIdx.x*256 + threadIdx.x;      // (b,l,h) h-fastest
  int h = i & 15;
  float dt0 = fminf(softplus_f(dtraw[i] + dt_b[h]), 30.f);
  hdtb[i] = 0.5f*dt0;
  dtarr[i] = dt0;
}

// ---------------- cs2: per-step dec-folded cos/sin: dcs = dec*cos, dss = dec*sin ----------------
__global__ void k_cs2(const float* __restrict__ dtarr, const float* __restrict__ omega,
    const float* __restrict__ A_log, float* __restrict__ dcst, float* __restrict__ dsst)
{
  int i = blockIdx.x*256 + threadIdx.x;   // (b,l,h,q)
  int q = i & 31, blh = i>>5, h = blh & 15;
  float dt = dtarr[blh];
  float dec = expf(-expf(A_log[h])*dt);
  float sn, cn; __sincosf(dt*omega[q], &sn, &cn);
  dcst[i]=dec*cn; dsst[i]=dec*sn;
}

// ---------------- chunk cumulative transition: prod[(bh*C+c)*64 + 2q+{0,1}] = exp(A*S)*(cos,sin)(w_q*S)
__global__ void k_chunkprod(const float* __restrict__ dtarr, const float* __restrict__ A_log,
    const float* __restrict__ omega, float* __restrict__ prod)
{
  int i = blockIdx.x*256 + threadIdx.x;   // 2048 items: (bh, c)
  int bh = i >> 5, c = i & 31;
  int b = bh >> 4, h = bh & 15;
  size_t base = ((size_t)b*nL + c*T_CH)*16 + h;
  float S = 0.f;
  for (int t=0;t<T_CH;t++) S += dtarr[base + (size_t)t*16];
  float A = -expf(A_log[h]);
  float decF = expf(A*S);
  float* pp = prod + (size_t)i*64;
#pragma unroll
  for (int q=0;q<32;q++){
    float sn, cn; __sincosf(omega[q]*S, &sn, &cn);
    pp[q*2]   = decF*cn;
    pp[q*2+1] = decF*sn;
  }
}

// ---------------- scan phase 1: per (bh, chunk), local scan from zero state; store end state ----
// hend layout: ((bh*C+c)*256 + tid)*32 + 4*j4 + {0..3} = {h1[2j4], h2[2j4], h1[2j4+1], h2[2j4+1]}
__global__ __launch_bounds__(256) void k_scan_p1(const u16* __restrict__ xz, const u16* __restrict__ bcb,
    const float* __restrict__ hdtb, const float* __restrict__ dcst, const float* __restrict__ dsst,
    float* __restrict__ hend)
{
  int bc_ = blockIdx.x;               // bh*32 + c
  int bh = bc_ >> 5, c = bc_ & 31;
  int b = bh >> 4, h = bh & 15;
  int t = threadIdx.x, p = t>>1, half = t&1, q0 = half*16;
  size_t rowbase = (size_t)b*nL + c*T_CH;
  __shared__ float sB[T_CH+1][64];
  __shared__ float sDC[T_CH][32];
  __shared__ float sDS[T_CH][32];
  for (int e=t; e<(T_CH+1)*64; e+=256){
    int l = e>>6, n = e&63;
    float v = 0.f;
    if (l) v = bf2f(bcb[(rowbase + l-1)*2048 + h*64 + n]);
    else if (c) v = bf2f(bcb[(rowbase - 1)*2048 + h*64 + n]);
    sB[l][n] = v;
  }
  for (int e=t; e<T_CH*32; e+=256){
    int l = e>>5, q = e&31;
    size_t idx = ((rowbase+l)*16 + h)*32 + q;
    sDC[l][q] = dcst[idx]; sDS[l][q] = dsst[idx];
  }
  __syncthreads();
  float h1[16], h2[16];
#pragma unroll
  for (int j=0;j<16;j++){ h1[j]=0.f; h2[j]=0.f; }
  float xprev = c ? bf2f(xz[(rowbase-1)*4096 + h*128 + p]) : 0.f;
  const u16* xp = xz + rowbase*4096 + h*128 + p;
  const float* scp = hdtb + rowbase*16 + h;
  for (int l=0; l<T_CH; l++){
    float hdt = *scp;
    float xv = bf2f(*xp);
    float a = hdt*xprev, bb = hdt*xv;
#pragma unroll
    for (int j4=0;j4<4;j4++){
      v4f Bp1 = *(const v4f*)&sB[l][q0+4*j4];
      v4f Bp2 = *(const v4f*)&sB[l][32+q0+4*j4];
      v4f Bn1 = *(const v4f*)&sB[l+1][q0+4*j4];
      v4f Bn2 = *(const v4f*)&sB[l+1][32+q0+4*j4];
      v4f dc  = *(const v4f*)&sDC[l][q0+4*j4];
      v4f dsn = *(const v4f*)&sDS[l][q0+4*j4];
#pragma unroll
      for (int j=0;j<4;j++){
        int jj = 4*j4+j;
        float m1 = fmaf(a, Bp1[j], h1[jj]);
        float m2 = fmaf(a, Bp2[j], h2[jj]);
        h1[jj] = fmaf(bb, Bn1[j], fmaf(-m2, dsn[j], m1*dc[j]));
        h2[jj] = fmaf(bb, Bn2[j], fmaf( m1, dsn[j], m2*dc[j]));
      }
    }
    xprev = xv;
    xp += 4096; scp += 16;
  }
  float* hp = hend + ((size_t)bc_*256 + t)*32;
#pragma unroll
  for (int j4=0;j4<8;j4++){
    v4f o = { h1[2*j4], h2[2*j4], h1[2*j4+1], h2[2*j4+1] };
    *(v4f*)(hp + 4*j4) = o;
  }
}

// ---------------- scan phase 2: propagate carries across chunks (serial depth 32) -------------
__global__ __launch_bounds__(256) void k_scan_p2(float* __restrict__ hend, const float* __restrict__ prod)
{
  int bh = blockIdx.x, t = threadIdx.x, half = t&1;
  float c1[16], c2[16];
#pragma unroll
  for (int j=0;j<16;j++){ c1[j]=0.f; c2[j]=0.f; }
  for (int c=0;c<C_CH;c++){
    float* hp = hend + (((size_t)(bh*C_CH+c))*256 + t)*32;
    const float* pp = prod + (size_t)(bh*C_CH+c)*64 + half*32;
    float t1[16], t2[16];
#pragma unroll
    for (int j4=0;j4<8;j4++){
      v4f r = *(const v4f*)(hp + 4*j4);
      t1[2*j4]=r[0]; t2[2*j4]=r[1]; t1[2*j4+1]=r[2]; t2[2*j4+1]=r[3];
    }
#pragma unroll
    for (int j4=0;j4<8;j4++){
      v4f o = { c1[2*j4], c2[2*j4], c1[2*j4+1], c2[2*j4+1] };
      *(v4f*)(hp + 4*j4) = o;
    }
#pragma unroll
    for (int j=0;j<16;j++){
      float pr = pp[2*j], pi = pp[2*j+1];
      float n1 = fmaf(pr, c1[j], fmaf(-pi, c2[j], t1[j]));
      float n2 = fmaf(pr, c2[j], fmaf( pi, c1[j], t2[j]));
      c1[j]=n1; c2[j]=n2;
    }
  }
}

// ---------------- scan phase 3: re-run chunk with carry-in; fused D-skip + gate -> gbuf bf16 --
__global__ __launch_bounds__(256) void k_scan_p3(const u16* __restrict__ xz, const u16* __restrict__ bcb,
    const float* __restrict__ hdtb, const float* __restrict__ dcst, const float* __restrict__ dsst,
    const float* __restrict__ Dsk, const float* __restrict__ hcar, u16* __restrict__ gbuf)
{
  int bc_ = blockIdx.x;               // bh*32 + c
  int bh = bc_ >> 5, c = bc_ & 31;
  int b = bh >> 4, h = bh & 15;
  int t = threadIdx.x, p = t>>1, half = t&1, q0 = half*16;
  size_t rowbase = (size_t)b*nL + c*T_CH;
  __shared__ float sB[T_CH+1][64];
  __shared__ float sC[T_CH][64];
  __shared__ float sDC[T_CH][32];
  __shared__ float sDS[T_CH][32];
  for (int e=t; e<(T_CH+1)*64; e+=256){
    int l = e>>6, n = e&63;
    float v = 0.f;
    if (l) v = bf2f(bcb[(rowbase + l-1)*2048 + h*64 + n]);
    else if (c) v = bf2f(bcb[(rowbase - 1)*2048 + h*64 + n]);
    sB[l][n] = v;
  }
  for (int e=t; e<T_CH*64; e+=256){
    int l = e>>6, n = e&63;
    sC[l][n] = bf2f(bcb[(rowbase + l)*2048 + 1024 + h*64 + n]);
  }
  for (int e=t; e<T_CH*32; e+=256){
    int l = e>>5, q = e&31;
    size_t idx = ((rowbase+l)*16 + h)*32 + q;
    sDC[l][q] = dcst[idx]; sDS[l][q] = dsst[idx];
  }
  __syncthreads();
  float h1[16], h2[16];
  const float* hp0 = hcar + ((size_t)bc_*256 + t)*32;
#pragma unroll
  for (int j4=0;j4<8;j4++){
    v4f r = *(const v4f*)(hp0 + 4*j4);
    h1[2*j4]=r[0]; h2[2*j4]=r[1]; h1[2*j4+1]=r[2]; h2[2*j4+1]=r[3];
  }
  float xprev = c ? bf2f(xz[(rowbase-1)*4096 + h*128 + p]) : 0.f;
  float Dskip = Dsk[h];
  const u16* xp = xz + rowbase*4096 + h*128 + p;
  const u16* zp = xz + rowbase*4096 + 2048 + h*128 + p;
  const float* scp = hdtb + rowbase*16 + h;
  u16* gp = gbuf + rowbase*2048 + h*128 + p;
  for (int l=0; l<T_CH; l++){
    float hdt = *scp;
    float xv = bf2f(*xp);
    float a = hdt*xprev, bb = hdt*xv;
    float yacc = 0.f;
#pragma unroll
    for (int j4=0;j4<4;j4++){
      v4f Bp1 = *(const v4f*)&sB[l][q0+4*j4];
      v4f Bp2 = *(const v4f*)&sB[l][32+q0+4*j4];
      v4f Bn1 = *(const v4f*)&sB[l+1][q0+4*j4];
      v4f Bn2 = *(const v4f*)&sB[l+1][32+q0+4*j4];
      v4f C1  = *(const v4f*)&sC[l][q0+4*j4];
      v4f C2  = *(const v4f*)&sC[l][32+q0+4*j4];
      v4f dc  = *(const v4f*)&sDC[l][q0+4*j4];
      v4f dsn = *(const v4f*)&sDS[l][q0+4*j4];
#pragma unroll
      for (int j=0;j<4;j++){
        int jj = 4*j4+j;
        float m1 = fmaf(a, Bp1[j], h1[jj]);
        float m2 = fmaf(a, Bp2[j], h2[jj]);
        float nh1 = fmaf(bb, Bn1[j], fmaf(-m2, dsn[j], m1*dc[j]));
        float nh2 = fmaf(bb, Bn2[j], fmaf( m1, dsn[j], m2*dc[j]));
        h1[jj]=nh1; h2[jj]=nh2;
        yacc = fmaf(nh1, C1[j], fmaf(nh2, C2[j], yacc));
      }
    }
    xprev = xv;
    yacc += __shfl_xor(yacc, 1);
    if (half==0){
      float yv = fmaf(xv, Dskip, yacc);
      float zv = bf2f(*zp);
      float g = yv*zv/(1.f+expf(-zv));
      *gp = f2bf(g);
    }
    xp += 4096; zp += 4096; scp += 16; gp += 2048;
  }
}

// ---------------- attention logits: attn[b,l] = q . xn[b,l] / 32 ----------------
__global__ __launch_bounds__(256) void k_attn(const float* __restrict__ xn, const float* __restrict__ q,
    float* __restrict__ attn)
{
  int wid = blockIdx.x*4 + (threadIdx.x>>6);
  int lane = threadIdx.x & 63;
  const float* xr = xn + (size_t)wid*1024 + lane*16;
  const float* qr = q + lane*16;
  float sAcc=0.f;
#pragma unroll
  for (int j4=0;j4<4;j4++){
    v4f xv = *(const v4f*)(xr + 4*j4);
    v4f qv = *(const v4f*)(qr + 4*j4);
#pragma unroll
    for (int j=0;j<4;j++) sAcc = fmaf(xv[j], qv[j], sAcc);
  }
#pragma unroll
  for (int o=1;o<64;o<<=1) sAcc += __shfl_xor(sAcc,o);
  if (lane==0) attn[wid] = sAcc*(1.f/32.f);
}

// ---------------- softmax over L (in place, normalized probs) ----------------
__global__ __launch_bounds__(1024) void k_smax(float* __restrict__ attn)
{
  int b = blockIdx.x, t = threadIdx.x;
  __shared__ float red[16];
  __shared__ float red2[16];
  float av = attn[b*1024 + t];
  float m = av;
#pragma unroll
  for (int o=1;o<64;o<<=1) m = fmaxf(m, __shfl_xor(m,o));
  if ((t&63)==0) red[t>>6] = m;
  __syncthreads();
  float bm = red[0];
  for (int jj=1;jj<16;jj++) bm = fmaxf(bm, red[jj]);
  float e = expf(av - bm);
  float sm = e;
#pragma unroll
  for (int o=1;o<64;o<<=1) sm += __shfl_xor(sm,o);
  if ((t&63)==0) red2[t>>6] = sm;
  __syncthreads();
  float tot = 0.f;
  for (int jj=0;jj<16;jj++) tot += red2[jj];
  attn[b*1024 + t] = e/tot;
}

// ---------------- pooled[b,w] = sum_l p[l] * xn[b,l,w], parallel over w slices ----------------
__global__ __launch_bounds__(256) void k_pool2(const float* __restrict__ attnp, const float* __restrict__ xn,
    float* __restrict__ pooled)
{
  int wsl = blockIdx.x, b = blockIdx.y, t = threadIdx.x;
  int w = wsl*64 + (t&63), ls = t>>6;
  float acc = 0.f;
  for (int l=ls; l<1024; l+=4)
    acc = fmaf(attnp[b*1024 + l], xn[((size_t)b*1024 + l)*1024 + w], acc);
  __shared__ float red[256];
  red[t] = acc;
  __syncthreads();
  if (t<64)
    pooled[(size_t)b*1024 + wsl*64 + t] = red[t]+red[t+64]+red[t+128]+red[t+192];
}

// ---------------- heads: 96 outputs (16 features then 80 biases), fp32 in, FP32 OUT -------
__global__ __launch_bounds__(256) void k_heads(const float* __restrict__ pooled,
    const float* __restrict__ fw, const float* __restrict__ fb,
    const float* __restrict__ bw, const float* __restrict__ bb, float* __restrict__ outp)
{
  int o = blockIdx.x, t = threadIdx.x;
  int b, j, NJ; const float *Wp, *Bp;
  if (o < 16){ b = o>>2; j = o&3; NJ = 4; Wp = fw; Bp = fb; }
  else { int oo = o-16; b = oo/20; j = oo - b*20; NJ = 20; Wp = bw; Bp = bb; }
  v4f pv = *(const v4f*)(pooled + (size_t)b*1024 + t*4);
  int w0 = t*4;
  float sAcc = pv[0]*Wp[(size_t)(w0+0)*NJ + j] + pv[1]*Wp[(size_t)(w0+1)*NJ + j]
             + pv[2]*Wp[(size_t)(w0+2)*NJ + j] + pv[3]*Wp[(size_t)(w0+3)*NJ + j];
#pragma unroll
  for (int of=1; of<64; of<<=1) sAcc += __shfl_xor(sAcc, of);
  __shared__ float red[4];
  if ((t&63)==0) red[t>>6] = sAcc;
  __syncthreads();
  if (t==0) outp[o] = red[0]+red[1]+red[2]+red[3] + Bp[j];   // fp32 output — d_out is float*
}

extern "C" void kernel_launch(void* const* d_in, const int* in_sizes, int n_in,
                              void* d_out, int out_size, void* d_ws, size_t ws_size,
                              hipStream_t stream)
{
  (void)n_in; (void)out_size;
  int base = (in_sizes[2] >= 1000000) ? 1 : 2;   // index of ln_w (mask present -> 2)
  const float* h_in   = (const float*)d_in[0];
  const float* ln_w   = (const float*)d_in[base+0];
  const float* in_w   = (const float*)d_in[base+1];
  const float* in_b   = (const float*)d_in[base+2];
  const float* dt_w   = (const float*)d_in[base+3];
  const float* dt_b   = (const float*)d_in[base+4];
  const float* bc_w   = (const float*)d_in[base+5];
  const float* bc_b   = (const float*)d_in[base+6];
  const float* A_log  = (const float*)d_in[base+7];
  const float* omega  = (const float*)d_in[base+8];
  const float* D_skip = (const float*)d_in[base+9];
  const float* out_w  = (const float*)d_in[base+10];
  const float* out_b  = (const float*)d_in[base+11];
  const float* fln_w  = (const float*)d_in[base+12];
  const float* queries= (const float*)d_in[base+13];
  const float* feat_w = (const float*)d_in[base+14];
  const float* feat_b = (const float*)d_in[base+15];
  const float* bias_w = (const float*)d_in[base+16];
  const float* bias_b = (const float*)d_in[base+17];

  char* w0 = (char*)d_ws;
  size_t off = 0;
  auto take = [&](size_t bytes)->char*{ char* pp = w0 + off; off += (bytes + 255) & ~(size_t)255; return pp; };
  u16* wT_in  = (u16*)take((size_t)4096*1024*2);
  u16* wT_bc  = (u16*)take((size_t)2048*1024*2);
  u16* wT_out = (u16*)take((size_t)1024*2048*2);
  u16* wT_dt  = (u16*)take((size_t)16*1024*2);
  float* x    = (float*)take((size_t)4194304*4);
  u16* rbf    = (u16*)take((size_t)4194304*2);
  u16* xz     = (u16*)take((size_t)16777216*2);
  u16* bcb    = (u16*)take((size_t)8388608*2);
  char* bigscratch = take((size_t)67108864);     // hendb (64MB) during scan; xn (16MB) after
  u16* gbuf   = (u16*)take((size_t)8388608*2);
  float* cst  = (float*)take((size_t)2097152*4);
  float* sst  = (float*)take((size_t)2097152*4);
  float* dtraw= (float*)take((size_t)65536*4);
  float* dtarr= (float*)take((size_t)65536*4);
  float* hdtb = (float*)take((size_t)65536*4);
  float* attnb= (float*)take((size_t)4096*4);
  float* pool = (float*)take((size_t)4096*4);
  float* prodb= (float*)take((size_t)2048*64*4);   // 2048 x 32 complex
  if (off > ws_size) return;   // insufficient scratch: fail cleanly, not a fault
  float* hendb = (float*)bigscratch;
  float* xn    = (float*)bigscratch;   // alias (hendb dead after last p3)

  k_cvt<<<4096,256,0,stream>>>(h_in, x);
  for (int d=0; d<4; d++){
    k_transpose<<<dim3(128,32),256,0,stream>>>(in_w + (size_t)d*1024*4096, wT_in, 1024, 4096);
    k_transpose<<<dim3(64,32),256,0,stream>>>(bc_w + (size_t)d*1024*2048, wT_bc, 1024, 2048);
    k_transpose<<<dim3(32,64),256,0,stream>>>(out_w + (size_t)d*2048*1024, wT_out, 2048, 1024);
    k_transpose<<<dim3(1,32),256,0,stream>>>(dt_w + (size_t)d*1024*16, wT_dt, 1024, 16);
    k_rmsnorm<<<4096,256,0,stream>>>(x, ln_w + d*1024, rbf, (float*)nullptr);
    k_gemm<u16,false><<<dim3(32,32),256,0,stream>>>(rbf, wT_in, in_b + d*4096, xz, 4096, 1024);
    k_gemm<u16,false><<<dim3(16,32),256,0,stream>>>(rbf, wT_bc, bc_b + d*2048, bcb, 2048, 1024);
    k_dt<<<4096,64,0,stream>>>(rbf, wT_dt, dtraw);
    k_prep2<<<256,256,0,stream>>>(dtraw, dt_b + d*16, hdtb, dtarr);
    k_cs2<<<8192,256,0,stream>>>(dtarr, omega + d*32, A_log + d*16, cst, sst);
    k_chunkprod<<<8,256,0,stream>>>(dtarr, A_log + d*16, omega + d*32, prodb);
    k_scan_p1<<<2048,256,0,stream>>>(xz, bcb, hdtb, cst, sst, hendb);
    k_scan_p2<<<64,256,0,stream>>>(hendb, prodb);
    k_scan_p3<<<2048,256,0,stream>>>(xz, bcb, hdtb, cst, sst, D_skip + d*16, hendb, gbuf);
    k_gemm<float,true><<<dim3(8,32),256,0,stream>>>(gbuf, wT_out, out_b + d*1024, x, 1024, 2048);
  }
  k_rmsnorm<<<4096,256,0,stream>>>(x, fln_w, (u16*)nullptr, xn);
  k_attn<<<1024,256,0,stream>>>(xn, queries, attnb);
  k_smax<<<4,1024,0,stream>>>(attnb);
  k_pool2<<<dim3(16,4),256,0,stream>>>(attnb, xn, pool);
  k_heads<<<96,256,0,stream>>>(pool, feat_w, feat_b, bias_w, bias_b, (float*)d_out);
}

// Round 4
// 2161.881 us; speedup vs baseline: 2.6703x; 1.3539x over previous
//
#include <hip/hip_runtime.h>
#include <math.h>

typedef unsigned short u16;
typedef float v4f  __attribute__((ext_vector_type(4)));
typedef __bf16 v8bf __attribute__((ext_vector_type(8)));

enum { nB=4, nL=1024, nW=1024, nH=16, nN=64, nE=2048, nP=128, nNH=32, nDEPTH=4 };
enum { C_CH=32, T_CH=32 };   // chunked scan: 32 chunks of 32 steps

__device__ __forceinline__ float bf2f(u16 u){ unsigned v=((unsigned)u)<<16; return __builtin_bit_cast(float,v); }
__device__ __forceinline__ u16 f2bf(float f){ unsigned x=__builtin_bit_cast(unsigned,f); return (u16)((x + 0x7fffu + ((x>>16)&1u))>>16); }
__device__ __forceinline__ unsigned pk2(float a, float b){ return (unsigned)f2bf(a) | ((unsigned)f2bf(b)<<16); }
__device__ __forceinline__ float softplus_f(float v){ return (v>15.f)? v : log1pf(expf(v)); }
__device__ __forceinline__ void unp8(uint4 u, float* f){
  f[0]=bf2f((u16)(u.x&0xffff)); f[1]=bf2f((u16)(u.x>>16));
  f[2]=bf2f((u16)(u.y&0xffff)); f[3]=bf2f((u16)(u.y>>16));
  f[4]=bf2f((u16)(u.z&0xffff)); f[5]=bf2f((u16)(u.z>>16));
  f[6]=bf2f((u16)(u.w&0xffff)); f[7]=bf2f((u16)(u.w>>16));
}

// async global->LDS, 16B per lane; LDS dest is wave-uniform base + lane*16 (m97 pattern)
#define GLOAD16(gptr, lptr) __builtin_amdgcn_global_load_lds( \
    (const __attribute__((address_space(1))) unsigned int*)(gptr), \
    (__attribute__((address_space(3))) unsigned int*)(lptr), 16, 0, 0)

// ---------------- copy h (fp32) -> x (fp32 residual) ----------------
__global__ void k_cvt(const float* __restrict__ hsrc, float* __restrict__ x){
  int i = (blockIdx.x*256 + threadIdx.x)*4;
  *(v4f*)(x + i) = *(const v4f*)(hsrc + i);
}

// ---------------- transpose fp32 (R,C) -> bf16 (C,R) ----------------
__global__ __launch_bounds__(256) void k_transpose(const float* __restrict__ src, u16* __restrict__ dst,
    int R, int C)
{
  __shared__ u16 tl[32][36];
  int r0 = blockIdx.y*32, c0 = blockIdx.x*32;
  int tid = threadIdx.x;
  int r = tid>>3, c4 = (tid&7)*4;
  if (r0 + r < R){
#pragma unroll
    for (int jj=0;jj<4;jj++){
      int c = c0 + c4 + jj;
      tl[r][c4+jj] = (c < C) ? f2bf(src[(size_t)(r0+r)*C + c]) : (u16)0;
    }
  }
  __syncthreads();
  int c = tid>>3, r4 = (tid&7)*4;
  if (c0 + c < C){
#pragma unroll
    for (int jj=0;jj<4;jj++){
      int rr = r0 + r4 + jj;
      if (rr < R) dst[(size_t)(c0+c)*R + rr] = tl[r4+jj][c];
    }
  }
}

// ---------------- rmsnorm: x(fp32) * w(fp32) -> bf16 and/or fp32 ----------------
__global__ __launch_bounds__(256) void k_rmsnorm(const float* __restrict__ x, const float* __restrict__ w,
    u16* __restrict__ obf, float* __restrict__ of32)
{
  int row = blockIdx.x, tid = threadIdx.x;
  const float* xr = x + (size_t)row*1024;
  v4f v = *(const v4f*)(xr + tid*4);
  float ss = v[0]*v[0]+v[1]*v[1]+v[2]*v[2]+v[3]*v[3];
#pragma unroll
  for (int o=1;o<64;o<<=1) ss += __shfl_xor(ss,o);
  __shared__ float red[4];
  if ((tid&63)==0) red[tid>>6] = ss;
  __syncthreads();
  float tot = red[0]+red[1]+red[2]+red[3];
  float rms = rsqrtf(tot*(1.f/1024.f) + 1e-6f);
  v4f wv = *(const v4f*)(w + tid*4);
  float o0=v[0]*rms*wv[0], o1=v[1]*rms*wv[1], o2=v[2]*rms*wv[2], o3=v[3]*rms*wv[3];
  if (obf){
    ushort4 ob = { f2bf(o0), f2bf(o1), f2bf(o2), f2bf(o3) };
    *(ushort4*)(obf + (size_t)row*1024 + tid*4) = ob;
  }
  if (of32){
    v4f ov = {o0,o1,o2,o3};
    *(v4f*)(of32 + (size_t)row*1024 + tid*4) = ov;
  }
}

// ---------------- MFMA GEMM (m97 structure): C = A(MxK,bf16) @ BT(NxK,bf16)^T + bias(fp32)
// 128x128 tile, BK=32, global_load_lds width-16 staging, linear LDS [128][32],
// 2 barriers per K-step, LDS-staged coalesced epilogue reusing the staging buffer.
template<typename OT, bool ADD>
__global__ __launch_bounds__(256) void k_gemm(const u16* __restrict__ A, const u16* __restrict__ BT,
    const float* __restrict__ bias, OT* __restrict__ C, int N, int K)
{
  __shared__ __align__(16) char sraw[32*132*4];   // 16.9 KB; staging uses first 16 KB
  u16* As = (u16*)sraw;            // [128][32] linear
  u16* Bs = As + 128*32;
  const int tid = threadIdx.x;
  const int wave = tid>>6, lane = tid&63, quad = lane>>4, l15 = lane&15;
  const int bm = blockIdx.y*128, bn = blockIdx.x*128;
  const int wm = (wave>>1)*64, wn = (wave&1)*64;
  v4f acc[4][4];
#pragma unroll
  for (int i=0;i<4;i++)
#pragma unroll
    for (int j=0;j<4;j++){ v4f z = {0.f,0.f,0.f,0.f}; acc[i][j]=z; }

  // staging: wave w covers rows w*32 .. w*32+31 (two 16-row issues per matrix).
  // lane l -> row offset l>>2, 8-elem chunk l&3  (matches LDS dest base + lane*16B)
  const int srow = wave*32 + (lane>>2);
  const int scol = (lane&3)*8;
  const u16* agp = A  + (size_t)(bm+srow)*K + scol;
  const u16* bgp = BT + (size_t)(bn+srow)*K + scol;
  u16* ldsA = As + (wave*32)*32;
  u16* ldsB = Bs + (wave*32)*32;

  for (int k0=0; k0<K; k0+=32){
    GLOAD16(agp,                ldsA);
    GLOAD16(agp + (size_t)16*K, ldsA + 16*32);
    GLOAD16(bgp,                ldsB);
    GLOAD16(bgp + (size_t)16*K, ldsB + 16*32);
    agp += 32; bgp += 32;
    __syncthreads();                 // drains vmcnt(0): staged tile visible
    v8bf af[4], bfr[4];
#pragma unroll
    for (int mi=0;mi<4;mi++) af[mi]  = *(const v8bf*)(As + (wm+mi*16+l15)*32 + quad*8);
#pragma unroll
    for (int ni=0;ni<4;ni++) bfr[ni] = *(const v8bf*)(Bs + (wn+ni*16+l15)*32 + quad*8);
#pragma unroll
    for (int mi=0;mi<4;mi++)
#pragma unroll
      for (int ni=0;ni<4;ni++)
        acc[mi][ni] = __builtin_amdgcn_mfma_f32_16x16x32_bf16(af[mi], bfr[ni], acc[mi][ni], 0,0,0);
    __syncthreads();                 // all LDS reads done before next stage overwrites
  }

  // -------- LDS-staged epilogue: coalesced full-line stores --------
  float* eps = (float*)sraw;         // 32 x 132 f32 = 16.9 KB
  float bz[4];
#pragma unroll
  for (int ni=0;ni<4;ni++) bz[ni] = bias[bn + wn + ni*16 + l15];
  const int erb = (wave>>1)*16 + quad*4;
#pragma unroll
  for (int mi=0;mi<4;mi++){
#pragma unroll
    for (int ni=0;ni<4;ni++){
      v4f v = acc[mi][ni];
#pragma unroll
      for (int r=0;r<4;r++)
        eps[(erb + r)*132 + wn + ni*16 + l15] = v[r] + bz[ni];
    }
    __syncthreads();
    {
      int e = tid>>3, seg = tid&7;
      int grow = bm + (e>>4)*64 + mi*16 + (e&15);
      int gcol = bn + seg*16;
      const float* ep = eps + e*132 + seg*16;
      if constexpr (ADD){
        float* cp = (float*)C + (size_t)grow*N + gcol;
#pragma unroll
        for (int u=0;u<4;u++){
          v4f ov = *(const v4f*)(ep + 4*u);
          v4f cv = *(const v4f*)(cp + 4*u);
          ov += cv;
          *(v4f*)(cp + 4*u) = ov;
        }
      } else {
        u16* cp = (u16*)C + (size_t)grow*N + gcol;
        v4f e0 = *(const v4f*)(ep+0), e1 = *(const v4f*)(ep+4);
        v4f e2 = *(const v4f*)(ep+8), e3 = *(const v4f*)(ep+12);
        uint4 pA = { pk2(e0[0],e0[1]), pk2(e0[2],e0[3]), pk2(e1[0],e1[1]), pk2(e1[2],e1[3]) };
        uint4 pB = { pk2(e2[0],e2[1]), pk2(e2[2],e2[3]), pk2(e3[0],e3[1]), pk2(e3[2],e3[3]) };
        *(uint4*)(cp)   = pA;
        *(uint4*)(cp+8) = pB;
      }
    }
    __syncthreads();
  }
}

// ---------------- dt matmul: dtraw(rows x 16) = r(bf16) @ dt_wT(16x1024,bf16)^T --------------
__global__ __launch_bounds__(64) void k_dt(const u16* __restrict__ r, const u16* __restrict__ dtwT,
    float* __restrict__ dtraw)
{
  int row = blockIdx.x, lane = threadIdx.x;
  const u16* rp = r + (size_t)row*1024 + lane*16;
  float rv[16];
  unp8(*(const uint4*)rp, rv);
  unp8(*(const uint4*)(rp+8), rv+8);
  float keep = 0.f;
  for (int hh=0; hh<16; hh++){
    const u16* wp = dtwT + hh*1024 + lane*16;
    float wv[16];
    unp8(*(const uint4*)wp, wv);
    unp8(*(const uint4*)(wp+8), wv+8);
    float sv = 0.f;
#pragma unroll
    for (int j=0;j<16;j++) sv = fmaf(rv[j], wv[j], sv);
#pragma unroll
    for (int o=1;o<64;o<<=1) sv += __shfl_xor(sv, o);
    if (lane==hh) keep = sv;
  }
  if (lane<16) dtraw[(size_t)row*16 + lane] = keep;
}

// ---------------- prep2 per (b,l,h): hdtb = 0.5*dt; dtarr = dt ----------------
__global__ void k_prep2(const float* __restrict__ dtraw, const float* __restrict__ dt_b,
    float* __restrict__ hdtb, float* __restrict__ dtarr)
{
  int i = blockIdx.x*256 + threadIdx.x;      // (b,l,h) h-fastest
  int h = i & 15;
  float dt0 = fminf(softplus_f(dtraw[i] + dt_b[h]), 30.f);
  hdtb[i] = 0.5f*dt0;
  dtarr[i] = dt0;
}

// ---------------- cs2: per-step dec-folded cos/sin: dcs = dec*cos, dss = dec*sin ----------------
__global__ void k_cs2(const float* __restrict__ dtarr, const float* __restrict__ omega,
    const float* __restrict__ A_log, float* __restrict__ dcst, float* __restrict__ dsst)
{
  int i = blockIdx.x*256 + threadIdx.x;   // (b,l,h,q)
  int q = i & 31, blh = i>>5, h = blh & 15;
  float dt = dtarr[blh];
  float dec = expf(-expf(A_log[h])*dt);
  float sn, cn; __sincosf(dt*omega[q], &sn, &cn);
  dcst[i]=dec*cn; dsst[i]=dec*sn;
}

// ---------------- chunk cumulative transition: prod[(bh*C+c)*64 + 2q+{0,1}] = exp(A*S)*(cos,sin)(w_q*S)
__global__ void k_chunkprod(const float* __restrict__ dtarr, const float* __restrict__ A_log,
    const float* __restrict__ omega, float* __restrict__ prod)
{
  int i = blockIdx.x*256 + threadIdx.x;   // 2048 items: (bh, c)
  int bh = i >> 5, c = i & 31;
  int b = bh >> 4, h = bh & 15;
  size_t base = ((size_t)b*nL + c*T_CH)*16 + h;
  float S = 0.f;
  for (int t=0;t<T_CH;t++) S += dtarr[base + (size_t)t*16];
  float A = -expf(A_log[h]);
  float decF = expf(A*S);
  float* pp = prod + (size_t)i*64;
#pragma unroll
  for (int q=0;q<32;q++){
    float sn, cn; __sincosf(omega[q]*S, &sn, &cn);
    pp[q*2]   = decF*cn;
    pp[q*2+1] = decF*sn;
  }
}

// ---------------- scan phase 1: per (bh, chunk), local scan from zero state; store end state ----
// hend layout: ((bh*C+c)*256 + tid)*32 + 4*j4 + {0..3} = {h1[2j4], h2[2j4], h1[2j4+1], h2[2j4+1]}
__global__ __launch_bounds__(256) void k_scan_p1(const u16* __restrict__ xz, const u16* __restrict__ bcb,
    const float* __restrict__ hdtb, const float* __restrict__ dcst, const float* __restrict__ dsst,
    float* __restrict__ hend)
{
  int bc_ = blockIdx.x;               // bh*32 + c
  int bh = bc_ >> 5, c = bc_ & 31;
  int b = bh >> 4, h = bh & 15;
  int t = threadIdx.x, p = t>>1, half = t&1, q0 = half*16;
  size_t rowbase = (size_t)b*nL + c*T_CH;
  __shared__ float sB[T_CH+1][64];
  __shared__ float sDC[T_CH][32];
  __shared__ float sDS[T_CH][32];
  for (int e=t; e<(T_CH+1)*64; e+=256){
    int l = e>>6, n = e&63;
    float v = 0.f;
    if (l) v = bf2f(bcb[(rowbase + l-1)*2048 + h*64 + n]);
    else if (c) v = bf2f(bcb[(rowbase - 1)*2048 + h*64 + n]);
    sB[l][n] = v;
  }
  for (int e=t; e<T_CH*32; e+=256){
    int l = e>>5, q = e&31;
    size_t idx = ((rowbase+l)*16 + h)*32 + q;
    sDC[l][q] = dcst[idx]; sDS[l][q] = dsst[idx];
  }
  __syncthreads();
  float h1[16], h2[16];
#pragma unroll
  for (int j=0;j<16;j++){ h1[j]=0.f; h2[j]=0.f; }
  float xprev = c ? bf2f(xz[(rowbase-1)*4096 + h*128 + p]) : 0.f;
  const u16* xp = xz + rowbase*4096 + h*128 + p;
  const float* scp = hdtb + rowbase*16 + h;
  for (int l=0; l<T_CH; l++){
    float hdt = *scp;
    float xv = bf2f(*xp);
    float a = hdt*xprev, bb = hdt*xv;
#pragma unroll
    for (int j4=0;j4<4;j4++){
      v4f Bp1 = *(const v4f*)&sB[l][q0+4*j4];
      v4f Bp2 = *(const v4f*)&sB[l][32+q0+4*j4];
      v4f Bn1 = *(const v4f*)&sB[l+1][q0+4*j4];
      v4f Bn2 = *(const v4f*)&sB[l+1][32+q0+4*j4];
      v4f dc  = *(const v4f*)&sDC[l][q0+4*j4];
      v4f dsn = *(const v4f*)&sDS[l][q0+4*j4];
#pragma unroll
      for (int j=0;j<4;j++){
        int jj = 4*j4+j;
        float m1 = fmaf(a, Bp1[j], h1[jj]);
        float m2 = fmaf(a, Bp2[j], h2[jj]);
        h1[jj] = fmaf(bb, Bn1[j], fmaf(-m2, dsn[j], m1*dc[j]));
        h2[jj] = fmaf(bb, Bn2[j], fmaf( m1, dsn[j], m2*dc[j]));
      }
    }
    xprev = xv;
    xp += 4096; scp += 16;
  }
  float* hp = hend + ((size_t)bc_*256 + t)*32;
#pragma unroll
  for (int j4=0;j4<8;j4++){
    v4f o = { h1[2*j4], h2[2*j4], h1[2*j4+1], h2[2*j4+1] };
    *(v4f*)(hp + 4*j4) = o;
  }
}

// ---------------- scan phase 2: propagate carries across chunks (serial depth 32) -------------
__global__ __launch_bounds__(256) void k_scan_p2(float* __restrict__ hend, const float* __restrict__ prod)
{
  int bh = blockIdx.x, t = threadIdx.x, half = t&1;
  float c1[16], c2[16];
#pragma unroll
  for (int j=0;j<16;j++){ c1[j]=0.f; c2[j]=0.f; }
  for (int c=0;c<C_CH;c++){
    float* hp = hend + (((size_t)(bh*C_CH+c))*256 + t)*32;
    const float* pp = prod + (size_t)(bh*C_CH+c)*64 + half*32;
    float t1[16], t2[16];
#pragma unroll
    for (int j4=0;j4<8;j4++){
      v4f r = *(const v4f*)(hp + 4*j4);
      t1[2*j4]=r[0]; t2[2*j4]=r[1]; t1[2*j4+1]=r[2]; t2[2*j4+1]=r[3];
    }
#pragma unroll
    for (int j4=0;j4<8;j4++){
      v4f o = { c1[2*j4], c2[2*j4], c1[2*j4+1], c2[2*j4+1] };
      *(v4f*)(hp + 4*j4) = o;
    }
#pragma unroll
    for (int j=0;j<16;j++){
      float pr = pp[2*j], pi = pp[2*j+1];
      float n1 = fmaf(pr, c1[j], fmaf(-pi, c2[j], t1[j]));
      float n2 = fmaf(pr, c2[j], fmaf( pi, c1[j], t2[j]));
      c1[j]=n1; c2[j]=n2;
    }
  }
}

// ---------------- scan phase 3: re-run chunk with carry-in; fused D-skip + gate -> gbuf bf16 --
__global__ __launch_bounds__(256) void k_scan_p3(const u16* __restrict__ xz, const u16* __restrict__ bcb,
    const float* __restrict__ hdtb, const float* __restrict__ dcst, const float* __restrict__ dsst,
    const float* __restrict__ Dsk, const float* __restrict__ hcar, u16* __restrict__ gbuf)
{
  int bc_ = blockIdx.x;               // bh*32 + c
  int bh = bc_ >> 5, c = bc_ & 31;
  int b = bh >> 4, h = bh & 15;
  int t = threadIdx.x, p = t>>1, half = t&1, q0 = half*16;
  size_t rowbase = (size_t)b*nL + c*T_CH;
  __shared__ float sB[T_CH+1][64];
  __shared__ float sC[T_CH][64];
  __shared__ float sDC[T_CH][32];
  __shared__ float sDS[T_CH][32];
  for (int e=t; e<(T_CH+1)*64; e+=256){
    int l = e>>6, n = e&63;
    float v = 0.f;
    if (l) v = bf2f(bcb[(rowbase + l-1)*2048 + h*64 + n]);
    else if (c) v = bf2f(bcb[(rowbase - 1)*2048 + h*64 + n]);
    sB[l][n] = v;
  }
  for (int e=t; e<T_CH*64; e+=256){
    int l = e>>6, n = e&63;
    sC[l][n] = bf2f(bcb[(rowbase + l)*2048 + 1024 + h*64 + n]);
  }
  for (int e=t; e<T_CH*32; e+=256){
    int l = e>>5, q = e&31;
    size_t idx = ((rowbase+l)*16 + h)*32 + q;
    sDC[l][q] = dcst[idx]; sDS[l][q] = dsst[idx];
  }
  __syncthreads();
  float h1[16], h2[16];
  const float* hp0 = hcar + ((size_t)bc_*256 + t)*32;
#pragma unroll
  for (int j4=0;j4<8;j4++){
    v4f r = *(const v4f*)(hp0 + 4*j4);
    h1[2*j4]=r[0]; h2[2*j4]=r[1]; h1[2*j4+1]=r[2]; h2[2*j4+1]=r[3];
  }
  float xprev = c ? bf2f(xz[(rowbase-1)*4096 + h*128 + p]) : 0.f;
  float Dskip = Dsk[h];
  const u16* xp = xz + rowbase*4096 + h*128 + p;
  const u16* zp = xz + rowbase*4096 + 2048 + h*128 + p;
  const float* scp = hdtb + rowbase*16 + h;
  u16* gp = gbuf + rowbase*2048 + h*128 + p;
  for (int l=0; l<T_CH; l++){
    float hdt = *scp;
    float xv = bf2f(*xp);
    float a = hdt*xprev, bb = hdt*xv;
    float yacc = 0.f;
#pragma unroll
    for (int j4=0;j4<4;j4++){
      v4f Bp1 = *(const v4f*)&sB[l][q0+4*j4];
      v4f Bp2 = *(const v4f*)&sB[l][32+q0+4*j4];
      v4f Bn1 = *(const v4f*)&sB[l+1][q0+4*j4];
      v4f Bn2 = *(const v4f*)&sB[l+1][32+q0+4*j4];
      v4f C1  = *(const v4f*)&sC[l][q0+4*j4];
      v4f C2  = *(const v4f*)&sC[l][32+q0+4*j4];
      v4f dc  = *(const v4f*)&sDC[l][q0+4*j4];
      v4f dsn = *(const v4f*)&sDS[l][q0+4*j4];
#pragma unroll
      for (int j=0;j<4;j++){
        int jj = 4*j4+j;
        float m1 = fmaf(a, Bp1[j], h1[jj]);
        float m2 = fmaf(a, Bp2[j], h2[jj]);
        float nh1 = fmaf(bb, Bn1[j], fmaf(-m2, dsn[j], m1*dc[j]));
        float nh2 = fmaf(bb, Bn2[j], fmaf( m1, dsn[j], m2*dc[j]));
        h1[jj]=nh1; h2[jj]=nh2;
        yacc = fmaf(nh1, C1[j], fmaf(nh2, C2[j], yacc));
      }
    }
    xprev = xv;
    yacc += __shfl_xor(yacc, 1);
    if (half==0){
      float yv = fmaf(xv, Dskip, yacc);
      float zv = bf2f(*zp);
      float g = yv*zv/(1.f+expf(-zv));
      *gp = f2bf(g);
    }
    xp += 4096; zp += 4096; scp += 16; gp += 2048;
  }
}

// ---------------- attention logits: attn[b,l] = q . xn[b,l] / 32 ----------------
__global__ __launch_bounds__(256) void k_attn(const float* __restrict__ xn, const float* __restrict__ q,
    float* __restrict__ attn)
{
  int wid = blockIdx.x*4 + (threadIdx.x>>6);
  int lane = threadIdx.x & 63;
  const float* xr = xn + (size_t)wid*1024 + lane*16;
  const float* qr = q + lane*16;
  float sAcc=0.f;
#pragma unroll
  for (int j4=0;j4<4;j4++){
    v4f xv = *(const v4f*)(xr + 4*j4);
    v4f qv = *(const v4f*)(qr + 4*j4);
#pragma unroll
    for (int j=0;j<4;j++) sAcc = fmaf(xv[j], qv[j], sAcc);
  }
#pragma unroll
  for (int o=1;o<64;o<<=1) sAcc += __shfl_xor(sAcc,o);
  if (lane==0) attn[wid] = sAcc*(1.f/32.f);
}

// ---------------- softmax over L (in place, normalized probs) ----------------
__global__ __launch_bounds__(1024) void k_smax(float* __restrict__ attn)
{
  int b = blockIdx.x, t = threadIdx.x;
  __shared__ float red[16];
  __shared__ float red2[16];
  float av = attn[b*1024 + t];
  float m = av;
#pragma unroll
  for (int o=1;o<64;o<<=1) m = fmaxf(m, __shfl_xor(m,o));
  if ((t&63)==0) red[t>>6] = m;
  __syncthreads();
  float bm = red[0];
  for (int jj=1;jj<16;jj++) bm = fmaxf(bm, red[jj]);
  float e = expf(av - bm);
  float sm = e;
#pragma unroll
  for (int o=1;o<64;o<<=1) sm += __shfl_xor(sm,o);
  if ((t&63)==0) red2[t>>6] = sm;
  __syncthreads();
  float tot = 0.f;
  for (int jj=0;jj<16;jj++) tot += red2[jj];
  attn[b*1024 + t] = e/tot;
}

// ---------------- pooled[b,w] = sum_l p[l] * xn[b,l,w], parallel over w slices ----------------
__global__ __launch_bounds__(256) void k_pool2(const float* __restrict__ attnp, const float* __restrict__ xn,
    float* __restrict__ pooled)
{
  int wsl = blockIdx.x, b = blockIdx.y, t = threadIdx.x;
  int w = wsl*64 + (t&63), ls = t>>6;
  float acc = 0.f;
  for (int l=ls; l<1024; l+=4)
    acc = fmaf(attnp[b*1024 + l], xn[((size_t)b*1024 + l)*1024 + w], acc);
  __shared__ float red[256];
  red[t] = acc;
  __syncthreads();
  if (t<64)
    pooled[(size_t)b*1024 + wsl*64 + t] = red[t]+red[t+64]+red[t+128]+red[t+192];
}

// ---------------- heads: 96 outputs (16 features then 80 biases), fp32 in, FP32 OUT -------
__global__ __launch_bounds__(256) void k_heads(const float* __restrict__ pooled,
    const float* __restrict__ fw, const float* __restrict__ fb,
    const float* __restrict__ bw, const float* __restrict__ bb, float* __restrict__ outp)
{
  int o = blockIdx.x, t = threadIdx.x;
  int b, j, NJ; const float *Wp, *Bp;
  if (o < 16){ b = o>>2; j = o&3; NJ = 4; Wp = fw; Bp = fb; }
  else { int oo = o-16; b = oo/20; j = oo - b*20; NJ = 20; Wp = bw; Bp = bb; }
  v4f pv = *(const v4f*)(pooled + (size_t)b*1024 + t*4);
  int w0 = t*4;
  float sAcc = pv[0]*Wp[(size_t)(w0+0)*NJ + j] + pv[1]*Wp[(size_t)(w0+1)*NJ + j]
             + pv[2]*Wp[(size_t)(w0+2)*NJ + j] + pv[3]*Wp[(size_t)(w0+3)*NJ + j];
#pragma unroll
  for (int of=1; of<64; of<<=1) sAcc += __shfl_xor(sAcc, of);
  __shared__ float red[4];
  if ((t&63)==0) red[t>>6] = sAcc;
  __syncthreads();
  if (t==0) outp[o] = red[0]+red[1]+red[2]+red[3] + Bp[j];   // fp32 output — d_out is float*
}

extern "C" void kernel_launch(void* const* d_in, const int* in_sizes, int n_in,
                              void* d_out, int out_size, void* d_ws, size_t ws_size,
                              hipStream_t stream)
{
  (void)n_in; (void)out_size;
  int base = (in_sizes[2] >= 1000000) ? 1 : 2;   // index of ln_w (mask present -> 2)
  const float* h_in   = (const float*)d_in[0];
  const float* ln_w   = (const float*)d_in[base+0];
  const float* in_w   = (const float*)d_in[base+1];
  const float* in_b   = (const float*)d_in[base+2];
  const float* dt_w   = (const float*)d_in[base+3];
  const float* dt_b   = (const float*)d_in[base+4];
  const float* bc_w   = (const float*)d_in[base+5];
  const float* bc_b   = (const float*)d_in[base+6];
  const float* A_log  = (const float*)d_in[base+7];
  const float* omega  = (const float*)d_in[base+8];
  const float* D_skip = (const float*)d_in[base+9];
  const float* out_w  = (const float*)d_in[base+10];
  const float* out_b  = (const float*)d_in[base+11];
  const float* fln_w  = (const float*)d_in[base+12];
  const float* queries= (const float*)d_in[base+13];
  const float* feat_w = (const float*)d_in[base+14];
  const float* feat_b = (const float*)d_in[base+15];
  const float* bias_w = (const float*)d_in[base+16];
  const float* bias_b = (const float*)d_in[base+17];

  char* w0 = (char*)d_ws;
  size_t off = 0;
  auto take = [&](size_t bytes)->char*{ char* pp = w0 + off; off += (bytes + 255) & ~(size_t)255; return pp; };
  u16* wT_in  = (u16*)take((size_t)4096*1024*2);
  u16* wT_bc  = (u16*)take((size_t)2048*1024*2);
  u16* wT_out = (u16*)take((size_t)1024*2048*2);
  u16* wT_dt  = (u16*)take((size_t)16*1024*2);
  float* x    = (float*)take((size_t)4194304*4);
  u16* rbf    = (u16*)take((size_t)4194304*2);
  u16* xz     = (u16*)take((size_t)16777216*2);
  u16* bcb    = (u16*)take((size_t)8388608*2);
  char* bigscratch = take((size_t)67108864);     // hendb (64MB) during scan; xn (16MB) after
  u16* gbuf   = (u16*)take((size_t)8388608*2);
  float* cst  = (float*)take((size_t)2097152*4);
  float* sst  = (float*)take((size_t)2097152*4);
  float* dtraw= (float*)take((size_t)65536*4);
  float* dtarr= (float*)take((size_t)65536*4);
  float* hdtb = (float*)take((size_t)65536*4);
  float* attnb= (float*)take((size_t)4096*4);
  float* pool = (float*)take((size_t)4096*4);
  float* prodb= (float*)take((size_t)2048*64*4);   // 2048 x 32 complex
  if (off > ws_size) return;   // insufficient scratch: fail cleanly, not a fault
  float* hendb = (float*)bigscratch;
  float* xn    = (float*)bigscratch;   // alias (hendb dead after last p3)

  k_cvt<<<4096,256,0,stream>>>(h_in, x);
  for (int d=0; d<4; d++){
    k_transpose<<<dim3(128,32),256,0,stream>>>(in_w + (size_t)d*1024*4096, wT_in, 1024, 4096);
    k_transpose<<<dim3(64,32),256,0,stream>>>(bc_w + (size_t)d*1024*2048, wT_bc, 1024, 2048);
    k_transpose<<<dim3(32,64),256,0,stream>>>(out_w + (size_t)d*2048*1024, wT_out, 2048, 1024);
    k_transpose<<<dim3(1,32),256,0,stream>>>(dt_w + (size_t)d*1024*16, wT_dt, 1024, 16);
    k_rmsnorm<<<4096,256,0,stream>>>(x, ln_w + d*1024, rbf, (float*)nullptr);
    k_gemm<u16,false><<<dim3(32,32),256,0,stream>>>(rbf, wT_in, in_b + d*4096, xz, 4096, 1024);
    k_gemm<u16,false><<<dim3(16,32),256,0,stream>>>(rbf, wT_bc, bc_b + d*2048, bcb, 2048, 1024);
    k_dt<<<4096,64,0,stream>>>(rbf, wT_dt, dtraw);
    k_prep2<<<256,256,0,stream>>>(dtraw, dt_b + d*16, hdtb, dtarr);
    k_cs2<<<8192,256,0,stream>>>(dtarr, omega + d*32, A_log + d*16, cst, sst);
    k_chunkprod<<<8,256,0,stream>>>(dtarr, A_log + d*16, omega + d*32, prodb);
    k_scan_p1<<<2048,256,0,stream>>>(xz, bcb, hdtb, cst, sst, hendb);
    k_scan_p2<<<64,256,0,stream>>>(hendb, prodb);
    k_scan_p3<<<2048,256,0,stream>>>(xz, bcb, hdtb, cst, sst, D_skip + d*16, hendb, gbuf);
    k_gemm<float,true><<<dim3(8,32),256,0,stream>>>(gbuf, wT_out, out_b + d*1024, x, 1024, 2048);
  }
  k_rmsnorm<<<4096,256,0,stream>>>(x, fln_w, (u16*)nullptr, xn);
  k_attn<<<1024,256,0,stream>>>(xn, queries, attnb);
  k_smax<<<4,1024,0,stream>>>(attnb);
  k_pool2<<<dim3(16,4),256,0,stream>>>(attnb, xn, pool);
  k_heads<<<96,256,0,stream>>>(pool, feat_w, feat_b, bias_w, bias_b, (float*)d_out);
}

// Round 5
// 2012.719 us; speedup vs baseline: 2.8682x; 1.0741x over previous
//
#include <hip/hip_runtime.h>
#include <math.h>

typedef unsigned short u16;
typedef float v4f  __attribute__((ext_vector_type(4)));
typedef __bf16 v8bf __attribute__((ext_vector_type(8)));

enum { nB=4, nL=1024, nW=1024, nH=16, nN=64, nE=2048, nP=128, nNH=32, nDEPTH=4 };
enum { C_CH=32, T_CH=32 };   // chunked scan: 32 chunks of 32 steps

__device__ __forceinline__ float bf2f(u16 u){ unsigned v=((unsigned)u)<<16; return __builtin_bit_cast(float,v); }
__device__ __forceinline__ u16 f2bf(float f){ unsigned x=__builtin_bit_cast(unsigned,f); return (u16)((x + 0x7fffu + ((x>>16)&1u))>>16); }
__device__ __forceinline__ unsigned pk2(float a, float b){ return (unsigned)f2bf(a) | ((unsigned)f2bf(b)<<16); }
__device__ __forceinline__ float softplus_f(float v){ return (v>15.f)? v : log1pf(expf(v)); }
__device__ __forceinline__ void unp8(uint4 u, float* f){
  f[0]=bf2f((u16)(u.x&0xffff)); f[1]=bf2f((u16)(u.x>>16));
  f[2]=bf2f((u16)(u.y&0xffff)); f[3]=bf2f((u16)(u.y>>16));
  f[4]=bf2f((u16)(u.z&0xffff)); f[5]=bf2f((u16)(u.z>>16));
  f[6]=bf2f((u16)(u.w&0xffff)); f[7]=bf2f((u16)(u.w>>16));
}

// async global->LDS, 16B per lane; LDS dest is wave-uniform base + lane*16 (m97 pattern)
#define GLOAD16(gptr, lptr) __builtin_amdgcn_global_load_lds( \
    (const __attribute__((address_space(1))) unsigned int*)(gptr), \
    (__attribute__((address_space(3))) unsigned int*)(lptr), 16, 0, 0)

// ---------------- copy h (fp32) -> x (fp32 residual) ----------------
__global__ void k_cvt(const float* __restrict__ hsrc, float* __restrict__ x){
  int i = (blockIdx.x*256 + threadIdx.x)*4;
  *(v4f*)(x + i) = *(const v4f*)(hsrc + i);
}

// ---------------- transpose fp32 (R,C) -> bf16 (C,R) ----------------
__global__ __launch_bounds__(256) void k_transpose(const float* __restrict__ src, u16* __restrict__ dst,
    int R, int C)
{
  __shared__ u16 tl[32][36];
  int r0 = blockIdx.y*32, c0 = blockIdx.x*32;
  int tid = threadIdx.x;
  int r = tid>>3, c4 = (tid&7)*4;
  if (r0 + r < R){
#pragma unroll
    for (int jj=0;jj<4;jj++){
      int c = c0 + c4 + jj;
      tl[r][c4+jj] = (c < C) ? f2bf(src[(size_t)(r0+r)*C + c]) : (u16)0;
    }
  }
  __syncthreads();
  int c = tid>>3, r4 = (tid&7)*4;
  if (c0 + c < C){
#pragma unroll
    for (int jj=0;jj<4;jj++){
      int rr = r0 + r4 + jj;
      if (rr < R) dst[(size_t)(c0+c)*R + rr] = tl[r4+jj][c];
    }
  }
}

// ---------------- rmsnorm: x(fp32) * w(fp32) -> bf16 and/or fp32 ----------------
__global__ __launch_bounds__(256) void k_rmsnorm(const float* __restrict__ x, const float* __restrict__ w,
    u16* __restrict__ obf, float* __restrict__ of32)
{
  int row = blockIdx.x, tid = threadIdx.x;
  const float* xr = x + (size_t)row*1024;
  v4f v = *(const v4f*)(xr + tid*4);
  float ss = v[0]*v[0]+v[1]*v[1]+v[2]*v[2]+v[3]*v[3];
#pragma unroll
  for (int o=1;o<64;o<<=1) ss += __shfl_xor(ss,o);
  __shared__ float red[4];
  if ((tid&63)==0) red[tid>>6] = ss;
  __syncthreads();
  float tot = red[0]+red[1]+red[2]+red[3];
  float rms = rsqrtf(tot*(1.f/1024.f) + 1e-6f);
  v4f wv = *(const v4f*)(w + tid*4);
  float o0=v[0]*rms*wv[0], o1=v[1]*rms*wv[1], o2=v[2]*rms*wv[2], o3=v[3]*rms*wv[3];
  if (obf){
    ushort4 ob = { f2bf(o0), f2bf(o1), f2bf(o2), f2bf(o3) };
    *(ushort4*)(obf + (size_t)row*1024 + tid*4) = ob;
  }
  if (of32){
    v4f ov = {o0,o1,o2,o3};
    *(v4f*)(of32 + (size_t)row*1024 + tid*4) = ov;
  }
}

// ---------------- MFMA GEMM (m97 structure): C = A(MxK,bf16) @ BT(NxK,bf16)^T + bias(fp32)
template<typename OT, bool ADD>
__global__ __launch_bounds__(256) void k_gemm(const u16* __restrict__ A, const u16* __restrict__ BT,
    const float* __restrict__ bias, OT* __restrict__ C, int N, int K)
{
  __shared__ __align__(16) char sraw[32*132*4];   // 16.9 KB; staging uses first 16 KB
  u16* As = (u16*)sraw;            // [128][32] linear
  u16* Bs = As + 128*32;
  const int tid = threadIdx.x;
  const int wave = tid>>6, lane = tid&63, quad = lane>>4, l15 = lane&15;
  const int bm = blockIdx.y*128, bn = blockIdx.x*128;
  const int wm = (wave>>1)*64, wn = (wave&1)*64;
  v4f acc[4][4];
#pragma unroll
  for (int i=0;i<4;i++)
#pragma unroll
    for (int j=0;j<4;j++){ v4f z = {0.f,0.f,0.f,0.f}; acc[i][j]=z; }

  const int srow = wave*32 + (lane>>2);
  const int scol = (lane&3)*8;
  const u16* agp = A  + (size_t)(bm+srow)*K + scol;
  const u16* bgp = BT + (size_t)(bn+srow)*K + scol;
  u16* ldsA = As + (wave*32)*32;
  u16* ldsB = Bs + (wave*32)*32;

  for (int k0=0; k0<K; k0+=32){
    GLOAD16(agp,                ldsA);
    GLOAD16(agp + (size_t)16*K, ldsA + 16*32);
    GLOAD16(bgp,                ldsB);
    GLOAD16(bgp + (size_t)16*K, ldsB + 16*32);
    agp += 32; bgp += 32;
    __syncthreads();
    v8bf af[4], bfr[4];
#pragma unroll
    for (int mi=0;mi<4;mi++) af[mi]  = *(const v8bf*)(As + (wm+mi*16+l15)*32 + quad*8);
#pragma unroll
    for (int ni=0;ni<4;ni++) bfr[ni] = *(const v8bf*)(Bs + (wn+ni*16+l15)*32 + quad*8);
#pragma unroll
    for (int mi=0;mi<4;mi++)
#pragma unroll
      for (int ni=0;ni<4;ni++)
        acc[mi][ni] = __builtin_amdgcn_mfma_f32_16x16x32_bf16(af[mi], bfr[ni], acc[mi][ni], 0,0,0);
    __syncthreads();
  }

  float* eps = (float*)sraw;
  float bz[4];
#pragma unroll
  for (int ni=0;ni<4;ni++) bz[ni] = bias[bn + wn + ni*16 + l15];
  const int erb = (wave>>1)*16 + quad*4;
#pragma unroll
  for (int mi=0;mi<4;mi++){
#pragma unroll
    for (int ni=0;ni<4;ni++){
      v4f v = acc[mi][ni];
#pragma unroll
      for (int r=0;r<4;r++)
        eps[(erb + r)*132 + wn + ni*16 + l15] = v[r] + bz[ni];
    }
    __syncthreads();
    {
      int e = tid>>3, seg = tid&7;
      int grow = bm + (e>>4)*64 + mi*16 + (e&15);
      int gcol = bn + seg*16;
      const float* ep = eps + e*132 + seg*16;
      if constexpr (ADD){
        float* cp = (float*)C + (size_t)grow*N + gcol;
#pragma unroll
        for (int u=0;u<4;u++){
          v4f ov = *(const v4f*)(ep + 4*u);
          v4f cv = *(const v4f*)(cp + 4*u);
          ov += cv;
          *(v4f*)(cp + 4*u) = ov;
        }
      } else {
        u16* cp = (u16*)C + (size_t)grow*N + gcol;
        v4f e0 = *(const v4f*)(ep+0), e1 = *(const v4f*)(ep+4);
        v4f e2 = *(const v4f*)(ep+8), e3 = *(const v4f*)(ep+12);
        uint4 pA = { pk2(e0[0],e0[1]), pk2(e0[2],e0[3]), pk2(e1[0],e1[1]), pk2(e1[2],e1[3]) };
        uint4 pB = { pk2(e2[0],e2[1]), pk2(e2[2],e2[3]), pk2(e3[0],e3[1]), pk2(e3[2],e3[3]) };
        *(uint4*)(cp)   = pA;
        *(uint4*)(cp+8) = pB;
      }
    }
    __syncthreads();
  }
}

// ---------------- dt matmul ----------------
__global__ __launch_bounds__(64) void k_dt(const u16* __restrict__ r, const u16* __restrict__ dtwT,
    float* __restrict__ dtraw)
{
  int row = blockIdx.x, lane = threadIdx.x;
  const u16* rp = r + (size_t)row*1024 + lane*16;
  float rv[16];
  unp8(*(const uint4*)rp, rv);
  unp8(*(const uint4*)(rp+8), rv+8);
  float keep = 0.f;
  for (int hh=0; hh<16; hh++){
    const u16* wp = dtwT + hh*1024 + lane*16;
    float wv[16];
    unp8(*(const uint4*)wp, wv);
    unp8(*(const uint4*)(wp+8), wv+8);
    float sv = 0.f;
#pragma unroll
    for (int j=0;j<16;j++) sv = fmaf(rv[j], wv[j], sv);
#pragma unroll
    for (int o=1;o<64;o<<=1) sv += __shfl_xor(sv, o);
    if (lane==hh) keep = sv;
  }
  if (lane<16) dtraw[(size_t)row*16 + lane] = keep;
}

// ---------------- prep2 per (b,l,h): hdtb = 0.5*dt; dtarr = dt ----------------
__global__ void k_prep2(const float* __restrict__ dtraw, const float* __restrict__ dt_b,
    float* __restrict__ hdtb, float* __restrict__ dtarr)
{
  int i = blockIdx.x*256 + threadIdx.x;
  int h = i & 15;
  float dt0 = fminf(softplus_f(dtraw[i] + dt_b[h]), 30.f);
  hdtb[i] = 0.5f*dt0;
  dtarr[i] = dt0;
}

// ---------------- cs2: per-step dec-folded cos/sin ----------------
__global__ void k_cs2(const float* __restrict__ dtarr, const float* __restrict__ omega,
    const float* __restrict__ A_log, float* __restrict__ dcst, float* __restrict__ dsst)
{
  int i = blockIdx.x*256 + threadIdx.x;
  int q = i & 31, blh = i>>5, h = blh & 15;
  float dt = dtarr[blh];
  float dec = expf(-expf(A_log[h])*dt);
  float sn, cn; __sincosf(dt*omega[q], &sn, &cn);
  dcst[i]=dec*cn; dsst[i]=dec*sn;
}

// ---------------- chunk cumulative transition ----------------
__global__ void k_chunkprod(const float* __restrict__ dtarr, const float* __restrict__ A_log,
    const float* __restrict__ omega, float* __restrict__ prod)
{
  int i = blockIdx.x*256 + threadIdx.x;   // 2048 items: (bh, c)
  int bh = i >> 5, c = i & 31;
  int b = bh >> 4, h = bh & 15;
  size_t base = ((size_t)b*nL + c*T_CH)*16 + h;
  float S = 0.f;
  for (int t=0;t<T_CH;t++) S += dtarr[base + (size_t)t*16];
  float A = -expf(A_log[h]);
  float decF = expf(A*S);
  float* pp = prod + (size_t)i*64;
#pragma unroll
  for (int q=0;q<32;q++){
    float sn, cn; __sincosf(omega[q]*S, &sn, &cn);
    pp[q*2]   = decF*cn;
    pp[q*2+1] = decF*sn;
  }
}

// ---------------- scan phase 1: 4p x 4q register blocking; local scan from zero; store end ----
// thread t: pg=t>>3 (p0=pg*4), qg=t&7 (q0=qg*4).
// hend record (32 f): ((bc*256+t)*32 + pi*8 + jp*4) = {h1[pi][2jp],h2[pi][2jp],h1[pi][2jp+1],h2[pi][2jp+1]}
__global__ __launch_bounds__(256) void k_scan_p1(const u16* __restrict__ xz, const u16* __restrict__ bcb,
    const float* __restrict__ hdtb, const float* __restrict__ dcst, const float* __restrict__ dsst,
    float* __restrict__ hend)
{
  int bc_ = blockIdx.x;
  int bh = bc_ >> 5, c = bc_ & 31;
  int b = bh >> 4, h = bh & 15;
  int t = threadIdx.x, pg = t>>3, qg = t&7;
  int p0 = pg*4, q0 = qg*4;
  size_t rowbase = (size_t)b*nL + c*T_CH;
  __shared__ float sB[T_CH+1][64];      // row i = B at step i-1 (row 0: prev-chunk last or 0)
  __shared__ float sDC[T_CH][32];
  __shared__ float sDS[T_CH][32];
  __shared__ u16  sX[T_CH+1][128];      // row i = x at step i-1
  __shared__ float sHD[T_CH];
  for (int e=t; e<(T_CH+1)*64; e+=256){
    int l = e>>6, n = e&63;
    float v = 0.f;
    if (l) v = bf2f(bcb[(rowbase + l-1)*2048 + h*64 + n]);
    else if (c) v = bf2f(bcb[(rowbase - 1)*2048 + h*64 + n]);
    sB[l][n] = v;
  }
  for (int e=t; e<T_CH*32; e+=256){
    int l = e>>5, q = e&31;
    size_t idx = ((rowbase+l)*16 + h)*32 + q;
    sDC[l][q] = dcst[idx]; sDS[l][q] = dsst[idx];
  }
  for (int e=t; e<(T_CH+1)*64; e+=256){
    int l = e>>6, n2 = (e&63)*2;
    unsigned v = 0;
    if (l || c) v = *(const unsigned*)(xz + (rowbase + l - 1)*4096 + h*128 + n2);
    *(unsigned*)&sX[l][n2] = v;
  }
  if (t < T_CH) sHD[t] = hdtb[(rowbase+t)*16 + h];
  __syncthreads();

  float h1[4][4], h2[4][4], Bp1[4], Bp2[4], xprev[4];
#pragma unroll
  for (int pi=0;pi<4;pi++)
#pragma unroll
    for (int j=0;j<4;j++){ h1[pi][j]=0.f; h2[pi][j]=0.f; }
  { ushort4 xm = *(const ushort4*)&sX[0][p0];
    xprev[0]=bf2f(xm.x); xprev[1]=bf2f(xm.y); xprev[2]=bf2f(xm.z); xprev[3]=bf2f(xm.w); }
  { v4f b1v = *(const v4f*)&sB[0][q0];
    v4f b2v = *(const v4f*)&sB[0][32+q0];
#pragma unroll
    for (int j=0;j<4;j++){ Bp1[j]=b1v[j]; Bp2[j]=b2v[j]; } }

  for (int l=0; l<T_CH; l++){
    float hdt = sHD[l];
    ushort4 xu = *(const ushort4*)&sX[l+1][p0];
    float xv[4] = { bf2f(xu.x), bf2f(xu.y), bf2f(xu.z), bf2f(xu.w) };
    v4f nb1 = *(const v4f*)&sB[l+1][q0];
    v4f nb2 = *(const v4f*)&sB[l+1][32+q0];
    v4f dc  = *(const v4f*)&sDC[l][q0];
    v4f dsn = *(const v4f*)&sDS[l][q0];
#pragma unroll
    for (int pi=0;pi<4;pi++){
      float a = hdt*xprev[pi], bb = hdt*xv[pi];
#pragma unroll
      for (int j=0;j<4;j++){
        float m1 = fmaf(a, Bp1[j], h1[pi][j]);
        float m2 = fmaf(a, Bp2[j], h2[pi][j]);
        h1[pi][j] = fmaf(bb, nb1[j], fmaf(-m2, dsn[j], m1*dc[j]));
        h2[pi][j] = fmaf(bb, nb2[j], fmaf( m1, dsn[j], m2*dc[j]));
      }
    }
#pragma unroll
    for (int pi=0;pi<4;pi++) xprev[pi]=xv[pi];
#pragma unroll
    for (int j=0;j<4;j++){ Bp1[j]=nb1[j]; Bp2[j]=nb2[j]; }
  }
  float* hp = hend + ((size_t)bc_*256 + t)*32;
#pragma unroll
  for (int pi=0;pi<4;pi++)
#pragma unroll
    for (int jp=0;jp<2;jp++){
      v4f o = { h1[pi][2*jp], h2[pi][2*jp], h1[pi][2*jp+1], h2[pi][2*jp+1] };
      *(v4f*)(hp + pi*8 + jp*4) = o;
    }
}

// ---------------- scan phase 2: carry propagation, parallel over (bh x 8 record-slices) -------
__global__ __launch_bounds__(256) void k_scan_p2(float* __restrict__ hend, const float* __restrict__ prod)
{
  int bh = blockIdx.x>>3, slice = blockIdx.x&7;
  int tid = threadIdx.x;
  int rec = slice*32 + (tid>>3);       // original thread index 0..255
  int sub = tid&7;                      // v4f index: pi = sub>>1, jp = sub&1
  int q0 = (rec&7)*4 + (sub&1)*2;       // two consecutive q's in this v4f
  float c1a=0.f,c2a=0.f,c1b=0.f,c2b=0.f;
  for (int c=0;c<C_CH;c++){
    float* hp = hend + (((size_t)(bh*C_CH+c))*256 + rec)*32 + sub*4;
    v4f r = *(const v4f*)hp;
    v4f w = { c1a, c2a, c1b, c2b };
    *(v4f*)hp = w;
    const float* pp = prod + (size_t)(bh*C_CH+c)*64 + q0*2;
    float pr0=pp[0], pi0=pp[1], pr1=pp[2], pi1=pp[3];
    float n1a = fmaf(pr0,c1a, fmaf(-pi0,c2a, r[0]));
    float n2a = fmaf(pr0,c2a, fmaf( pi0,c1a, r[1]));
    float n1b = fmaf(pr1,c1b, fmaf(-pi1,c2b, r[2]));
    float n2b = fmaf(pr1,c2b, fmaf( pi1,c1b, r[3]));
    c1a=n1a; c2a=n2a; c1b=n1b; c2b=n2b;
  }
}

// ---------------- scan phase 3: 4p x 4q; carry-in; fused D-skip + gate -> gbuf bf16 ----------
__global__ __launch_bounds__(256) void k_scan_p3(const u16* __restrict__ xz, const u16* __restrict__ bcb,
    const float* __restrict__ hdtb, const float* __restrict__ dcst, const float* __restrict__ dsst,
    const float* __restrict__ Dsk, const float* __restrict__ hcar, u16* __restrict__ gbuf)
{
  int bc_ = blockIdx.x;
  int bh = bc_ >> 5, c = bc_ & 31;
  int b = bh >> 4, h = bh & 15;
  int t = threadIdx.x, pg = t>>3, qg = t&7;
  int p0 = pg*4, q0 = qg*4;
  size_t rowbase = (size_t)b*nL + c*T_CH;
  __shared__ float sB[T_CH+1][64];
  __shared__ float sC[T_CH][64];
  __shared__ float sDC[T_CH][32];
  __shared__ float sDS[T_CH][32];
  __shared__ u16  sX[T_CH+1][128];
  __shared__ float sHD[T_CH];
  for (int e=t; e<(T_CH+1)*64; e+=256){
    int l = e>>6, n = e&63;
    float v = 0.f;
    if (l) v = bf2f(bcb[(rowbase + l-1)*2048 + h*64 + n]);
    else if (c) v = bf2f(bcb[(rowbase - 1)*2048 + h*64 + n]);
    sB[l][n] = v;
  }
  for (int e=t; e<T_CH*64; e+=256){
    int l = e>>6, n = e&63;
    sC[l][n] = bf2f(bcb[(rowbase + l)*2048 + 1024 + h*64 + n]);
  }
  for (int e=t; e<T_CH*32; e+=256){
    int l = e>>5, q = e&31;
    size_t idx = ((rowbase+l)*16 + h)*32 + q;
    sDC[l][q] = dcst[idx]; sDS[l][q] = dsst[idx];
  }
  for (int e=t; e<(T_CH+1)*64; e+=256){
    int l = e>>6, n2 = (e&63)*2;
    unsigned v = 0;
    if (l || c) v = *(const unsigned*)(xz + (rowbase + l - 1)*4096 + h*128 + n2);
    *(unsigned*)&sX[l][n2] = v;
  }
  if (t < T_CH) sHD[t] = hdtb[(rowbase+t)*16 + h];
  __syncthreads();

  float h1[4][4], h2[4][4], Bp1[4], Bp2[4], xprev[4];
  const float* hp0 = hcar + ((size_t)bc_*256 + t)*32;
#pragma unroll
  for (int pi=0;pi<4;pi++)
#pragma unroll
    for (int jp=0;jp<2;jp++){
      v4f r = *(const v4f*)(hp0 + pi*8 + jp*4);
      h1[pi][2*jp]=r[0]; h2[pi][2*jp]=r[1]; h1[pi][2*jp+1]=r[2]; h2[pi][2*jp+1]=r[3];
    }
  { ushort4 xm = *(const ushort4*)&sX[0][p0];
    xprev[0]=bf2f(xm.x); xprev[1]=bf2f(xm.y); xprev[2]=bf2f(xm.z); xprev[3]=bf2f(xm.w); }
  { v4f b1v = *(const v4f*)&sB[0][q0];
    v4f b2v = *(const v4f*)&sB[0][32+q0];
#pragma unroll
    for (int j=0;j<4;j++){ Bp1[j]=b1v[j]; Bp2[j]=b2v[j]; } }
  float Dskip = Dsk[h];

  for (int l=0; l<T_CH; l++){
    float hdt = sHD[l];
    ushort4 xu = *(const ushort4*)&sX[l+1][p0];
    float xv[4] = { bf2f(xu.x), bf2f(xu.y), bf2f(xu.z), bf2f(xu.w) };
    v4f nb1 = *(const v4f*)&sB[l+1][q0];
    v4f nb2 = *(const v4f*)&sB[l+1][32+q0];
    v4f cc1 = *(const v4f*)&sC[l][q0];
    v4f cc2 = *(const v4f*)&sC[l][32+q0];
    v4f dc  = *(const v4f*)&sDC[l][q0];
    v4f dsn = *(const v4f*)&sDS[l][q0];
    float yred[4];
#pragma unroll
    for (int pi=0;pi<4;pi++){
      float a = hdt*xprev[pi], bb = hdt*xv[pi];
      float ya = 0.f;
#pragma unroll
      for (int j=0;j<4;j++){
        float m1 = fmaf(a, Bp1[j], h1[pi][j]);
        float m2 = fmaf(a, Bp2[j], h2[pi][j]);
        float nh1 = fmaf(bb, nb1[j], fmaf(-m2, dsn[j], m1*dc[j]));
        float nh2 = fmaf(bb, nb2[j], fmaf( m1, dsn[j], m2*dc[j]));
        h1[pi][j]=nh1; h2[pi][j]=nh2;
        ya = fmaf(nh1, cc1[j], fmaf(nh2, cc2[j], ya));
      }
      yred[pi] = ya;
    }
#pragma unroll
    for (int pi=0;pi<4;pi++){
      yred[pi] += __shfl_xor(yred[pi],1);
      yred[pi] += __shfl_xor(yred[pi],2);
      yred[pi] += __shfl_xor(yred[pi],4);
    }
    if (qg==0){
      ushort4 zu = *(const ushort4*)(xz + (rowbase+l)*4096 + 2048 + h*128 + p0);
      float z0=bf2f(zu.x), z1=bf2f(zu.y), z2=bf2f(zu.z), z3=bf2f(zu.w);
      float y0 = fmaf(xv[0], Dskip, yred[0]);
      float y1 = fmaf(xv[1], Dskip, yred[1]);
      float y2 = fmaf(xv[2], Dskip, yred[2]);
      float y3 = fmaf(xv[3], Dskip, yred[3]);
      ushort4 ob;
      ob.x = f2bf(y0*z0/(1.f+expf(-z0)));
      ob.y = f2bf(y1*z1/(1.f+expf(-z1)));
      ob.z = f2bf(y2*z2/(1.f+expf(-z2)));
      ob.w = f2bf(y3*z3/(1.f+expf(-z3)));
      *(ushort4*)(gbuf + (rowbase+l)*2048 + h*128 + p0) = ob;
    }
#pragma unroll
    for (int pi=0;pi<4;pi++) xprev[pi]=xv[pi];
#pragma unroll
    for (int j=0;j<4;j++){ Bp1[j]=nb1[j]; Bp2[j]=nb2[j]; }
  }
}

// ---------------- attention logits ----------------
__global__ __launch_bounds__(256) void k_attn(const float* __restrict__ xn, const float* __restrict__ q,
    float* __restrict__ attn)
{
  int wid = blockIdx.x*4 + (threadIdx.x>>6);
  int lane = threadIdx.x & 63;
  const float* xr = xn + (size_t)wid*1024 + lane*16;
  const float* qr = q + lane*16;
  float sAcc=0.f;
#pragma unroll
  for (int j4=0;j4<4;j4++){
    v4f xv = *(const v4f*)(xr + 4*j4);
    v4f qv = *(const v4f*)(qr + 4*j4);
#pragma unroll
    for (int j=0;j<4;j++) sAcc = fmaf(xv[j], qv[j], sAcc);
  }
#pragma unroll
  for (int o=1;o<64;o<<=1) sAcc += __shfl_xor(sAcc,o);
  if (lane==0) attn[wid] = sAcc*(1.f/32.f);
}

// ---------------- softmax over L (in place) ----------------
__global__ __launch_bounds__(1024) void k_smax(float* __restrict__ attn)
{
  int b = blockIdx.x, t = threadIdx.x;
  __shared__ float red[16];
  __shared__ float red2[16];
  float av = attn[b*1024 + t];
  float m = av;
#pragma unroll
  for (int o=1;o<64;o<<=1) m = fmaxf(m, __shfl_xor(m,o));
  if ((t&63)==0) red[t>>6] = m;
  __syncthreads();
  float bm = red[0];
  for (int jj=1;jj<16;jj++) bm = fmaxf(bm, red[jj]);
  float e = expf(av - bm);
  float sm = e;
#pragma unroll
  for (int o=1;o<64;o<<=1) sm += __shfl_xor(sm,o);
  if ((t&63)==0) red2[t>>6] = sm;
  __syncthreads();
  float tot = 0.f;
  for (int jj=0;jj<16;jj++) tot += red2[jj];
  attn[b*1024 + t] = e/tot;
}

// ---------------- pooled[b,w] ----------------
__global__ __launch_bounds__(256) void k_pool2(const float* __restrict__ attnp, const float* __restrict__ xn,
    float* __restrict__ pooled)
{
  int wsl = blockIdx.x, b = blockIdx.y, t = threadIdx.x;
  int w = wsl*64 + (t&63), ls = t>>6;
  float acc = 0.f;
  for (int l=ls; l<1024; l+=4)
    acc = fmaf(attnp[b*1024 + l], xn[((size_t)b*1024 + l)*1024 + w], acc);
  __shared__ float red[256];
  red[t] = acc;
  __syncthreads();
  if (t<64)
    pooled[(size_t)b*1024 + wsl*64 + t] = red[t]+red[t+64]+red[t+128]+red[t+192];
}

// ---------------- heads ----------------
__global__ __launch_bounds__(256) void k_heads(const float* __restrict__ pooled,
    const float* __restrict__ fw, const float* __restrict__ fb,
    const float* __restrict__ bw, const float* __restrict__ bb, float* __restrict__ outp)
{
  int o = blockIdx.x, t = threadIdx.x;
  int b, j, NJ; const float *Wp, *Bp;
  if (o < 16){ b = o>>2; j = o&3; NJ = 4; Wp = fw; Bp = fb; }
  else { int oo = o-16; b = oo/20; j = oo - b*20; NJ = 20; Wp = bw; Bp = bb; }
  v4f pv = *(const v4f*)(pooled + (size_t)b*1024 + t*4);
  int w0 = t*4;
  float sAcc = pv[0]*Wp[(size_t)(w0+0)*NJ + j] + pv[1]*Wp[(size_t)(w0+1)*NJ + j]
             + pv[2]*Wp[(size_t)(w0+2)*NJ + j] + pv[3]*Wp[(size_t)(w0+3)*NJ + j];
#pragma unroll
  for (int of=1; of<64; of<<=1) sAcc += __shfl_xor(sAcc, of);
  __shared__ float red[4];
  if ((t&63)==0) red[t>>6] = sAcc;
  __syncthreads();
  if (t==0) outp[o] = red[0]+red[1]+red[2]+red[3] + Bp[j];
}

extern "C" void kernel_launch(void* const* d_in, const int* in_sizes, int n_in,
                              void* d_out, int out_size, void* d_ws, size_t ws_size,
                              hipStream_t stream)
{
  (void)n_in; (void)out_size;
  int base = (in_sizes[2] >= 1000000) ? 1 : 2;
  const float* h_in   = (const float*)d_in[0];
  const float* ln_w   = (const float*)d_in[base+0];
  const float* in_w   = (const float*)d_in[base+1];
  const float* in_b   = (const float*)d_in[base+2];
  const float* dt_w   = (const float*)d_in[base+3];
  const float* dt_b   = (const float*)d_in[base+4];
  const float* bc_w   = (const float*)d_in[base+5];
  const float* bc_b   = (const float*)d_in[base+6];
  const float* A_log  = (const float*)d_in[base+7];
  const float* omega  = (const float*)d_in[base+8];
  const float* D_skip = (const float*)d_in[base+9];
  const float* out_w  = (const float*)d_in[base+10];
  const float* out_b  = (const float*)d_in[base+11];
  const float* fln_w  = (const float*)d_in[base+12];
  const float* queries= (const float*)d_in[base+13];
  const float* feat_w = (const float*)d_in[base+14];
  const float* feat_b = (const float*)d_in[base+15];
  const float* bias_w = (const float*)d_in[base+16];
  const float* bias_b = (const float*)d_in[base+17];

  char* w0 = (char*)d_ws;
  size_t off = 0;
  auto take = [&](size_t bytes)->char*{ char* pp = w0 + off; off += (bytes + 255) & ~(size_t)255; return pp; };
  u16* wT_in  = (u16*)take((size_t)4096*1024*2);
  u16* wT_bc  = (u16*)take((size_t)2048*1024*2);
  u16* wT_out = (u16*)take((size_t)1024*2048*2);
  u16* wT_dt  = (u16*)take((size_t)16*1024*2);
  float* x    = (float*)take((size_t)4194304*4);
  u16* rbf    = (u16*)take((size_t)4194304*2);
  u16* xz     = (u16*)take((size_t)16777216*2);
  u16* bcb    = (u16*)take((size_t)8388608*2);
  char* bigscratch = take((size_t)67108864);     // hendb (64MB) during scan; xn (16MB) after
  u16* gbuf   = (u16*)take((size_t)8388608*2);
  float* cst  = (float*)take((size_t)2097152*4);
  float* sst  = (float*)take((size_t)2097152*4);
  float* dtraw= (float*)take((size_t)65536*4);
  float* dtarr= (float*)take((size_t)65536*4);
  float* hdtb = (float*)take((size_t)65536*4);
  float* attnb= (float*)take((size_t)4096*4);
  float* pool = (float*)take((size_t)4096*4);
  float* prodb= (float*)take((size_t)2048*64*4);
  if (off > ws_size) return;
  float* hendb = (float*)bigscratch;
  float* xn    = (float*)bigscratch;   // alias (hendb dead after last p3)

  k_cvt<<<4096,256,0,stream>>>(h_in, x);
  for (int d=0; d<4; d++){
    k_transpose<<<dim3(128,32),256,0,stream>>>(in_w + (size_t)d*1024*4096, wT_in, 1024, 4096);
    k_transpose<<<dim3(64,32),256,0,stream>>>(bc_w + (size_t)d*1024*2048, wT_bc, 1024, 2048);
    k_transpose<<<dim3(32,64),256,0,stream>>>(out_w + (size_t)d*2048*1024, wT_out, 2048, 1024);
    k_transpose<<<dim3(1,32),256,0,stream>>>(dt_w + (size_t)d*1024*16, wT_dt, 1024, 16);
    k_rmsnorm<<<4096,256,0,stream>>>(x, ln_w + d*1024, rbf, (float*)nullptr);
    k_gemm<u16,false><<<dim3(32,32),256,0,stream>>>(rbf, wT_in, in_b + d*4096, xz, 4096, 1024);
    k_gemm<u16,false><<<dim3(16,32),256,0,stream>>>(rbf, wT_bc, bc_b + d*2048, bcb, 2048, 1024);
    k_dt<<<4096,64,0,stream>>>(rbf, wT_dt, dtraw);
    k_prep2<<<256,256,0,stream>>>(dtraw, dt_b + d*16, hdtb, dtarr);
    k_cs2<<<8192,256,0,stream>>>(dtarr, omega + d*32, A_log + d*16, cst, sst);
    k_chunkprod<<<8,256,0,stream>>>(dtarr, A_log + d*16, omega + d*32, prodb);
    k_scan_p1<<<2048,256,0,stream>>>(xz, bcb, hdtb, cst, sst, hendb);
    k_scan_p2<<<512,256,0,stream>>>(hendb, prodb);
    k_scan_p3<<<2048,256,0,stream>>>(xz, bcb, hdtb, cst, sst, D_skip + d*16, hendb, gbuf);
    k_gemm<float,true><<<dim3(8,32),256,0,stream>>>(gbuf, wT_out, out_b + d*1024, x, 1024, 2048);
  }
  k_rmsnorm<<<4096,256,0,stream>>>(x, fln_w, (u16*)nullptr, xn);
  k_attn<<<1024,256,0,stream>>>(xn, queries, attnb);
  k_smax<<<4,1024,0,stream>>>(attnb);
  k_pool2<<<dim3(16,4),256,0,stream>>>(attnb, xn, pool);
  k_heads<<<96,256,0,stream>>>(pool, feat_w, feat_b, bias_w, bias_b, (float*)d_out);
}

// Round 6
// 1811.184 us; speedup vs baseline: 3.1874x; 1.1113x over previous
//
#include <hip/hip_runtime.h>
#include <math.h>

typedef unsigned short u16;
typedef float v4f  __attribute__((ext_vector_type(4)));
typedef __bf16 v8bf __attribute__((ext_vector_type(8)));

enum { nB=4, nL=1024, nW=1024, nH=16, nN=64, nE=2048, nP=128, nNH=32, nDEPTH=4 };
enum { C_CH=16, T_CH=64 };   // chunked scan: 16 chunks of 64 steps

__device__ __forceinline__ float bf2f(u16 u){ unsigned v=((unsigned)u)<<16; return __builtin_bit_cast(float,v); }
__device__ __forceinline__ u16 f2bf(float f){ unsigned x=__builtin_bit_cast(unsigned,f); return (u16)((x + 0x7fffu + ((x>>16)&1u))>>16); }
__device__ __forceinline__ unsigned pk2(float a, float b){ return (unsigned)f2bf(a) | ((unsigned)f2bf(b)<<16); }
__device__ __forceinline__ float softplus_f(float v){ return (v>15.f)? v : log1pf(expf(v)); }
__device__ __forceinline__ void unp8(uint4 u, float* f){
  f[0]=bf2f((u16)(u.x&0xffff)); f[1]=bf2f((u16)(u.x>>16));
  f[2]=bf2f((u16)(u.y&0xffff)); f[3]=bf2f((u16)(u.y>>16));
  f[4]=bf2f((u16)(u.z&0xffff)); f[5]=bf2f((u16)(u.z>>16));
  f[6]=bf2f((u16)(u.w&0xffff)); f[7]=bf2f((u16)(u.w>>16));
}

// async global->LDS, 16B per lane; LDS dest is wave-uniform base + lane*16 (m97 pattern)
#define GLOAD16(gptr, lptr) __builtin_amdgcn_global_load_lds( \
    (const __attribute__((address_space(1))) unsigned int*)(gptr), \
    (__attribute__((address_space(3))) unsigned int*)(lptr), 16, 0, 0)

// ---------------- copy h (fp32) -> x (fp32 residual) ----------------
__global__ void k_cvt(const float* __restrict__ hsrc, float* __restrict__ x){
  int i = (blockIdx.x*256 + threadIdx.x)*4;
  *(v4f*)(x + i) = *(const v4f*)(hsrc + i);
}

// ---------------- transpose fp32 (R,C) -> bf16 (C,R) ----------------
__global__ __launch_bounds__(256) void k_transpose(const float* __restrict__ src, u16* __restrict__ dst,
    int R, int C)
{
  __shared__ u16 tl[32][36];
  int r0 = blockIdx.y*32, c0 = blockIdx.x*32;
  int tid = threadIdx.x;
  int r = tid>>3, c4 = (tid&7)*4;
  if (r0 + r < R){
#pragma unroll
    for (int jj=0;jj<4;jj++){
      int c = c0 + c4 + jj;
      tl[r][c4+jj] = (c < C) ? f2bf(src[(size_t)(r0+r)*C + c]) : (u16)0;
    }
  }
  __syncthreads();
  int c = tid>>3, r4 = (tid&7)*4;
  if (c0 + c < C){
#pragma unroll
    for (int jj=0;jj<4;jj++){
      int rr = r0 + r4 + jj;
      if (rr < R) dst[(size_t)(c0+c)*R + rr] = tl[r4+jj][c];
    }
  }
}

// ---------------- rmsnorm: x(fp32) * w(fp32) -> bf16 and/or fp32 ----------------
__global__ __launch_bounds__(256) void k_rmsnorm(const float* __restrict__ x, const float* __restrict__ w,
    u16* __restrict__ obf, float* __restrict__ of32)
{
  int row = blockIdx.x, tid = threadIdx.x;
  const float* xr = x + (size_t)row*1024;
  v4f v = *(const v4f*)(xr + tid*4);
  float ss = v[0]*v[0]+v[1]*v[1]+v[2]*v[2]+v[3]*v[3];
#pragma unroll
  for (int o=1;o<64;o<<=1) ss += __shfl_xor(ss,o);
  __shared__ float red[4];
  if ((tid&63)==0) red[tid>>6] = ss;
  __syncthreads();
  float tot = red[0]+red[1]+red[2]+red[3];
  float rms = rsqrtf(tot*(1.f/1024.f) + 1e-6f);
  v4f wv = *(const v4f*)(w + tid*4);
  float o0=v[0]*rms*wv[0], o1=v[1]*rms*wv[1], o2=v[2]*rms*wv[2], o3=v[3]*rms*wv[3];
  if (obf){
    ushort4 ob = { f2bf(o0), f2bf(o1), f2bf(o2), f2bf(o3) };
    *(ushort4*)(obf + (size_t)row*1024 + tid*4) = ob;
  }
  if (of32){
    v4f ov = {o0,o1,o2,o3};
    *(v4f*)(of32 + (size_t)row*1024 + tid*4) = ov;
  }
}

// ---------------- MFMA GEMM (m97 structure): C = A(MxK,bf16) @ BT(NxK,bf16)^T + bias(fp32)
template<typename OT, bool ADD>
__global__ __launch_bounds__(256) void k_gemm(const u16* __restrict__ A, const u16* __restrict__ BT,
    const float* __restrict__ bias, OT* __restrict__ C, int N, int K)
{
  __shared__ __align__(16) char sraw[32*132*4];   // 16.9 KB; staging uses first 16 KB
  u16* As = (u16*)sraw;            // [128][32] linear
  u16* Bs = As + 128*32;
  const int tid = threadIdx.x;
  const int wave = tid>>6, lane = tid&63, quad = lane>>4, l15 = lane&15;
  const int bm = blockIdx.y*128, bn = blockIdx.x*128;
  const int wm = (wave>>1)*64, wn = (wave&1)*64;
  v4f acc[4][4];
#pragma unroll
  for (int i=0;i<4;i++)
#pragma unroll
    for (int j=0;j<4;j++){ v4f z = {0.f,0.f,0.f,0.f}; acc[i][j]=z; }

  const int srow = wave*32 + (lane>>2);
  const int scol = (lane&3)*8;
  const u16* agp = A  + (size_t)(bm+srow)*K + scol;
  const u16* bgp = BT + (size_t)(bn+srow)*K + scol;
  u16* ldsA = As + (wave*32)*32;
  u16* ldsB = Bs + (wave*32)*32;

  for (int k0=0; k0<K; k0+=32){
    GLOAD16(agp,                ldsA);
    GLOAD16(agp + (size_t)16*K, ldsA + 16*32);
    GLOAD16(bgp,                ldsB);
    GLOAD16(bgp + (size_t)16*K, ldsB + 16*32);
    agp += 32; bgp += 32;
    __syncthreads();
    v8bf af[4], bfr[4];
#pragma unroll
    for (int mi=0;mi<4;mi++) af[mi]  = *(const v8bf*)(As + (wm+mi*16+l15)*32 + quad*8);
#pragma unroll
    for (int ni=0;ni<4;ni++) bfr[ni] = *(const v8bf*)(Bs + (wn+ni*16+l15)*32 + quad*8);
#pragma unroll
    for (int mi=0;mi<4;mi++)
#pragma unroll
      for (int ni=0;ni<4;ni++)
        acc[mi][ni] = __builtin_amdgcn_mfma_f32_16x16x32_bf16(af[mi], bfr[ni], acc[mi][ni], 0,0,0);
    __syncthreads();
  }

  float* eps = (float*)sraw;
  float bz[4];
#pragma unroll
  for (int ni=0;ni<4;ni++) bz[ni] = bias[bn + wn + ni*16 + l15];
  const int erb = (wave>>1)*16 + quad*4;
#pragma unroll
  for (int mi=0;mi<4;mi++){
#pragma unroll
    for (int ni=0;ni<4;ni++){
      v4f v = acc[mi][ni];
#pragma unroll
      for (int r=0;r<4;r++)
        eps[(erb + r)*132 + wn + ni*16 + l15] = v[r] + bz[ni];
    }
    __syncthreads();
    {
      int e = tid>>3, seg = tid&7;
      int grow = bm + (e>>4)*64 + mi*16 + (e&15);
      int gcol = bn + seg*16;
      const float* ep = eps + e*132 + seg*16;
      if constexpr (ADD){
        float* cp = (float*)C + (size_t)grow*N + gcol;
#pragma unroll
        for (int u=0;u<4;u++){
          v4f ov = *(const v4f*)(ep + 4*u);
          v4f cv = *(const v4f*)(cp + 4*u);
          ov += cv;
          *(v4f*)(cp + 4*u) = ov;
        }
      } else {
        u16* cp = (u16*)C + (size_t)grow*N + gcol;
        v4f e0 = *(const v4f*)(ep+0), e1 = *(const v4f*)(ep+4);
        v4f e2 = *(const v4f*)(ep+8), e3 = *(const v4f*)(ep+12);
        uint4 pA = { pk2(e0[0],e0[1]), pk2(e0[2],e0[3]), pk2(e1[0],e1[1]), pk2(e1[2],e1[3]) };
        uint4 pB = { pk2(e2[0],e2[1]), pk2(e2[2],e2[3]), pk2(e3[0],e3[1]), pk2(e3[2],e3[3]) };
        *(uint4*)(cp)   = pA;
        *(uint4*)(cp+8) = pB;
      }
    }
    __syncthreads();
  }
}

// ---------------- dt matmul ----------------
__global__ __launch_bounds__(64) void k_dt(const u16* __restrict__ r, const u16* __restrict__ dtwT,
    float* __restrict__ dtraw)
{
  int row = blockIdx.x, lane = threadIdx.x;
  const u16* rp = r + (size_t)row*1024 + lane*16;
  float rv[16];
  unp8(*(const uint4*)rp, rv);
  unp8(*(const uint4*)(rp+8), rv+8);
  float keep = 0.f;
  for (int hh=0; hh<16; hh++){
    const u16* wp = dtwT + hh*1024 + lane*16;
    float wv[16];
    unp8(*(const uint4*)wp, wv);
    unp8(*(const uint4*)(wp+8), wv+8);
    float sv = 0.f;
#pragma unroll
    for (int j=0;j<16;j++) sv = fmaf(rv[j], wv[j], sv);
#pragma unroll
    for (int o=1;o<64;o<<=1) sv += __shfl_xor(sv, o);
    if (lane==hh) keep = sv;
  }
  if (lane<16) dtraw[(size_t)row*16 + lane] = keep;
}

// ---------------- prep2 per (b,l,h): hdtb = 0.5*dt; dtarr = dt ----------------
__global__ void k_prep2(const float* __restrict__ dtraw, const float* __restrict__ dt_b,
    float* __restrict__ hdtb, float* __restrict__ dtarr)
{
  int i = blockIdx.x*256 + threadIdx.x;
  int h = i & 15;
  float dt0 = fminf(softplus_f(dtraw[i] + dt_b[h]), 30.f);
  hdtb[i] = 0.5f*dt0;
  dtarr[i] = dt0;
}

// ---------------- cs2: per-step dec-folded cos/sin ----------------
__global__ void k_cs2(const float* __restrict__ dtarr, const float* __restrict__ omega,
    const float* __restrict__ A_log, float* __restrict__ dcst, float* __restrict__ dsst)
{
  int i = blockIdx.x*256 + threadIdx.x;
  int q = i & 31, blh = i>>5, h = blh & 15;
  float dt = dtarr[blh];
  float dec = expf(-expf(A_log[h])*dt);
  float sn, cn; __sincosf(dt*omega[q], &sn, &cn);
  dcst[i]=dec*cn; dsst[i]=dec*sn;
}

// ---------------- chunk cumulative transition: prod[(bh*C+c)*64 + 2q+{0,1}] ----------------
__global__ void k_chunkprod(const float* __restrict__ dtarr, const float* __restrict__ A_log,
    const float* __restrict__ omega, float* __restrict__ prod)
{
  int i = blockIdx.x*256 + threadIdx.x;   // 1024 items: (bh, c)
  int bh = i >> 4, c = i & 15;
  int b = bh >> 4, h = bh & 15;
  size_t base = ((size_t)b*nL + c*T_CH)*16 + h;
  float S = 0.f;
  for (int t=0;t<T_CH;t++) S += dtarr[base + (size_t)t*16];
  float A = -expf(A_log[h]);
  float decF = expf(A*S);
  float* pp = prod + (size_t)i*64;
#pragma unroll
  for (int q=0;q<32;q++){
    float sn, cn; __sincosf(omega[q]*S, &sn, &cn);
    pp[q*2]   = decF*cn;
    pp[q*2+1] = decF*sn;
  }
}

// ---------------- scan phase 1: local scan from zero; writes ylocal AND end-state ----
// thread t: p = t>>1, half = t&1, q0 = half*16 (16 q's per thread, 1 shuffle reduce).
// hend record: ((bc*256+t)*32 + 4*j4) = {h1[2j4],h2[2j4],h1[2j4+1],h2[2j4+1]}, q = q0+j
__global__ __launch_bounds__(256) void k_scan_p1(const u16* __restrict__ xz, const u16* __restrict__ bcb,
    const float* __restrict__ hdtb, const float* __restrict__ dcst, const float* __restrict__ dsst,
    float* __restrict__ hend, float* __restrict__ ylocal)
{
  int bc_ = blockIdx.x;               // bh*16 + c
  int bh = bc_ >> 4, c = bc_ & 15;
  int b = bh >> 4, h = bh & 15;
  int t = threadIdx.x, p = t>>1, half = t&1, q0 = half*16;
  size_t rowbase = (size_t)b*nL + c*T_CH;
  __shared__ float sB[T_CH+1][64];     // row i = B at step i-1 (row 0: prev-chunk last or 0)
  __shared__ float sC[T_CH][64];
  __shared__ float sDC[T_CH][32];
  __shared__ float sDS[T_CH][32];
  for (int e=t; e<(T_CH+1)*64; e+=256){
    int l = e>>6, n = e&63;
    float v = 0.f;
    if (l) v = bf2f(bcb[(rowbase + l-1)*2048 + h*64 + n]);
    else if (c) v = bf2f(bcb[(rowbase - 1)*2048 + h*64 + n]);
    sB[l][n] = v;
  }
  for (int e=t; e<T_CH*64; e+=256){
    int l = e>>6, n = e&63;
    sC[l][n] = bf2f(bcb[(rowbase + l)*2048 + 1024 + h*64 + n]);
  }
  for (int e=t; e<T_CH*32; e+=256){
    int l = e>>5, q = e&31;
    size_t idx = ((rowbase+l)*16 + h)*32 + q;
    sDC[l][q] = dcst[idx]; sDS[l][q] = dsst[idx];
  }
  __syncthreads();
  float h1[16], h2[16], B1p[16], B2p[16];
#pragma unroll
  for (int j=0;j<16;j++){ h1[j]=0.f; h2[j]=0.f; }
  { v4f b1a = *(const v4f*)&sB[0][q0];
    v4f b1b = *(const v4f*)&sB[0][q0+4];
    v4f b1c = *(const v4f*)&sB[0][q0+8];
    v4f b1d = *(const v4f*)&sB[0][q0+12];
#pragma unroll
    for (int j=0;j<4;j++){ B1p[j]=b1a[j]; B1p[4+j]=b1b[j]; B1p[8+j]=b1c[j]; B1p[12+j]=b1d[j]; }
    v4f b2a = *(const v4f*)&sB[0][32+q0];
    v4f b2b = *(const v4f*)&sB[0][32+q0+4];
    v4f b2c = *(const v4f*)&sB[0][32+q0+8];
    v4f b2d = *(const v4f*)&sB[0][32+q0+12];
#pragma unroll
    for (int j=0;j<4;j++){ B2p[j]=b2a[j]; B2p[4+j]=b2b[j]; B2p[8+j]=b2c[j]; B2p[12+j]=b2d[j]; }
  }
  float xprev = c ? bf2f(xz[(rowbase-1)*4096 + h*128 + p]) : 0.f;
  const u16* xp = xz + rowbase*4096 + h*128 + p;
  const float* scp = hdtb + rowbase*16 + h;
  float* yp = ylocal + rowbase*2048 + h*128 + p;
  for (int l=0; l<T_CH; l++){
    float hdt = *scp;
    float xv = bf2f(*xp);
    float a = hdt*xprev, bb = hdt*xv;
    float yacc = 0.f;
#pragma unroll
    for (int j4=0;j4<4;j4++){
      v4f Bn1 = *(const v4f*)&sB[l+1][q0+4*j4];
      v4f Bn2 = *(const v4f*)&sB[l+1][32+q0+4*j4];
      v4f C1  = *(const v4f*)&sC[l][q0+4*j4];
      v4f C2  = *(const v4f*)&sC[l][32+q0+4*j4];
      v4f dc  = *(const v4f*)&sDC[l][q0+4*j4];
      v4f dsn = *(const v4f*)&sDS[l][q0+4*j4];
#pragma unroll
      for (int j=0;j<4;j++){
        int jj = 4*j4+j;
        float m1 = fmaf(a, B1p[jj], h1[jj]);
        float m2 = fmaf(a, B2p[jj], h2[jj]);
        float nh1 = fmaf(bb, Bn1[j], fmaf(-m2, dsn[j], m1*dc[j]));
        float nh2 = fmaf(bb, Bn2[j], fmaf( m1, dsn[j], m2*dc[j]));
        h1[jj]=nh1; h2[jj]=nh2;
        B1p[jj]=Bn1[j]; B2p[jj]=Bn2[j];
        yacc = fmaf(nh1, C1[j], fmaf(nh2, C2[j], yacc));
      }
    }
    xprev = xv;
    yacc += __shfl_xor(yacc, 1);
    if (half==0) *yp = yacc;            // ylocal: no D-skip, no carry term
    xp += 4096; scp += 16; yp += 2048;
  }
  float* hp = hend + ((size_t)bc_*256 + t)*32;
#pragma unroll
  for (int j4=0;j4<8;j4++){
    v4f o = { h1[2*j4], h2[2*j4], h1[2*j4+1], h2[2*j4+1] };
    *(v4f*)(hp + 4*j4) = o;
  }
}

// ---------------- scan phase 2: carry propagation, parallel over (bh x 8 record-slices) ------
// record rec ~ p1 thread t; v4f sub: q = (rec&1)*16 + sub*2 + {0,1}
__global__ __launch_bounds__(256) void k_scan_p2(float* __restrict__ hend, const float* __restrict__ prod)
{
  int bh = blockIdx.x>>3, slice = blockIdx.x&7;
  int tid = threadIdx.x;
  int rec = slice*32 + (tid>>3);
  int sub = tid&7;
  int qa = (rec&1)*16 + sub*2;
  float c1a=0.f,c2a=0.f,c1b=0.f,c2b=0.f;
  for (int c=0;c<C_CH;c++){
    float* hp = hend + (((size_t)(bh*C_CH+c))*256 + rec)*32 + sub*4;
    v4f r = *(const v4f*)hp;
    v4f w = { c1a, c2a, c1b, c2b };
    *(v4f*)hp = w;
    const float* pp = prod + (size_t)(bh*C_CH+c)*64 + qa*2;
    float pr0=pp[0], pi0=pp[1], pr1=pp[2], pi1=pp[3];
    float n1a = fmaf(pr0,c1a, fmaf(-pi0,c2a, r[0]));
    float n2a = fmaf(pr0,c2a, fmaf( pi0,c1a, r[1]));
    float n1b = fmaf(pr1,c1b, fmaf(-pi1,c2b, r[2]));
    float n2b = fmaf(pr1,c2b, fmaf( pi1,c1b, r[3]));
    c1a=n1a; c2a=n2a; c1b=n1b; c2b=n2b;
  }
}

// ---------------- k_corr: y = ylocal + Re(carry . D_l) + Dskip*x; gate -> gbuf ----------------
// D_l[q] = exp(A*S_l) * e^{i w_q S_l} * conj(C_l[q]), S_l = inclusive prefix sum of dt in chunk.
__global__ __launch_bounds__(256) void k_corr(const u16* __restrict__ xz, const u16* __restrict__ bcb,
    const float* __restrict__ dtarr, const float* __restrict__ A_log, const float* __restrict__ omega,
    const float* __restrict__ Dsk, const float* __restrict__ hcar, const float* __restrict__ ylocal,
    u16* __restrict__ gbuf)
{
  int bc_ = blockIdx.x;               // bh*16 + c
  int bh = bc_ >> 4, c = bc_ & 15;
  int b = bh >> 4, h = bh & 15;
  int t = threadIdx.x, p = t>>1, qh = t&1, q0 = qh*16;
  size_t rowbase = (size_t)b*nL + c*T_CH;
  __shared__ float sDr[T_CH][32];
  __shared__ float sDi[T_CH][32];
  __shared__ float sS[T_CH];
  if (t < 64){
    float v = dtarr[(rowbase+t)*16 + h];
#pragma unroll
    for (int j=1;j<64;j<<=1){
      float o = __shfl_up(v, j);
      if (t >= j) v += o;
    }
    sS[t] = v;
  }
  __syncthreads();
  float A = -expf(A_log[h]);
  for (int e=t; e<T_CH*32; e+=256){
    int l = e>>5, q = e&31;
    float S = sS[l];
    float sn, cn; __sincosf(omega[q]*S, &sn, &cn);
    float dA = expf(A*S);
    float Ar = dA*cn, Ai = dA*sn;
    float C1 = bf2f(bcb[(rowbase+l)*2048 + 1024 + h*64 + q]);
    float C2 = bf2f(bcb[(rowbase+l)*2048 + 1024 + h*64 + 32 + q]);
    sDr[l][q] = Ar*C1 + Ai*C2;
    sDi[l][q] = Ai*C1 - Ar*C2;
  }
  __syncthreads();
  float c1[16], c2[16];
  const float* hp0 = hcar + ((size_t)bc_*256 + t)*32;
#pragma unroll
  for (int j4=0;j4<8;j4++){
    v4f r = *(const v4f*)(hp0 + 4*j4);
    c1[2*j4]=r[0]; c2[2*j4]=r[1]; c1[2*j4+1]=r[2]; c2[2*j4+1]=r[3];
  }
  float Dskip = Dsk[h];
  const float* yl = ylocal + rowbase*2048 + h*128 + p;
  const u16* xp = xz + rowbase*4096 + h*128 + p;
  const u16* zp = xp + 2048;
  u16* gp = gbuf + rowbase*2048 + h*128 + p;
  for (int l=0; l<T_CH; l++){
    float corr = 0.f;
#pragma unroll
    for (int j4=0;j4<4;j4++){
      v4f dr = *(const v4f*)&sDr[l][q0+4*j4];
      v4f di = *(const v4f*)&sDi[l][q0+4*j4];
#pragma unroll
      for (int j=0;j<4;j++){
        int jj = 4*j4+j;
        corr = fmaf(c1[jj], dr[j], corr);
        corr = fmaf(-c2[jj], di[j], corr);
      }
    }
    corr += __shfl_xor(corr, 1);
    if (qh==0){
      float xv = bf2f(*xp);
      float zv = bf2f(*zp);
      float yv = fmaf(xv, Dskip, yl[0] + corr);
      float g = yv*zv/(1.f+expf(-zv));
      *gp = f2bf(g);
    }
    yl += 2048; xp += 4096; zp += 4096; gp += 2048;
  }
}

// ---------------- attention logits ----------------
__global__ __launch_bounds__(256) void k_attn(const float* __restrict__ xn, const float* __restrict__ q,
    float* __restrict__ attn)
{
  int wid = blockIdx.x*4 + (threadIdx.x>>6);
  int lane = threadIdx.x & 63;
  const float* xr = xn + (size_t)wid*1024 + lane*16;
  const float* qr = q + lane*16;
  float sAcc=0.f;
#pragma unroll
  for (int j4=0;j4<4;j4++){
    v4f xv = *(const v4f*)(xr + 4*j4);
    v4f qv = *(const v4f*)(qr + 4*j4);
#pragma unroll
    for (int j=0;j<4;j++) sAcc = fmaf(xv[j], qv[j], sAcc);
  }
#pragma unroll
  for (int o=1;o<64;o<<=1) sAcc += __shfl_xor(sAcc,o);
  if (lane==0) attn[wid] = sAcc*(1.f/32.f);
}

// ---------------- softmax over L (in place) ----------------
__global__ __launch_bounds__(1024) void k_smax(float* __restrict__ attn)
{
  int b = blockIdx.x, t = threadIdx.x;
  __shared__ float red[16];
  __shared__ float red2[16];
  float av = attn[b*1024 + t];
  float m = av;
#pragma unroll
  for (int o=1;o<64;o<<=1) m = fmaxf(m, __shfl_xor(m,o));
  if ((t&63)==0) red[t>>6] = m;
  __syncthreads();
  float bm = red[0];
  for (int jj=1;jj<16;jj++) bm = fmaxf(bm, red[jj]);
  float e = expf(av - bm);
  float sm = e;
#pragma unroll
  for (int o=1;o<64;o<<=1) sm += __shfl_xor(sm,o);
  if ((t&63)==0) red2[t>>6] = sm;
  __syncthreads();
  float tot = 0.f;
  for (int jj=0;jj<16;jj++) tot += red2[jj];
  attn[b*1024 + t] = e/tot;
}

// ---------------- pooled[b,w] ----------------
__global__ __launch_bounds__(256) void k_pool2(const float* __restrict__ attnp, const float* __restrict__ xn,
    float* __restrict__ pooled)
{
  int wsl = blockIdx.x, b = blockIdx.y, t = threadIdx.x;
  int w = wsl*64 + (t&63), ls = t>>6;
  float acc = 0.f;
  for (int l=ls; l<1024; l+=4)
    acc = fmaf(attnp[b*1024 + l], xn[((size_t)b*1024 + l)*1024 + w], acc);
  __shared__ float red[256];
  red[t] = acc;
  __syncthreads();
  if (t<64)
    pooled[(size_t)b*1024 + wsl*64 + t] = red[t]+red[t+64]+red[t+128]+red[t+192];
}

// ---------------- heads ----------------
__global__ __launch_bounds__(256) void k_heads(const float* __restrict__ pooled,
    const float* __restrict__ fw, const float* __restrict__ fb,
    const float* __restrict__ bw, const float* __restrict__ bb, float* __restrict__ outp)
{
  int o = blockIdx.x, t = threadIdx.x;
  int b, j, NJ; const float *Wp, *Bp;
  if (o < 16){ b = o>>2; j = o&3; NJ = 4; Wp = fw; Bp = fb; }
  else { int oo = o-16; b = oo/20; j = oo - b*20; NJ = 20; Wp = bw; Bp = bb; }
  v4f pv = *(const v4f*)(pooled + (size_t)b*1024 + t*4);
  int w0 = t*4;
  float sAcc = pv[0]*Wp[(size_t)(w0+0)*NJ + j] + pv[1]*Wp[(size_t)(w0+1)*NJ + j]
             + pv[2]*Wp[(size_t)(w0+2)*NJ + j] + pv[3]*Wp[(size_t)(w0+3)*NJ + j];
#pragma unroll
  for (int of=1; of<64; of<<=1) sAcc += __shfl_xor(sAcc, of);
  __shared__ float red[4];
  if ((t&63)==0) red[t>>6] = sAcc;
  __syncthreads();
  if (t==0) outp[o] = red[0]+red[1]+red[2]+red[3] + Bp[j];
}

extern "C" void kernel_launch(void* const* d_in, const int* in_sizes, int n_in,
                              void* d_out, int out_size, void* d_ws, size_t ws_size,
                              hipStream_t stream)
{
  (void)n_in; (void)out_size;
  int base = (in_sizes[2] >= 1000000) ? 1 : 2;
  const float* h_in   = (const float*)d_in[0];
  const float* ln_w   = (const float*)d_in[base+0];
  const float* in_w   = (const float*)d_in[base+1];
  const float* in_b   = (const float*)d_in[base+2];
  const float* dt_w   = (const float*)d_in[base+3];
  const float* dt_b   = (const float*)d_in[base+4];
  const float* bc_w   = (const float*)d_in[base+5];
  const float* bc_b   = (const float*)d_in[base+6];
  const float* A_log  = (const float*)d_in[base+7];
  const float* omega  = (const float*)d_in[base+8];
  const float* D_skip = (const float*)d_in[base+9];
  const float* out_w  = (const float*)d_in[base+10];
  const float* out_b  = (const float*)d_in[base+11];
  const float* fln_w  = (const float*)d_in[base+12];
  const float* queries= (const float*)d_in[base+13];
  const float* feat_w = (const float*)d_in[base+14];
  const float* feat_b = (const float*)d_in[base+15];
  const float* bias_w = (const float*)d_in[base+16];
  const float* bias_b = (const float*)d_in[base+17];

  char* w0 = (char*)d_ws;
  size_t off = 0;
  auto take = [&](size_t bytes)->char*{ char* pp = w0 + off; off += (bytes + 255) & ~(size_t)255; return pp; };
  u16* wT_in  = (u16*)take((size_t)4096*1024*2);
  u16* wT_bc  = (u16*)take((size_t)2048*1024*2);
  u16* wT_out = (u16*)take((size_t)1024*2048*2);
  u16* wT_dt  = (u16*)take((size_t)16*1024*2);
  float* x    = (float*)take((size_t)4194304*4);
  u16* rbf    = (u16*)take((size_t)4194304*2);
  u16* xz     = (u16*)take((size_t)16777216*2);
  u16* bcb    = (u16*)take((size_t)8388608*2);
  char* bigscratch = take((size_t)67108864);     // hendb(33.5M)+ylocal(33.5M) during scan; xn after
  u16* gbuf   = (u16*)take((size_t)8388608*2);
  float* cst  = (float*)take((size_t)2097152*4);
  float* sst  = (float*)take((size_t)2097152*4);
  float* dtraw= (float*)take((size_t)65536*4);
  float* dtarr= (float*)take((size_t)65536*4);
  float* hdtb = (float*)take((size_t)65536*4);
  float* attnb= (float*)take((size_t)4096*4);
  float* pool = (float*)take((size_t)4096*4);
  float* prodb= (float*)take((size_t)2048*64*4);
  if (off > ws_size) return;
  float* hendb  = (float*)bigscratch;                    // 1024 x 256 x 32 f = 33.5 MB
  float* ylocal = (float*)(bigscratch + 33554432);       // 4 x 1024 x 2048 f = 33.5 MB
  float* xn     = (float*)bigscratch;                    // alias (scan scratch dead after layers)

  k_cvt<<<4096,256,0,stream>>>(h_in, x);
  for (int d=0; d<4; d++){
    k_transpose<<<dim3(128,32),256,0,stream>>>(in_w + (size_t)d*1024*4096, wT_in, 1024, 4096);
    k_transpose<<<dim3(64,32),256,0,stream>>>(bc_w + (size_t)d*1024*2048, wT_bc, 1024, 2048);
    k_transpose<<<dim3(32,64),256,0,stream>>>(out_w + (size_t)d*2048*1024, wT_out, 2048, 1024);
    k_transpose<<<dim3(1,32),256,0,stream>>>(dt_w + (size_t)d*1024*16, wT_dt, 1024, 16);
    k_rmsnorm<<<4096,256,0,stream>>>(x, ln_w + d*1024, rbf, (float*)nullptr);
    k_gemm<u16,false><<<dim3(32,32),256,0,stream>>>(rbf, wT_in, in_b + d*4096, xz, 4096, 1024);
    k_gemm<u16,false><<<dim3(16,32),256,0,stream>>>(rbf, wT_bc, bc_b + d*2048, bcb, 2048, 1024);
    k_dt<<<4096,64,0,stream>>>(rbf, wT_dt, dtraw);
    k_prep2<<<256,256,0,stream>>>(dtraw, dt_b + d*16, hdtb, dtarr);
    k_cs2<<<8192,256,0,stream>>>(dtarr, omega + d*32, A_log + d*16, cst, sst);
    k_chunkprod<<<4,256,0,stream>>>(dtarr, A_log + d*16, omega + d*32, prodb);
    k_scan_p1<<<1024,256,0,stream>>>(xz, bcb, hdtb, cst, sst, hendb, ylocal);
    k_scan_p2<<<512,256,0,stream>>>(hendb, prodb);
    k_corr<<<1024,256,0,stream>>>(xz, bcb, dtarr, A_log + d*16, omega + d*32,
                                  D_skip + d*16, hendb, ylocal, gbuf);
    k_gemm<float,true><<<dim3(8,32),256,0,stream>>>(gbuf, wT_out, out_b + d*1024, x, 1024, 2048);
  }
  k_rmsnorm<<<4096,256,0,stream>>>(x, fln_w, (u16*)nullptr, xn);
  k_attn<<<1024,256,0,stream>>>(xn, queries, attnb);
  k_smax<<<4,1024,0,stream>>>(attnb);
  k_pool2<<<dim3(16,4),256,0,stream>>>(attnb, xn, pool);
  k_heads<<<96,256,0,stream>>>(pool, feat_w, feat_b, bias_w, bias_b, (float*)d_out);
}

// Round 7
// 1480.994 us; speedup vs baseline: 3.8980x; 1.2230x over previous
//
#include <hip/hip_runtime.h>
#include <math.h>

typedef unsigned short u16;
typedef float v4f  __attribute__((ext_vector_type(4)));
typedef __bf16 v8bf __attribute__((ext_vector_type(8)));

enum { nB=4, nL=1024, nW=1024, nH=16, nN=64, nE=2048, nP=128, nNH=32, nDEPTH=4 };
enum { C_CH=16, T_CH=64 };   // chunked scan: 16 chunks of 64 steps

__device__ __forceinline__ float bf2f(u16 u){ unsigned v=((unsigned)u)<<16; return __builtin_bit_cast(float,v); }
__device__ __forceinline__ u16 f2bf(float f){ unsigned x=__builtin_bit_cast(unsigned,f); return (u16)((x + 0x7fffu + ((x>>16)&1u))>>16); }
__device__ __forceinline__ unsigned pk2(float a, float b){ return (unsigned)f2bf(a) | ((unsigned)f2bf(b)<<16); }
__device__ __forceinline__ float softplus_f(float v){ return (v>15.f)? v : log1pf(expf(v)); }
__device__ __forceinline__ void unp8(uint4 u, float* f){
  f[0]=bf2f((u16)(u.x&0xffff)); f[1]=bf2f((u16)(u.x>>16));
  f[2]=bf2f((u16)(u.y&0xffff)); f[3]=bf2f((u16)(u.y>>16));
  f[4]=bf2f((u16)(u.z&0xffff)); f[5]=bf2f((u16)(u.z>>16));
  f[6]=bf2f((u16)(u.w&0xffff)); f[7]=bf2f((u16)(u.w>>16));
}

// async global->LDS, 16B per lane; LDS dest is wave-uniform base + lane*16 (m97 pattern)
#define GLOAD16(gptr, lptr) __builtin_amdgcn_global_load_lds( \
    (const __attribute__((address_space(1))) unsigned int*)(gptr), \
    (__attribute__((address_space(3))) unsigned int*)(lptr), 16, 0, 0)

// ---------------- copy h (fp32) -> x (fp32 residual) ----------------
__global__ void k_cvt(const float* __restrict__ hsrc, float* __restrict__ x){
  int i = (blockIdx.x*256 + threadIdx.x)*4;
  *(v4f*)(x + i) = *(const v4f*)(hsrc + i);
}

// ---------------- transpose fp32 (R,C) -> bf16 (C,R) ----------------
__global__ __launch_bounds__(256) void k_transpose(const float* __restrict__ src, u16* __restrict__ dst,
    int R, int C)
{
  __shared__ u16 tl[32][36];
  int r0 = blockIdx.y*32, c0 = blockIdx.x*32;
  int tid = threadIdx.x;
  int r = tid>>3, c4 = (tid&7)*4;
  if (r0 + r < R){
#pragma unroll
    for (int jj=0;jj<4;jj++){
      int c = c0 + c4 + jj;
      tl[r][c4+jj] = (c < C) ? f2bf(src[(size_t)(r0+r)*C + c]) : (u16)0;
    }
  }
  __syncthreads();
  int c = tid>>3, r4 = (tid&7)*4;
  if (c0 + c < C){
#pragma unroll
    for (int jj=0;jj<4;jj++){
      int rr = r0 + r4 + jj;
      if (rr < R) dst[(size_t)(c0+c)*R + rr] = tl[r4+jj][c];
    }
  }
}

// ---------------- rmsnorm: x(fp32) * w(fp32) -> bf16 and/or fp32 ----------------
__global__ __launch_bounds__(256) void k_rmsnorm(const float* __restrict__ x, const float* __restrict__ w,
    u16* __restrict__ obf, float* __restrict__ of32)
{
  int row = blockIdx.x, tid = threadIdx.x;
  const float* xr = x + (size_t)row*1024;
  v4f v = *(const v4f*)(xr + tid*4);
  float ss = v[0]*v[0]+v[1]*v[1]+v[2]*v[2]+v[3]*v[3];
#pragma unroll
  for (int o=1;o<64;o<<=1) ss += __shfl_xor(ss,o);
  __shared__ float red[4];
  if ((tid&63)==0) red[tid>>6] = ss;
  __syncthreads();
  float tot = red[0]+red[1]+red[2]+red[3];
  float rms = rsqrtf(tot*(1.f/1024.f) + 1e-6f);
  v4f wv = *(const v4f*)(w + tid*4);
  float o0=v[0]*rms*wv[0], o1=v[1]*rms*wv[1], o2=v[2]*rms*wv[2], o3=v[3]*rms*wv[3];
  if (obf){
    ushort4 ob = { f2bf(o0), f2bf(o1), f2bf(o2), f2bf(o3) };
    *(ushort4*)(obf + (size_t)row*1024 + tid*4) = ob;
  }
  if (of32){
    v4f ov = {o0,o1,o2,o3};
    *(v4f*)(of32 + (size_t)row*1024 + tid*4) = ov;
  }
}

// ---------------- MFMA GEMM (m97 structure): C = A(MxK,bf16) @ BT(NxK,bf16)^T + bias(fp32)
template<typename OT, bool ADD>
__global__ __launch_bounds__(256) void k_gemm(const u16* __restrict__ A, const u16* __restrict__ BT,
    const float* __restrict__ bias, OT* __restrict__ C, int N, int K)
{
  __shared__ __align__(16) char sraw[32*132*4];   // 16.9 KB; staging uses first 16 KB
  u16* As = (u16*)sraw;            // [128][32] linear
  u16* Bs = As + 128*32;
  const int tid = threadIdx.x;
  const int wave = tid>>6, lane = tid&63, quad = lane>>4, l15 = lane&15;
  const int bm = blockIdx.y*128, bn = blockIdx.x*128;
  const int wm = (wave>>1)*64, wn = (wave&1)*64;
  v4f acc[4][4];
#pragma unroll
  for (int i=0;i<4;i++)
#pragma unroll
    for (int j=0;j<4;j++){ v4f z = {0.f,0.f,0.f,0.f}; acc[i][j]=z; }

  const int srow = wave*32 + (lane>>2);
  const int scol = (lane&3)*8;
  const u16* agp = A  + (size_t)(bm+srow)*K + scol;
  const u16* bgp = BT + (size_t)(bn+srow)*K + scol;
  u16* ldsA = As + (wave*32)*32;
  u16* ldsB = Bs + (wave*32)*32;

  for (int k0=0; k0<K; k0+=32){
    GLOAD16(agp,                ldsA);
    GLOAD16(agp + (size_t)16*K, ldsA + 16*32);
    GLOAD16(bgp,                ldsB);
    GLOAD16(bgp + (size_t)16*K, ldsB + 16*32);
    agp += 32; bgp += 32;
    __syncthreads();
    v8bf af[4], bfr[4];
#pragma unroll
    for (int mi=0;mi<4;mi++) af[mi]  = *(const v8bf*)(As + (wm+mi*16+l15)*32 + quad*8);
#pragma unroll
    for (int ni=0;ni<4;ni++) bfr[ni] = *(const v8bf*)(Bs + (wn+ni*16+l15)*32 + quad*8);
#pragma unroll
    for (int mi=0;mi<4;mi++)
#pragma unroll
      for (int ni=0;ni<4;ni++)
        acc[mi][ni] = __builtin_amdgcn_mfma_f32_16x16x32_bf16(af[mi], bfr[ni], acc[mi][ni], 0,0,0);
    __syncthreads();
  }

  float* eps = (float*)sraw;
  float bz[4];
#pragma unroll
  for (int ni=0;ni<4;ni++) bz[ni] = bias[bn + wn + ni*16 + l15];
  const int erb = (wave>>1)*16 + quad*4;
#pragma unroll
  for (int mi=0;mi<4;mi++){
#pragma unroll
    for (int ni=0;ni<4;ni++){
      v4f v = acc[mi][ni];
#pragma unroll
      for (int r=0;r<4;r++)
        eps[(erb + r)*132 + wn + ni*16 + l15] = v[r] + bz[ni];
    }
    __syncthreads();
    {
      int e = tid>>3, seg = tid&7;
      int grow = bm + (e>>4)*64 + mi*16 + (e&15);
      int gcol = bn + seg*16;
      const float* ep = eps + e*132 + seg*16;
      if constexpr (ADD){
        float* cp = (float*)C + (size_t)grow*N + gcol;
#pragma unroll
        for (int u=0;u<4;u++){
          v4f ov = *(const v4f*)(ep + 4*u);
          v4f cv = *(const v4f*)(cp + 4*u);
          ov += cv;
          *(v4f*)(cp + 4*u) = ov;
        }
      } else {
        u16* cp = (u16*)C + (size_t)grow*N + gcol;
        v4f e0 = *(const v4f*)(ep+0), e1 = *(const v4f*)(ep+4);
        v4f e2 = *(const v4f*)(ep+8), e3 = *(const v4f*)(ep+12);
        uint4 pA = { pk2(e0[0],e0[1]), pk2(e0[2],e0[3]), pk2(e1[0],e1[1]), pk2(e1[2],e1[3]) };
        uint4 pB = { pk2(e2[0],e2[1]), pk2(e2[2],e2[3]), pk2(e3[0],e3[1]), pk2(e3[2],e3[3]) };
        *(uint4*)(cp)   = pA;
        *(uint4*)(cp+8) = pB;
      }
    }
    __syncthreads();
  }
}

// ---------------- dt matmul ----------------
__global__ __launch_bounds__(64) void k_dt(const u16* __restrict__ r, const u16* __restrict__ dtwT,
    float* __restrict__ dtraw)
{
  int row = blockIdx.x, lane = threadIdx.x;
  const u16* rp = r + (size_t)row*1024 + lane*16;
  float rv[16];
  unp8(*(const uint4*)rp, rv);
  unp8(*(const uint4*)(rp+8), rv+8);
  float keep = 0.f;
  for (int hh=0; hh<16; hh++){
    const u16* wp = dtwT + hh*1024 + lane*16;
    float wv[16];
    unp8(*(const uint4*)wp, wv);
    unp8(*(const uint4*)(wp+8), wv+8);
    float sv = 0.f;
#pragma unroll
    for (int j=0;j<16;j++) sv = fmaf(rv[j], wv[j], sv);
#pragma unroll
    for (int o=1;o<64;o<<=1) sv += __shfl_xor(sv, o);
    if (lane==hh) keep = sv;
  }
  if (lane<16) dtraw[(size_t)row*16 + lane] = keep;
}

// ---------------- prep2 per (b,l,h): hdtb = 0.5*dt; dtarr = dt ----------------
__global__ void k_prep2(const float* __restrict__ dtraw, const float* __restrict__ dt_b,
    float* __restrict__ hdtb, float* __restrict__ dtarr)
{
  int i = blockIdx.x*256 + threadIdx.x;
  int h = i & 15;
  float dt0 = fminf(softplus_f(dtraw[i] + dt_b[h]), 30.f);
  hdtb[i] = 0.5f*dt0;
  dtarr[i] = dt0;
}

// ---------------- chunk cumulative transition: prod[(bh*C+c)*64 + 2q+{0,1}] ----------------
__global__ void k_chunkprod(const float* __restrict__ dtarr, const float* __restrict__ A_log,
    const float* __restrict__ omega, float* __restrict__ prod)
{
  int i = blockIdx.x*256 + threadIdx.x;   // 1024 items: (bh, c)
  int bh = i >> 4, c = i & 15;
  int b = bh >> 4, h = bh & 15;
  size_t base = ((size_t)b*nL + c*T_CH)*16 + h;
  float S = 0.f;
  for (int t=0;t<T_CH;t++) S += dtarr[base + (size_t)t*16];
  float A = -expf(A_log[h]);
  float decF = expf(A*S);
  float* pp = prod + (size_t)i*64;
#pragma unroll
  for (int q=0;q<32;q++){
    float sn, cn; __sincosf(omega[q]*S, &sn, &cn);
    pp[q*2]   = decF*cn;
    pp[q*2+1] = decF*sn;
  }
}

// ---------------- scan phase 1 (rescaled prefix-sum form) ----------------
// h_l = P_l*(Gt_{l-1} + hdt_l*x_l*w_l);  w_l = B_l/P_l,  D_l = P_l*conj(C_l),
// y_l = sum_q Re(Gt*D_l) + hdt_l*x_l*E_l,  E_l = sum_q (B1C1+B2C2) (exact).
// Gt_l = Gt_{l-1} + (hdt_l + hdt_{l+1})*x_l*w_l (hdt beyond chunk = 0).
// thread t: p = t>>1, half = t&1, q0 = half*16. hend record layout as before.
__global__ __launch_bounds__(256) void k_scan_p1(const u16* __restrict__ xz, const u16* __restrict__ bcb,
    const float* __restrict__ hdtb, const float* __restrict__ dtarr,
    const float* __restrict__ A_log, const float* __restrict__ omega,
    float* __restrict__ hend, float* __restrict__ ylocal)
{
  int bc_ = blockIdx.x;               // bh*16 + c
  int bh = bc_ >> 4, c = bc_ & 15;
  int b = bh >> 4, h = bh & 15;
  int t = threadIdx.x, p = t>>1, half = t&1, q0 = half*16;
  size_t rowbase = (size_t)b*nL + c*T_CH;
  __shared__ float sWr[T_CH+1][32], sWi[T_CH+1][32];   // w_s, s=0..64 (row0 = prev-chunk B)
  __shared__ float sDr[T_CH][32],   sDi[T_CH][32];     // D_l, l=1..64 at row l-1
  __shared__ float sS[T_CH], sdA[T_CH], seI[T_CH], sHD[T_CH], sE[T_CH];
  if (t < 64){
    float v = dtarr[(rowbase+t)*16 + h];
#pragma unroll
    for (int j=1;j<64;j<<=1){
      float o = __shfl_up(v, j);
      if (t >= j) v += o;
    }
    sS[t] = v;
  }
  __syncthreads();
  float A = -expf(A_log[h]);
  if (t < 64){
    float S = sS[t];
    sdA[t] = expf(A*S);
    seI[t] = expf(-A*S);
    sHD[t] = hdtb[(rowbase+t)*16 + h];
  }
  if (t >= 64 && t < 96){
    int q = t - 64;
    float b1=0.f, b2=0.f;
    if (c){
      b1 = bf2f(bcb[(rowbase-1)*2048 + h*64 + q]);
      b2 = bf2f(bcb[(rowbase-1)*2048 + h*64 + 32 + q]);
    }
    sWr[0][q] = b1; sWi[0][q] = b2;
  }
  __syncthreads();
  for (int e=t; e<T_CH*32; e+=256){
    int li = e>>5, q = e&31;
    size_t g = rowbase + li;
    float B1 = bf2f(bcb[g*2048 + h*64 + q]);
    float B2 = bf2f(bcb[g*2048 + h*64 + 32 + q]);
    float C1 = bf2f(bcb[g*2048 + 1024 + h*64 + q]);
    float C2 = bf2f(bcb[g*2048 + 1024 + h*64 + 32 + q]);
    float sn, cn; __sincosf(omega[q]*sS[li], &sn, &cn);
    float eI = seI[li], dA = sdA[li];
    sWr[li+1][q] = eI*(B1*cn + B2*sn);
    sWi[li+1][q] = eI*(B2*cn - B1*sn);
    sDr[li][q]   = dA*(cn*C1 + sn*C2);
    sDi[li][q]   = dA*(sn*C1 - cn*C2);
    // stash exact E contribution via atomic-free trick: E computed in a second pass below
  }
  __syncthreads();
  if (t < 64){
    float e = 0.f;
#pragma unroll
    for (int q=0;q<32;q++)
      e += sWr[t+1][q]*sDr[t][q] - sWi[t+1][q]*sDi[t][q];   // = sum_q Re(w_l D_l) = sum B1C1+B2C2
    sE[t] = e;
  }
  __syncthreads();

  float gr[16], gi[16];
  float x0 = c ? bf2f(xz[(rowbase-1)*4096 + h*128 + p]) : 0.f;
  float c0 = sHD[0]*x0;
#pragma unroll
  for (int j4=0;j4<4;j4++){
    v4f wr0 = *(const v4f*)&sWr[0][q0+4*j4];
    v4f wi0 = *(const v4f*)&sWi[0][q0+4*j4];
#pragma unroll
    for (int j=0;j<4;j++){ gr[4*j4+j] = c0*wr0[j]; gi[4*j4+j] = c0*wi0[j]; }
  }
  const u16* xp = xz + rowbase*4096 + h*128 + p;
  float* yp = ylocal + rowbase*2048 + h*128 + p;
  for (int li=0; li<T_CH; li++){
    float hdt = sHD[li];
    float hnx = (li<T_CH-1) ? sHD[li+1] : 0.f;
    float xv = bf2f(*xp);
    float cx = (hdt + hnx)*xv;
    float y = 0.f;
#pragma unroll
    for (int j4=0;j4<4;j4++){
      v4f Dr = *(const v4f*)&sDr[li][q0+4*j4];
      v4f Di = *(const v4f*)&sDi[li][q0+4*j4];
      v4f Wr = *(const v4f*)&sWr[li+1][q0+4*j4];
      v4f Wi = *(const v4f*)&sWi[li+1][q0+4*j4];
#pragma unroll
      for (int j=0;j<4;j++){
        int jj = 4*j4+j;
        y = fmaf(gr[jj], Dr[j], y);
        y = fmaf(-gi[jj], Di[j], y);
        gr[jj] = fmaf(cx, Wr[j], gr[jj]);
        gi[jj] = fmaf(cx, Wi[j], gi[jj]);
      }
    }
    y += __shfl_xor(y, 1);
    if (half==0) *yp = fmaf(hdt*xv, sE[li], y);
    xp += 4096; yp += 2048;
  }
  // end state: h_64 = P_64 * Gt_64
  float S64 = sS[T_CH-1], dA64 = sdA[T_CH-1];
  float* hp = hend + ((size_t)bc_*256 + t)*32;
#pragma unroll
  for (int j4=0;j4<8;j4++){
    float hr[2], hi[2];
#pragma unroll
    for (int u=0;u<2;u++){
      int jj = 2*j4+u;
      float sn, cn; __sincosf(omega[q0+jj]*S64, &sn, &cn);
      float pr = dA64*cn, pi = dA64*sn;
      hr[u] = pr*gr[jj] - pi*gi[jj];
      hi[u] = pr*gi[jj] + pi*gr[jj];
    }
    v4f o = { hr[0], hi[0], hr[1], hi[1] };
    *(v4f*)(hp + 4*j4) = o;
  }
}

// ---------------- scan phase 2: carry propagation, parallel over (bh x 8 record-slices) ------
__global__ __launch_bounds__(256) void k_scan_p2(float* __restrict__ hend, const float* __restrict__ prod)
{
  int bh = blockIdx.x>>3, slice = blockIdx.x&7;
  int tid = threadIdx.x;
  int rec = slice*32 + (tid>>3);
  int sub = tid&7;
  int qa = (rec&1)*16 + sub*2;
  float c1a=0.f,c2a=0.f,c1b=0.f,c2b=0.f;
  for (int c=0;c<C_CH;c++){
    float* hp = hend + (((size_t)(bh*C_CH+c))*256 + rec)*32 + sub*4;
    v4f r = *(const v4f*)hp;
    v4f w = { c1a, c2a, c1b, c2b };
    *(v4f*)hp = w;
    const float* pp = prod + (size_t)(bh*C_CH+c)*64 + qa*2;
    float pr0=pp[0], pi0=pp[1], pr1=pp[2], pi1=pp[3];
    float n1a = fmaf(pr0,c1a, fmaf(-pi0,c2a, r[0]));
    float n2a = fmaf(pr0,c2a, fmaf( pi0,c1a, r[1]));
    float n1b = fmaf(pr1,c1b, fmaf(-pi1,c2b, r[2]));
    float n2b = fmaf(pr1,c2b, fmaf( pi1,c1b, r[3]));
    c1a=n1a; c2a=n2a; c1b=n1b; c2b=n2b;
  }
}

// ---------------- k_corr: y = ylocal + Re(carry . D_l) + Dskip*x; gate -> gbuf ----------------
__global__ __launch_bounds__(256) void k_corr(const u16* __restrict__ xz, const u16* __restrict__ bcb,
    const float* __restrict__ dtarr, const float* __restrict__ A_log, const float* __restrict__ omega,
    const float* __restrict__ Dsk, const float* __restrict__ hcar, const float* __restrict__ ylocal,
    u16* __restrict__ gbuf)
{
  int bc_ = blockIdx.x;               // bh*16 + c
  int bh = bc_ >> 4, c = bc_ & 15;
  int b = bh >> 4, h = bh & 15;
  int t = threadIdx.x, p = t>>1, qh = t&1, q0 = qh*16;
  size_t rowbase = (size_t)b*nL + c*T_CH;
  __shared__ float sDr[T_CH][32];
  __shared__ float sDi[T_CH][32];
  __shared__ float sS[T_CH];
  if (t < 64){
    float v = dtarr[(rowbase+t)*16 + h];
#pragma unroll
    for (int j=1;j<64;j<<=1){
      float o = __shfl_up(v, j);
      if (t >= j) v += o;
    }
    sS[t] = v;
  }
  __syncthreads();
  float A = -expf(A_log[h]);
  for (int e=t; e<T_CH*32; e+=256){
    int l = e>>5, q = e&31;
    float S = sS[l];
    float sn, cn; __sincosf(omega[q]*S, &sn, &cn);
    float dA = expf(A*S);
    float Ar = dA*cn, Ai = dA*sn;
    float C1 = bf2f(bcb[(rowbase+l)*2048 + 1024 + h*64 + q]);
    float C2 = bf2f(bcb[(rowbase+l)*2048 + 1024 + h*64 + 32 + q]);
    sDr[l][q] = Ar*C1 + Ai*C2;
    sDi[l][q] = Ai*C1 - Ar*C2;
  }
  __syncthreads();
  float c1[16], c2[16];
  const float* hp0 = hcar + ((size_t)bc_*256 + t)*32;
#pragma unroll
  for (int j4=0;j4<8;j4++){
    v4f r = *(const v4f*)(hp0 + 4*j4);
    c1[2*j4]=r[0]; c2[2*j4]=r[1]; c1[2*j4+1]=r[2]; c2[2*j4+1]=r[3];
  }
  float Dskip = Dsk[h];
  const float* yl = ylocal + rowbase*2048 + h*128 + p;
  const u16* xp = xz + rowbase*4096 + h*128 + p;
  const u16* zp = xp + 2048;
  u16* gp = gbuf + rowbase*2048 + h*128 + p;
  for (int l=0; l<T_CH; l++){
    float corr = 0.f;
#pragma unroll
    for (int j4=0;j4<4;j4++){
      v4f dr = *(const v4f*)&sDr[l][q0+4*j4];
      v4f di = *(const v4f*)&sDi[l][q0+4*j4];
#pragma unroll
      for (int j=0;j<4;j++){
        int jj = 4*j4+j;
        corr = fmaf(c1[jj], dr[j], corr);
        corr = fmaf(-c2[jj], di[j], corr);
      }
    }
    corr += __shfl_xor(corr, 1);
    if (qh==0){
      float xv = bf2f(*xp);
      float zv = bf2f(*zp);
      float yv = fmaf(xv, Dskip, yl[0] + corr);
      float g = yv*zv/(1.f+expf(-zv));
      *gp = f2bf(g);
    }
    yl += 2048; xp += 4096; zp += 4096; gp += 2048;
  }
}

// ---------------- attention logits ----------------
__global__ __launch_bounds__(256) void k_attn(const float* __restrict__ xn, const float* __restrict__ q,
    float* __restrict__ attn)
{
  int wid = blockIdx.x*4 + (threadIdx.x>>6);
  int lane = threadIdx.x & 63;
  const float* xr = xn + (size_t)wid*1024 + lane*16;
  const float* qr = q + lane*16;
  float sAcc=0.f;
#pragma unroll
  for (int j4=0;j4<4;j4++){
    v4f xv = *(const v4f*)(xr + 4*j4);
    v4f qv = *(const v4f*)(qr + 4*j4);
#pragma unroll
    for (int j=0;j<4;j++) sAcc = fmaf(xv[j], qv[j], sAcc);
  }
#pragma unroll
  for (int o=1;o<64;o<<=1) sAcc += __shfl_xor(sAcc,o);
  if (lane==0) attn[wid] = sAcc*(1.f/32.f);
}

// ---------------- softmax over L (in place) ----------------
__global__ __launch_bounds__(1024) void k_smax(float* __restrict__ attn)
{
  int b = blockIdx.x, t = threadIdx.x;
  __shared__ float red[16];
  __shared__ float red2[16];
  float av = attn[b*1024 + t];
  float m = av;
#pragma unroll
  for (int o=1;o<64;o<<=1) m = fmaxf(m, __shfl_xor(m,o));
  if ((t&63)==0) red[t>>6] = m;
  __syncthreads();
  float bm = red[0];
  for (int jj=1;jj<16;jj++) bm = fmaxf(bm, red[jj]);
  float e = expf(av - bm);
  float sm = e;
#pragma unroll
  for (int o=1;o<64;o<<=1) sm += __shfl_xor(sm,o);
  if ((t&63)==0) red2[t>>6] = sm;
  __syncthreads();
  float tot = 0.f;
  for (int jj=0;jj<16;jj++) tot += red2[jj];
  attn[b*1024 + t] = e/tot;
}

// ---------------- pooled[b,w] ----------------
__global__ __launch_bounds__(256) void k_pool2(const float* __restrict__ attnp, const float* __restrict__ xn,
    float* __restrict__ pooled)
{
  int wsl = blockIdx.x, b = blockIdx.y, t = threadIdx.x;
  int w = wsl*64 + (t&63), ls = t>>6;
  float acc = 0.f;
  for (int l=ls; l<1024; l+=4)
    acc = fmaf(attnp[b*1024 + l], xn[((size_t)b*1024 + l)*1024 + w], acc);
  __shared__ float red[256];
  red[t] = acc;
  __syncthreads();
  if (t<64)
    pooled[(size_t)b*1024 + wsl*64 + t] = red[t]+red[t+64]+red[t+128]+red[t+192];
}

// ---------------- heads ----------------
__global__ __launch_bounds__(256) void k_heads(const float* __restrict__ pooled,
    const float* __restrict__ fw, const float* __restrict__ fb,
    const float* __restrict__ bw, const float* __restrict__ bb, float* __restrict__ outp)
{
  int o = blockIdx.x, t = threadIdx.x;
  int b, j, NJ; const float *Wp, *Bp;
  if (o < 16){ b = o>>2; j = o&3; NJ = 4; Wp = fw; Bp = fb; }
  else { int oo = o-16; b = oo/20; j = oo - b*20; NJ = 20; Wp = bw; Bp = bb; }
  v4f pv = *(const v4f*)(pooled + (size_t)b*1024 + t*4);
  int w0 = t*4;
  float sAcc = pv[0]*Wp[(size_t)(w0+0)*NJ + j] + pv[1]*Wp[(size_t)(w0+1)*NJ + j]
             + pv[2]*Wp[(size_t)(w0+2)*NJ + j] + pv[3]*Wp[(size_t)(w0+3)*NJ + j];
#pragma unroll
  for (int of=1; of<64; of<<=1) sAcc += __shfl_xor(sAcc, of);
  __shared__ float red[4];
  if ((t&63)==0) red[t>>6] = sAcc;
  __syncthreads();
  if (t==0) outp[o] = red[0]+red[1]+red[2]+red[3] + Bp[j];
}

extern "C" void kernel_launch(void* const* d_in, const int* in_sizes, int n_in,
                              void* d_out, int out_size, void* d_ws, size_t ws_size,
                              hipStream_t stream)
{
  (void)n_in; (void)out_size;
  int base = (in_sizes[2] >= 1000000) ? 1 : 2;
  const float* h_in   = (const float*)d_in[0];
  const float* ln_w   = (const float*)d_in[base+0];
  const float* in_w   = (const float*)d_in[base+1];
  const float* in_b   = (const float*)d_in[base+2];
  const float* dt_w   = (const float*)d_in[base+3];
  const float* dt_b   = (const float*)d_in[base+4];
  const float* bc_w   = (const float*)d_in[base+5];
  const float* bc_b   = (const float*)d_in[base+6];
  const float* A_log  = (const float*)d_in[base+7];
  const float* omega  = (const float*)d_in[base+8];
  const float* D_skip = (const float*)d_in[base+9];
  const float* out_w  = (const float*)d_in[base+10];
  const float* out_b  = (const float*)d_in[base+11];
  const float* fln_w  = (const float*)d_in[base+12];
  const float* queries= (const float*)d_in[base+13];
  const float* feat_w = (const float*)d_in[base+14];
  const float* feat_b = (const float*)d_in[base+15];
  const float* bias_w = (const float*)d_in[base+16];
  const float* bias_b = (const float*)d_in[base+17];

  char* w0 = (char*)d_ws;
  size_t off = 0;
  auto take = [&](size_t bytes)->char*{ char* pp = w0 + off; off += (bytes + 255) & ~(size_t)255; return pp; };
  u16* wT_in  = (u16*)take((size_t)4096*1024*2);
  u16* wT_bc  = (u16*)take((size_t)2048*1024*2);
  u16* wT_out = (u16*)take((size_t)1024*2048*2);
  u16* wT_dt  = (u16*)take((size_t)16*1024*2);
  float* x    = (float*)take((size_t)4194304*4);
  u16* rbf    = (u16*)take((size_t)4194304*2);
  u16* xz     = (u16*)take((size_t)16777216*2);
  u16* bcb    = (u16*)take((size_t)8388608*2);
  char* bigscratch = take((size_t)67108864);     // hendb(33.5M)+ylocal(33.5M) during scan; xn after
  u16* gbuf   = (u16*)take((size_t)8388608*2);
  float* dtraw= (float*)take((size_t)65536*4);
  float* dtarr= (float*)take((size_t)65536*4);
  float* hdtb = (float*)take((size_t)65536*4);
  float* attnb= (float*)take((size_t)4096*4);
  float* pool = (float*)take((size_t)4096*4);
  float* prodb= (float*)take((size_t)2048*64*4);
  if (off > ws_size) return;
  float* hendb  = (float*)bigscratch;                    // 1024 x 256 x 32 f = 33.5 MB
  float* ylocal = (float*)(bigscratch + 33554432);       // 4 x 1024 x 2048 f = 33.5 MB
  float* xn     = (float*)bigscratch;                    // alias (scan scratch dead after layers)

  k_cvt<<<4096,256,0,stream>>>(h_in, x);
  for (int d=0; d<4; d++){
    k_transpose<<<dim3(128,32),256,0,stream>>>(in_w + (size_t)d*1024*4096, wT_in, 1024, 4096);
    k_transpose<<<dim3(64,32),256,0,stream>>>(bc_w + (size_t)d*1024*2048, wT_bc, 1024, 2048);
    k_transpose<<<dim3(32,64),256,0,stream>>>(out_w + (size_t)d*2048*1024, wT_out, 2048, 1024);
    k_transpose<<<dim3(1,32),256,0,stream>>>(dt_w + (size_t)d*1024*16, wT_dt, 1024, 16);
    k_rmsnorm<<<4096,256,0,stream>>>(x, ln_w + d*1024, rbf, (float*)nullptr);
    k_gemm<u16,false><<<dim3(32,32),256,0,stream>>>(rbf, wT_in, in_b + d*4096, xz, 4096, 1024);
    k_gemm<u16,false><<<dim3(16,32),256,0,stream>>>(rbf, wT_bc, bc_b + d*2048, bcb, 2048, 1024);
    k_dt<<<4096,64,0,stream>>>(rbf, wT_dt, dtraw);
    k_prep2<<<256,256,0,stream>>>(dtraw, dt_b + d*16, hdtb, dtarr);
    k_chunkprod<<<4,256,0,stream>>>(dtarr, A_log + d*16, omega + d*32, prodb);
    k_scan_p1<<<1024,256,0,stream>>>(xz, bcb, hdtb, dtarr, A_log + d*16, omega + d*32,
                                     hendb, ylocal);
    k_scan_p2<<<512,256,0,stream>>>(hendb, prodb);
    k_corr<<<1024,256,0,stream>>>(xz, bcb, dtarr, A_log + d*16, omega + d*32,
                                  D_skip + d*16, hendb, ylocal, gbuf);
    k_gemm<float,true><<<dim3(8,32),256,0,stream>>>(gbuf, wT_out, out_b + d*1024, x, 1024, 2048);
  }
  k_rmsnorm<<<4096,256,0,stream>>>(x, fln_w, (u16*)nullptr, xn);
  k_attn<<<1024,256,0,stream>>>(xn, queries, attnb);
  k_smax<<<4,1024,0,stream>>>(attnb);
  k_pool2<<<dim3(16,4),256,0,stream>>>(attnb, xn, pool);
  k_heads<<<96,256,0,stream>>>(pool, feat_w, feat_b, bias_w, bias_b, (float*)d_out);
}

// Round 8
// 1418.363 us; speedup vs baseline: 4.0701x; 1.0442x over previous
//
#include <hip/hip_runtime.h>
#include <math.h>

typedef unsigned short u16;
typedef float v4f  __attribute__((ext_vector_type(4)));
typedef __bf16 v8bf __attribute__((ext_vector_type(8)));

enum { nB=4, nL=1024, nW=1024, nH=16, nN=64, nE=2048, nP=128, nNH=32, nDEPTH=4 };
enum { C_CH=16, T_CH=64 };   // chunked scan: 16 chunks of 64 steps

__device__ __forceinline__ float bf2f(u16 u){ unsigned v=((unsigned)u)<<16; return __builtin_bit_cast(float,v); }
__device__ __forceinline__ u16 f2bf(float f){ unsigned x=__builtin_bit_cast(unsigned,f); return (u16)((x + 0x7fffu + ((x>>16)&1u))>>16); }
__device__ __forceinline__ unsigned pk2(float a, float b){ return (unsigned)f2bf(a) | ((unsigned)f2bf(b)<<16); }
__device__ __forceinline__ float softplus_f(float v){ return (v>15.f)? v : log1pf(expf(v)); }
__device__ __forceinline__ void unp8(uint4 u, float* f){
  f[0]=bf2f((u16)(u.x&0xffff)); f[1]=bf2f((u16)(u.x>>16));
  f[2]=bf2f((u16)(u.y&0xffff)); f[3]=bf2f((u16)(u.y>>16));
  f[4]=bf2f((u16)(u.z&0xffff)); f[5]=bf2f((u16)(u.z>>16));
  f[6]=bf2f((u16)(u.w&0xffff)); f[7]=bf2f((u16)(u.w>>16));
}

// async global->LDS, 16B per lane; LDS dest is wave-uniform base + lane*16 (m97 pattern)
#define GLOAD16(gptr, lptr) __builtin_amdgcn_global_load_lds( \
    (const __attribute__((address_space(1))) unsigned int*)(gptr), \
    (__attribute__((address_space(3))) unsigned int*)(lptr), 16, 0, 0)

// ---------------- copy h (fp32) -> x (fp32 residual) ----------------
__global__ void k_cvt(const float* __restrict__ hsrc, float* __restrict__ x){
  int i = (blockIdx.x*256 + threadIdx.x)*4;
  *(v4f*)(x + i) = *(const v4f*)(hsrc + i);
}

// ---------------- transpose fp32 (R,C) -> bf16 (C,R), vectorized ----------------
__global__ __launch_bounds__(256) void k_transpose(const float* __restrict__ src, u16* __restrict__ dst,
    int R, int C)
{
  __shared__ u16 tl[32][36];
  int r0 = blockIdx.y*32, c0 = blockIdx.x*32;
  int tid = threadIdx.x;
  int r = tid>>3, c4 = (tid&7)*4;
  if (r0 + r < R){
    if (c0 + c4 + 3 < C){
      v4f v = *(const v4f*)(src + (size_t)(r0+r)*C + c0 + c4);
      tl[r][c4+0] = f2bf(v[0]); tl[r][c4+1] = f2bf(v[1]);
      tl[r][c4+2] = f2bf(v[2]); tl[r][c4+3] = f2bf(v[3]);
    } else {
#pragma unroll
      for (int jj=0;jj<4;jj++){
        int c = c0 + c4 + jj;
        tl[r][c4+jj] = (c < C) ? f2bf(src[(size_t)(r0+r)*C + c]) : (u16)0;
      }
    }
  }
  __syncthreads();
  int c = tid>>3, r4 = (tid&7)*4;
  if (c0 + c < C){
    if (r0 + r4 + 3 < R){
      ushort4 st = { tl[r4][c], tl[r4+1][c], tl[r4+2][c], tl[r4+3][c] };
      *(ushort4*)(dst + (size_t)(c0+c)*R + r0 + r4) = st;
    } else {
#pragma unroll
      for (int jj=0;jj<4;jj++){
        int rr = r0 + r4 + jj;
        if (rr < R) dst[(size_t)(c0+c)*R + rr] = tl[r4+jj][c];
      }
    }
  }
}

// ---------------- rmsnorm: x(fp32) * w(fp32) -> bf16 and/or fp32 ----------------
__global__ __launch_bounds__(256) void k_rmsnorm(const float* __restrict__ x, const float* __restrict__ w,
    u16* __restrict__ obf, float* __restrict__ of32)
{
  int row = blockIdx.x, tid = threadIdx.x;
  const float* xr = x + (size_t)row*1024;
  v4f v = *(const v4f*)(xr + tid*4);
  float ss = v[0]*v[0]+v[1]*v[1]+v[2]*v[2]+v[3]*v[3];
#pragma unroll
  for (int o=1;o<64;o<<=1) ss += __shfl_xor(ss,o);
  __shared__ float red[4];
  if ((tid&63)==0) red[tid>>6] = ss;
  __syncthreads();
  float tot = red[0]+red[1]+red[2]+red[3];
  float rms = rsqrtf(tot*(1.f/1024.f) + 1e-6f);
  v4f wv = *(const v4f*)(w + tid*4);
  float o0=v[0]*rms*wv[0], o1=v[1]*rms*wv[1], o2=v[2]*rms*wv[2], o3=v[3]*rms*wv[3];
  if (obf){
    ushort4 ob = { f2bf(o0), f2bf(o1), f2bf(o2), f2bf(o3) };
    *(ushort4*)(obf + (size_t)row*1024 + tid*4) = ob;
  }
  if (of32){
    v4f ov = {o0,o1,o2,o3};
    *(v4f*)(of32 + (size_t)row*1024 + tid*4) = ov;
  }
}

// ---------------- MFMA GEMM (m97 structure): C = A(MxK,bf16) @ BT(NxK,bf16)^T + bias(fp32)
template<typename OT, bool ADD>
__global__ __launch_bounds__(256) void k_gemm(const u16* __restrict__ A, const u16* __restrict__ BT,
    const float* __restrict__ bias, OT* __restrict__ C, int N, int K)
{
  __shared__ __align__(16) char sraw[32*132*4];   // 16.9 KB; staging uses first 16 KB
  u16* As = (u16*)sraw;            // [128][32] linear
  u16* Bs = As + 128*32;
  const int tid = threadIdx.x;
  const int wave = tid>>6, lane = tid&63, quad = lane>>4, l15 = lane&15;
  const int bm = blockIdx.y*128, bn = blockIdx.x*128;
  const int wm = (wave>>1)*64, wn = (wave&1)*64;
  v4f acc[4][4];
#pragma unroll
  for (int i=0;i<4;i++)
#pragma unroll
    for (int j=0;j<4;j++){ v4f z = {0.f,0.f,0.f,0.f}; acc[i][j]=z; }

  const int srow = wave*32 + (lane>>2);
  const int scol = (lane&3)*8;
  const u16* agp = A  + (size_t)(bm+srow)*K + scol;
  const u16* bgp = BT + (size_t)(bn+srow)*K + scol;
  u16* ldsA = As + (wave*32)*32;
  u16* ldsB = Bs + (wave*32)*32;

  for (int k0=0; k0<K; k0+=32){
    GLOAD16(agp,                ldsA);
    GLOAD16(agp + (size_t)16*K, ldsA + 16*32);
    GLOAD16(bgp,                ldsB);
    GLOAD16(bgp + (size_t)16*K, ldsB + 16*32);
    agp += 32; bgp += 32;
    __syncthreads();
    v8bf af[4], bfr[4];
#pragma unroll
    for (int mi=0;mi<4;mi++) af[mi]  = *(const v8bf*)(As + (wm+mi*16+l15)*32 + quad*8);
#pragma unroll
    for (int ni=0;ni<4;ni++) bfr[ni] = *(const v8bf*)(Bs + (wn+ni*16+l15)*32 + quad*8);
#pragma unroll
    for (int mi=0;mi<4;mi++)
#pragma unroll
      for (int ni=0;ni<4;ni++)
        acc[mi][ni] = __builtin_amdgcn_mfma_f32_16x16x32_bf16(af[mi], bfr[ni], acc[mi][ni], 0,0,0);
    __syncthreads();
  }

  float* eps = (float*)sraw;
  float bz[4];
#pragma unroll
  for (int ni=0;ni<4;ni++) bz[ni] = bias[bn + wn + ni*16 + l15];
  const int erb = (wave>>1)*16 + quad*4;
#pragma unroll
  for (int mi=0;mi<4;mi++){
#pragma unroll
    for (int ni=0;ni<4;ni++){
      v4f v = acc[mi][ni];
#pragma unroll
      for (int r=0;r<4;r++)
        eps[(erb + r)*132 + wn + ni*16 + l15] = v[r] + bz[ni];
    }
    __syncthreads();
    {
      int e = tid>>3, seg = tid&7;
      int grow = bm + (e>>4)*64 + mi*16 + (e&15);
      int gcol = bn + seg*16;
      const float* ep = eps + e*132 + seg*16;
      if constexpr (ADD){
        float* cp = (float*)C + (size_t)grow*N + gcol;
#pragma unroll
        for (int u=0;u<4;u++){
          v4f ov = *(const v4f*)(ep + 4*u);
          v4f cv = *(const v4f*)(cp + 4*u);
          ov += cv;
          *(v4f*)(cp + 4*u) = ov;
        }
      } else {
        u16* cp = (u16*)C + (size_t)grow*N + gcol;
        v4f e0 = *(const v4f*)(ep+0), e1 = *(const v4f*)(ep+4);
        v4f e2 = *(const v4f*)(ep+8), e3 = *(const v4f*)(ep+12);
        uint4 pA = { pk2(e0[0],e0[1]), pk2(e0[2],e0[3]), pk2(e1[0],e1[1]), pk2(e1[2],e1[3]) };
        uint4 pB = { pk2(e2[0],e2[1]), pk2(e2[2],e2[3]), pk2(e3[0],e3[1]), pk2(e3[2],e3[3]) };
        *(uint4*)(cp)   = pA;
        *(uint4*)(cp+8) = pB;
      }
    }
    __syncthreads();
  }
}

// ---------------- dt matmul: dtraw(rows x 16) = r @ dt_wT^T; lane=(h,kslice) ----------------
__global__ __launch_bounds__(256) void k_dt(const u16* __restrict__ r, const u16* __restrict__ dtwT,
    float* __restrict__ dtraw)
{
  int row = blockIdx.x*4 + (threadIdx.x>>6);
  int lane = threadIdx.x & 63;
  int h = lane & 15, kg = lane >> 4;
  const u16* rp = r + (size_t)row*1024 + kg*256;
  const u16* wp = dtwT + h*1024 + kg*256;
  float sv = 0.f;
  for (int i=0;i<256;i+=16){
    float rv[16], wv[16];
    unp8(*(const uint4*)(rp+i),   rv);
    unp8(*(const uint4*)(rp+i+8), rv+8);
    unp8(*(const uint4*)(wp+i),   wv);
    unp8(*(const uint4*)(wp+i+8), wv+8);
#pragma unroll
    for (int j=0;j<16;j++) sv = fmaf(rv[j], wv[j], sv);
  }
  sv += __shfl_xor(sv, 16);
  sv += __shfl_xor(sv, 32);
  if (lane < 16) dtraw[(size_t)row*16 + lane] = sv;
}

// ---------------- prep2 per (b,l,h): hdtb = 0.5*dt; dtarr = dt ----------------
__global__ void k_prep2(const float* __restrict__ dtraw, const float* __restrict__ dt_b,
    float* __restrict__ hdtb, float* __restrict__ dtarr)
{
  int i = blockIdx.x*256 + threadIdx.x;
  int h = i & 15;
  float dt0 = fminf(softplus_f(dtraw[i] + dt_b[h]), 30.f);
  hdtb[i] = 0.5f*dt0;
  dtarr[i] = dt0;
}

// ---------------- chunk cumulative transition: prod[(bh*C+c)*64 + 2q+{0,1}] ----------------
__global__ void k_chunkprod(const float* __restrict__ dtarr, const float* __restrict__ A_log,
    const float* __restrict__ omega, float* __restrict__ prod)
{
  int i = blockIdx.x*256 + threadIdx.x;   // 1024 items: (bh, c)
  int bh = i >> 4, c = i & 15;
  int b = bh >> 4, h = bh & 15;
  size_t base = ((size_t)b*nL + c*T_CH)*16 + h;
  float S = 0.f;
  for (int t=0;t<T_CH;t++) S += dtarr[base + (size_t)t*16];
  float A = -expf(A_log[h]);
  float decF = expf(A*S);
  float* pp = prod + (size_t)i*64;
#pragma unroll
  for (int q=0;q<32;q++){
    float sn, cn; __sincosf(omega[q]*S, &sn, &cn);
    pp[q*2]   = decF*cn;
    pp[q*2+1] = decF*sn;
  }
}

// ---------------- scan phase 1 (rescaled prefix-sum form) ----------------
// h_l = P_l*(Gt_{l-1} + hdt_l*x_l*w_l);  w_l = B_l/P_l,  D_l = P_l*conj(C_l),
// y_l = sum_q Re(Gt*D_l) + hdt_l*x_l*E_l,  E_l = sum_q (B1C1+B2C2) (exact).
// Gt_l = Gt_{l-1} + (hdt_l + hdt_{l+1})*x_l*w_l (hdt beyond chunk = 0).
__global__ __launch_bounds__(256) void k_scan_p1(const u16* __restrict__ xz, const u16* __restrict__ bcb,
    const float* __restrict__ hdtb, const float* __restrict__ dtarr,
    const float* __restrict__ A_log, const float* __restrict__ omega,
    float* __restrict__ hend, float* __restrict__ ylocal)
{
  int bc_ = blockIdx.x;               // bh*16 + c
  int bh = bc_ >> 4, c = bc_ & 15;
  int b = bh >> 4, h = bh & 15;
  int t = threadIdx.x, p = t>>1, half = t&1, q0 = half*16;
  size_t rowbase = (size_t)b*nL + c*T_CH;
  __shared__ float sWr[T_CH+1][32], sWi[T_CH+1][32];   // w_s, s=0..64 (row0 = prev-chunk B)
  __shared__ float sDr[T_CH][32],   sDi[T_CH][32];     // D_l, l=1..64 at row l-1
  __shared__ float sS[T_CH], sdA[T_CH], seI[T_CH], sHD[T_CH], sE[T_CH];
  if (t < 64){
    float v = dtarr[(rowbase+t)*16 + h];
#pragma unroll
    for (int j=1;j<64;j<<=1){
      float o = __shfl_up(v, j);
      if (t >= j) v += o;
    }
    sS[t] = v;
  }
  __syncthreads();
  float A = -expf(A_log[h]);
  if (t < 64){
    float S = sS[t];
    sdA[t] = expf(A*S);
    seI[t] = expf(-A*S);
    sHD[t] = hdtb[(rowbase+t)*16 + h];
  }
  if (t >= 64 && t < 96){
    int q = t - 64;
    float b1=0.f, b2=0.f;
    if (c){
      b1 = bf2f(bcb[(rowbase-1)*2048 + h*64 + q]);
      b2 = bf2f(bcb[(rowbase-1)*2048 + h*64 + 32 + q]);
    }
    sWr[0][q] = b1; sWi[0][q] = b2;
  }
  __syncthreads();
  for (int e=t; e<T_CH*32; e+=256){
    int li = e>>5, q = e&31;
    size_t g = rowbase + li;
    float B1 = bf2f(bcb[g*2048 + h*64 + q]);
    float B2 = bf2f(bcb[g*2048 + h*64 + 32 + q]);
    float C1 = bf2f(bcb[g*2048 + 1024 + h*64 + q]);
    float C2 = bf2f(bcb[g*2048 + 1024 + h*64 + 32 + q]);
    float sn, cn; __sincosf(omega[q]*sS[li], &sn, &cn);
    float eI = seI[li], dA = sdA[li];
    sWr[li+1][q] = eI*(B1*cn + B2*sn);
    sWi[li+1][q] = eI*(B2*cn - B1*sn);
    sDr[li][q]   = dA*(cn*C1 + sn*C2);
    sDi[li][q]   = dA*(sn*C1 - cn*C2);
  }
  __syncthreads();
  if (t < 64){
    float e = 0.f;
#pragma unroll
    for (int q=0;q<32;q++)
      e += sWr[t+1][q]*sDr[t][q] - sWi[t+1][q]*sDi[t][q];   // = sum B1C1+B2C2 (exact)
    sE[t] = e;
  }
  __syncthreads();

  float gr[16], gi[16];
  float x0 = c ? bf2f(xz[(rowbase-1)*4096 + h*128 + p]) : 0.f;
  float c0 = sHD[0]*x0;
#pragma unroll
  for (int j4=0;j4<4;j4++){
    v4f wr0 = *(const v4f*)&sWr[0][q0+4*j4];
    v4f wi0 = *(const v4f*)&sWi[0][q0+4*j4];
#pragma unroll
    for (int j=0;j<4;j++){ gr[4*j4+j] = c0*wr0[j]; gi[4*j4+j] = c0*wi0[j]; }
  }
  const u16* xp = xz + rowbase*4096 + h*128 + p;
  float* yp = ylocal + rowbase*2048 + h*128 + p;
  for (int li=0; li<T_CH; li++){
    float hdt = sHD[li];
    float hnx = (li<T_CH-1) ? sHD[li+1] : 0.f;
    float xv = bf2f(*xp);
    float cx = (hdt + hnx)*xv;
    float y = 0.f;
#pragma unroll
    for (int j4=0;j4<4;j4++){
      v4f Dr = *(const v4f*)&sDr[li][q0+4*j4];
      v4f Di = *(const v4f*)&sDi[li][q0+4*j4];
      v4f Wr = *(const v4f*)&sWr[li+1][q0+4*j4];
      v4f Wi = *(const v4f*)&sWi[li+1][q0+4*j4];
#pragma unroll
      for (int j=0;j<4;j++){
        int jj = 4*j4+j;
        y = fmaf(gr[jj], Dr[j], y);
        y = fmaf(-gi[jj], Di[j], y);
        gr[jj] = fmaf(cx, Wr[j], gr[jj]);
        gi[jj] = fmaf(cx, Wi[j], gi[jj]);
      }
    }
    y += __shfl_xor(y, 1);
    if (half==0) *yp = fmaf(hdt*xv, sE[li], y);
    xp += 4096; yp += 2048;
  }
  // end state: h_64 = P_64 * Gt_64
  float S64 = sS[T_CH-1], dA64 = sdA[T_CH-1];
  float* hp = hend + ((size_t)bc_*256 + t)*32;
#pragma unroll
  for (int j4=0;j4<8;j4++){
    float hr[2], hi[2];
#pragma unroll
    for (int u=0;u<2;u++){
      int jj = 2*j4+u;
      float sn, cn; __sincosf(omega[q0+jj]*S64, &sn, &cn);
      float pr = dA64*cn, pi = dA64*sn;
      hr[u] = pr*gr[jj] - pi*gi[jj];
      hi[u] = pr*gi[jj] + pi*gr[jj];
    }
    v4f o = { hr[0], hi[0], hr[1], hi[1] };
    *(v4f*)(hp + 4*j4) = o;
  }
}

// ---------------- scan phase 2: carry propagation, parallel over (bh x 8 record-slices) ------
__global__ __launch_bounds__(256) void k_scan_p2(float* __restrict__ hend, const float* __restrict__ prod)
{
  int bh = blockIdx.x>>3, slice = blockIdx.x&7;
  int tid = threadIdx.x;
  int rec = slice*32 + (tid>>3);
  int sub = tid&7;
  int qa = (rec&1)*16 + sub*2;
  float c1a=0.f,c2a=0.f,c1b=0.f,c2b=0.f;
  for (int c=0;c<C_CH;c++){
    float* hp = hend + (((size_t)(bh*C_CH+c))*256 + rec)*32 + sub*4;
    v4f r = *(const v4f*)hp;
    v4f w = { c1a, c2a, c1b, c2b };
    *(v4f*)hp = w;
    const float* pp = prod + (size_t)(bh*C_CH+c)*64 + qa*2;
    float pr0=pp[0], pi0=pp[1], pr1=pp[2], pi1=pp[3];
    float n1a = fmaf(pr0,c1a, fmaf(-pi0,c2a, r[0]));
    float n2a = fmaf(pr0,c2a, fmaf( pi0,c1a, r[1]));
    float n1b = fmaf(pr1,c1b, fmaf(-pi1,c2b, r[2]));
    float n2b = fmaf(pr1,c2b, fmaf( pi1,c1b, r[3]));
    c1a=n1a; c2a=n2a; c1b=n1b; c2b=n2b;
  }
}

// ---------------- k_corr: y = ylocal + Re(carry . D_l) + Dskip*x; gate -> gbuf ----------------
__global__ __launch_bounds__(256) void k_corr(const u16* __restrict__ xz, const u16* __restrict__ bcb,
    const float* __restrict__ dtarr, const float* __restrict__ A_log, const float* __restrict__ omega,
    const float* __restrict__ Dsk, const float* __restrict__ hcar, const float* __restrict__ ylocal,
    u16* __restrict__ gbuf)
{
  int bc_ = blockIdx.x;               // bh*16 + c
  int bh = bc_ >> 4, c = bc_ & 15;
  int b = bh >> 4, h = bh & 15;
  int t = threadIdx.x, p = t>>1, qh = t&1, q0 = qh*16;
  size_t rowbase = (size_t)b*nL + c*T_CH;
  __shared__ float sDr[T_CH][32];
  __shared__ float sDi[T_CH][32];
  __shared__ float sS[T_CH];
  if (t < 64){
    float v = dtarr[(rowbase+t)*16 + h];
#pragma unroll
    for (int j=1;j<64;j<<=1){
      float o = __shfl_up(v, j);
      if (t >= j) v += o;
    }
    sS[t] = v;
  }
  __syncthreads();
  float A = -expf(A_log[h]);
  for (int e=t; e<T_CH*32; e+=256){
    int l = e>>5, q = e&31;
    float S = sS[l];
    float sn, cn; __sincosf(omega[q]*S, &sn, &cn);
    float dA = expf(A*S);
    float Ar = dA*cn, Ai = dA*sn;
    float C1 = bf2f(bcb[(rowbase+l)*2048 + 1024 + h*64 + q]);
    float C2 = bf2f(bcb[(rowbase+l)*2048 + 1024 + h*64 + 32 + q]);
    sDr[l][q] = Ar*C1 + Ai*C2;
    sDi[l][q] = Ai*C1 - Ar*C2;
  }
  __syncthreads();
  float c1[16], c2[16];
  const float* hp0 = hcar + ((size_t)bc_*256 + t)*32;
#pragma unroll
  for (int j4=0;j4<8;j4++){
    v4f r = *(const v4f*)(hp0 + 4*j4);
    c1[2*j4]=r[0]; c2[2*j4]=r[1]; c1[2*j4+1]=r[2]; c2[2*j4+1]=r[3];
  }
  float Dskip = Dsk[h];
  const float* yl = ylocal + rowbase*2048 + h*128 + p;
  const u16* xp = xz + rowbase*4096 + h*128 + p;
  const u16* zp = xp + 2048;
  u16* gp = gbuf + rowbase*2048 + h*128 + p;
  for (int l=0; l<T_CH; l++){
    float corr = 0.f;
#pragma unroll
    for (int j4=0;j4<4;j4++){
      v4f dr = *(const v4f*)&sDr[l][q0+4*j4];
      v4f di = *(const v4f*)&sDi[l][q0+4*j4];
#pragma unroll
      for (int j=0;j<4;j++){
        int jj = 4*j4+j;
        corr = fmaf(c1[jj], dr[j], corr);
        corr = fmaf(-c2[jj], di[j], corr);
      }
    }
    corr += __shfl_xor(corr, 1);
    if (qh==0){
      float xv = bf2f(*xp);
      float zv = bf2f(*zp);
      float yv = fmaf(xv, Dskip, yl[0] + corr);
      float g = yv*zv/(1.f+expf(-zv));
      *gp = f2bf(g);
    }
    yl += 2048; xp += 4096; zp += 4096; gp += 2048;
  }
}

// ---------------- attention logits ----------------
__global__ __launch_bounds__(256) void k_attn(const float* __restrict__ xn, const float* __restrict__ q,
    float* __restrict__ attn)
{
  int wid = blockIdx.x*4 + (threadIdx.x>>6);
  int lane = threadIdx.x & 63;
  const float* xr = xn + (size_t)wid*1024 + lane*16;
  const float* qr = q + lane*16;
  float sAcc=0.f;
#pragma unroll
  for (int j4=0;j4<4;j4++){
    v4f xv = *(const v4f*)(xr + 4*j4);
    v4f qv = *(const v4f*)(qr + 4*j4);
#pragma unroll
    for (int j=0;j<4;j++) sAcc = fmaf(xv[j], qv[j], sAcc);
  }
#pragma unroll
  for (int o=1;o<64;o<<=1) sAcc += __shfl_xor(sAcc,o);
  if (lane==0) attn[wid] = sAcc*(1.f/32.f);
}

// ---------------- softmax over L (in place) ----------------
__global__ __launch_bounds__(1024) void k_smax(float* __restrict__ attn)
{
  int b = blockIdx.x, t = threadIdx.x;
  __shared__ float red[16];
  __shared__ float red2[16];
  float av = attn[b*1024 + t];
  float m = av;
#pragma unroll
  for (int o=1;o<64;o<<=1) m = fmaxf(m, __shfl_xor(m,o));
  if ((t&63)==0) red[t>>6] = m;
  __syncthreads();
  float bm = red[0];
  for (int jj=1;jj<16;jj++) bm = fmaxf(bm, red[jj]);
  float e = expf(av - bm);
  float sm = e;
#pragma unroll
  for (int o=1;o<64;o<<=1) sm += __shfl_xor(sm,o);
  if ((t&63)==0) red2[t>>6] = sm;
  __syncthreads();
  float tot = 0.f;
  for (int jj=0;jj<16;jj++) tot += red2[jj];
  attn[b*1024 + t] = e/tot;
}

// ---------------- pooled partials: part[seg][b][w] = sum_{l in seg} p[l]*xn[b,l,w] -----------
__global__ __launch_bounds__(256) void k_pool2(const float* __restrict__ attnp, const float* __restrict__ xn,
    float* __restrict__ part)
{
  int wsl = blockIdx.x, b = blockIdx.y, seg = blockIdx.z, t = threadIdx.x;
  int w = wsl*64 + (t&63), ls = seg*128 + (t>>6);
  float acc = 0.f;
  for (int l=ls; l<seg*128+128; l+=4)
    acc = fmaf(attnp[b*1024 + l], xn[((size_t)b*1024 + l)*1024 + w], acc);
  __shared__ float red[256];
  red[t] = acc;
  __syncthreads();
  if (t<64)
    part[((size_t)seg*4 + b)*1024 + wsl*64 + t] = red[t]+red[t+64]+red[t+128]+red[t+192];
}

// ---------------- pool reduce: pooled[b,w] = sum_seg part[seg][b][w] ----------------
__global__ __launch_bounds__(1024) void k_pool3(const float* __restrict__ part, float* __restrict__ pooled)
{
  int b = blockIdx.x, t = threadIdx.x;
  float acc = 0.f;
#pragma unroll
  for (int seg=0; seg<8; seg++)
    acc += part[((size_t)seg*4 + b)*1024 + t];
  pooled[(size_t)b*1024 + t] = acc;
}

// ---------------- heads ----------------
__global__ __launch_bounds__(256) void k_heads(const float* __restrict__ pooled,
    const float* __restrict__ fw, const float* __restrict__ fb,
    const float* __restrict__ bw, const float* __restrict__ bb, float* __restrict__ outp)
{
  int o = blockIdx.x, t = threadIdx.x;
  int b, j, NJ; const float *Wp, *Bp;
  if (o < 16){ b = o>>2; j = o&3; NJ = 4; Wp = fw; Bp = fb; }
  else { int oo = o-16; b = oo/20; j = oo - b*20; NJ = 20; Wp = bw; Bp = bb; }
  v4f pv = *(const v4f*)(pooled + (size_t)b*1024 + t*4);
  int w0 = t*4;
  float sAcc = pv[0]*Wp[(size_t)(w0+0)*NJ + j] + pv[1]*Wp[(size_t)(w0+1)*NJ + j]
             + pv[2]*Wp[(size_t)(w0+2)*NJ + j] + pv[3]*Wp[(size_t)(w0+3)*NJ + j];
#pragma unroll
  for (int of=1; of<64; of<<=1) sAcc += __shfl_xor(sAcc, of);
  __shared__ float red[4];
  if ((t&63)==0) red[t>>6] = sAcc;
  __syncthreads();
  if (t==0) outp[o] = red[0]+red[1]+red[2]+red[3] + Bp[j];
}

extern "C" void kernel_launch(void* const* d_in, const int* in_sizes, int n_in,
                              void* d_out, int out_size, void* d_ws, size_t ws_size,
                              hipStream_t stream)
{
  (void)n_in; (void)out_size;
  int base = (in_sizes[2] >= 1000000) ? 1 : 2;
  const float* h_in   = (const float*)d_in[0];
  const float* ln_w   = (const float*)d_in[base+0];
  const float* in_w   = (const float*)d_in[base+1];
  const float* in_b   = (const float*)d_in[base+2];
  const float* dt_w   = (const float*)d_in[base+3];
  const float* dt_b   = (const float*)d_in[base+4];
  const float* bc_w   = (const float*)d_in[base+5];
  const float* bc_b   = (const float*)d_in[base+6];
  const float* A_log  = (const float*)d_in[base+7];
  const float* omega  = (const float*)d_in[base+8];
  const float* D_skip = (const float*)d_in[base+9];
  const float* out_w  = (const float*)d_in[base+10];
  const float* out_b  = (const float*)d_in[base+11];
  const float* fln_w  = (const float*)d_in[base+12];
  const float* queries= (const float*)d_in[base+13];
  const float* feat_w = (const float*)d_in[base+14];
  const float* feat_b = (const float*)d_in[base+15];
  const float* bias_w = (const float*)d_in[base+16];
  const float* bias_b = (const float*)d_in[base+17];

  char* w0 = (char*)d_ws;
  size_t off = 0;
  auto take = [&](size_t bytes)->char*{ char* pp = w0 + off; off += (bytes + 255) & ~(size_t)255; return pp; };
  u16* wT_in  = (u16*)take((size_t)4096*1024*2);
  u16* wT_bc  = (u16*)take((size_t)2048*1024*2);
  u16* wT_out = (u16*)take((size_t)1024*2048*2);
  u16* wT_dt  = (u16*)take((size_t)16*1024*2);
  float* x    = (float*)take((size_t)4194304*4);
  u16* rbf    = (u16*)take((size_t)4194304*2);
  u16* xz     = (u16*)take((size_t)16777216*2);
  u16* bcb    = (u16*)take((size_t)8388608*2);
  char* bigscratch = take((size_t)67108864);     // hendb(33.5M)+ylocal(33.5M) during scan; xn after
  u16* gbuf   = (u16*)take((size_t)8388608*2);
  float* dtraw= (float*)take((size_t)65536*4);
  float* dtarr= (float*)take((size_t)65536*4);
  float* hdtb = (float*)take((size_t)65536*4);
  float* attnb= (float*)take((size_t)4096*4);
  float* pool = (float*)take((size_t)4096*4);
  float* prodb= (float*)take((size_t)2048*64*4);
  float* partb= (float*)take((size_t)8*4*1024*4);
  if (off > ws_size) return;
  float* hendb  = (float*)bigscratch;                    // 1024 x 256 x 32 f = 33.5 MB
  float* ylocal = (float*)(bigscratch + 33554432);       // 4 x 1024 x 2048 f = 33.5 MB
  float* xn     = (float*)bigscratch;                    // alias (scan scratch dead after layers)

  k_cvt<<<4096,256,0,stream>>>(h_in, x);
  for (int d=0; d<4; d++){
    k_transpose<<<dim3(128,32),256,0,stream>>>(in_w + (size_t)d*1024*4096, wT_in, 1024, 4096);
    k_transpose<<<dim3(64,32),256,0,stream>>>(bc_w + (size_t)d*1024*2048, wT_bc, 1024, 2048);
    k_transpose<<<dim3(32,64),256,0,stream>>>(out_w + (size_t)d*2048*1024, wT_out, 2048, 1024);
    k_transpose<<<dim3(1,32),256,0,stream>>>(dt_w + (size_t)d*1024*16, wT_dt, 1024, 16);
    k_rmsnorm<<<4096,256,0,stream>>>(x, ln_w + d*1024, rbf, (float*)nullptr);
    k_gemm<u16,false><<<dim3(32,32),256,0,stream>>>(rbf, wT_in, in_b + d*4096, xz, 4096, 1024);
    k_gemm<u16,false><<<dim3(16,32),256,0,stream>>>(rbf, wT_bc, bc_b + d*2048, bcb, 2048, 1024);
    k_dt<<<1024,256,0,stream>>>(rbf, wT_dt, dtraw);
    k_prep2<<<256,256,0,stream>>>(dtraw, dt_b + d*16, hdtb, dtarr);
    k_chunkprod<<<4,256,0,stream>>>(dtarr, A_log + d*16, omega + d*32, prodb);
    k_scan_p1<<<1024,256,0,stream>>>(xz, bcb, hdtb, dtarr, A_log + d*16, omega + d*32,
                                     hendb, ylocal);
    k_scan_p2<<<512,256,0,stream>>>(hendb, prodb);
    k_corr<<<1024,256,0,stream>>>(xz, bcb, dtarr, A_log + d*16, omega + d*32,
                                  D_skip + d*16, hendb, ylocal, gbuf);
    k_gemm<float,true><<<dim3(8,32),256,0,stream>>>(gbuf, wT_out, out_b + d*1024, x, 1024, 2048);
  }
  k_rmsnorm<<<4096,256,0,stream>>>(x, fln_w, (u16*)nullptr, xn);
  k_attn<<<1024,256,0,stream>>>(xn, queries, attnb);
  k_smax<<<4,1024,0,stream>>>(attnb);
  k_pool2<<<dim3(16,4,8),256,0,stream>>>(attnb, xn, partb);
  k_pool3<<<4,1024,0,stream>>>(partb, pool);
  k_heads<<<96,256,0,stream>>>(pool, feat_w, feat_b, bias_w, bias_b, (float*)d_out);
}